// Round 1
// baseline (1551.825 us; speedup 1.0000x reference)
//
// CustomTransformerEncoderMoELayerStoich — MI355X (gfx950)
// Round 1: correctness-first pipeline.
//   - QKV / Wo projections: split-bf16 (hi+lo) 4-term MFMA GEMM  -> fp32-accurate (routing safety)
//   - attention: fp32 vector flash (online softmax, stoich bias exact)
//   - LN1 + gate + top2 routing: fp32, wave-per-token
//   - MoE FFN: grouped bf16 MFMA GEMMs over padded per-expert token tiles (128)
//   - LN2 gather epilogue
// Workspace budget ~241 MB (aliased regions, see offsets in kernel_launch).

#include <hip/hip_runtime.h>
#include <stdint.h>

typedef unsigned short u16;
typedef unsigned int   u32;

using bf16x8 = __attribute__((ext_vector_type(8))) short;
using f32x4  = __attribute__((ext_vector_type(4))) float;

#define N_T   1024
#define N_D   1024
#define N_HD  64
#define N_E   8
#define N_BT  4096
#define LNEPS 1e-5f

// ---------------- helpers ----------------
__device__ __forceinline__ u32 rne2(float a, float b) {
  u32 ua = __float_as_uint(a); ua = (ua + 0x7fffu + ((ua >> 16) & 1u)) >> 16;
  u32 ub = __float_as_uint(b); ub = (ub + 0x7fffu + ((ub >> 16) & 1u)) >> 16;
  return ua | (ub << 16);
}
__device__ __forceinline__ u16 rne1(float a) {
  u32 ua = __float_as_uint(a);
  return (u16)((ua + 0x7fffu + ((ua >> 16) & 1u)) >> 16);
}
__device__ __forceinline__ float bfhi_f(float a) {   // nearest-bf16 value as fp32
  u32 ua = __float_as_uint(a);
  ua = (ua + 0x7fffu + ((ua >> 16) & 1u)) & 0xffff0000u;
  return __uint_as_float(ua);
}
// 16B-chunk XOR swizzle inside a [row][32 bf16] tile: 2-way (free) frag-read conflicts
__device__ __forceinline__ int swz(int row, int chunk) {
  return row * 32 + (((chunk ^ (row & 3) ^ ((row >> 2) & 3)) & 3) << 3);
}
__device__ __forceinline__ float wred(float v) {
  #pragma unroll
  for (int o2 = 32; o2 > 0; o2 >>= 1) v += __shfl_xor(v, o2, 64);
  return v;
}
__device__ __forceinline__ f32x4 mfma16(bf16x8 a, bf16x8 b, f32x4 c) {
  return __builtin_amdgcn_mfma_f32_16x16x32_bf16(a, b, c, 0, 0, 0);
}

// ---------------- transpose fp32 [R][C] -> bf16 [C][R] (optional hi/lo split) ----------------
template<int SPLIT>
__global__ __launch_bounds__(256)
void transpose_bf16(const float* __restrict__ in, u16* __restrict__ outh,
                    u16* __restrict__ outl, int R, int C)
{
  __shared__ u16 th[64][68];
  __shared__ u16 tl[SPLIT ? 64 : 1][SPLIT ? 68 : 1];
  const long long zb = (long long)blockIdx.z * R * C;
  const float* srcp = in + zb;
  const int r0 = blockIdx.y * 64, c0 = blockIdx.x * 64;
  const int t = threadIdx.x;
  {
    const int rr = t >> 4, cc = (t & 15) << 2;
    #pragma unroll
    for (int i = 0; i < 4; i++) {
      const int r = rr + i * 16;
      float4 v = *(const float4*)(srcp + (long long)(r0 + r) * C + c0 + cc);
      if constexpr (SPLIT) {
        float hx = bfhi_f(v.x), hy = bfhi_f(v.y), hz = bfhi_f(v.z), hw = bfhi_f(v.w);
        *(uint2*)&th[r][cc] = make_uint2(rne2(hx, hy), rne2(hz, hw));
        *(uint2*)&tl[r][cc] = make_uint2(rne2(v.x - hx, v.y - hy), rne2(v.z - hz, v.w - hw));
      } else {
        *(uint2*)&th[r][cc] = make_uint2(rne2(v.x, v.y), rne2(v.z, v.w));
      }
    }
  }
  __syncthreads();
  {
    const int c = t >> 2, rs = (t & 3) << 4;
    const long long ob = zb + (long long)(c0 + c) * R + r0 + rs;
    u32 w[8];
    #pragma unroll
    for (int i = 0; i < 8; i++)
      w[i] = (u32)th[rs + 2*i][c] | ((u32)th[rs + 2*i + 1][c] << 16);
    *(uint4*)(outh + ob)     = make_uint4(w[0], w[1], w[2], w[3]);
    *(uint4*)(outh + ob + 8) = make_uint4(w[4], w[5], w[6], w[7]);
    if constexpr (SPLIT) {
      #pragma unroll
      for (int i = 0; i < 8; i++)
        w[i] = (u32)tl[rs + 2*i][c] | ((u32)tl[rs + 2*i + 1][c] << 16);
      *(uint4*)(outl + ob)     = make_uint4(w[0], w[1], w[2], w[3]);
      *(uint4*)(outl + ob + 8) = make_uint4(w[4], w[5], w[6], w[7]);
    }
  }
}

// ---------------- 128x128x32 MFMA GEMM (4 waves, 4x4 16x16 frags each) ----------------
// C[m][n] = A[m][:] * B[:][n] (+bias[n]) ; B provided TRANSPOSED bf16 [N][K] (hi + optional lo).
// SPLIT: A fp32 split on the fly into hi/lo bf16; 4 MFMAs per frag pair (~2^-18 rel err).
// GROUPED: blockIdx.x -> tile descriptor {expert, slot_base}; GATHER: A row = token_idx[slot].
template<int SPLIT, int ABF, int GATHER, int DORELU, int DOSCALE, int OBF, int GROUPED>
__global__ __launch_bounds__(256, 2)
void gemm128(const void* __restrict__ Ap, int lda,
             const u16* __restrict__ Bhp, const u16* __restrict__ Blp,
             long long bstride,
             void* __restrict__ Cp, int ldc,
             const float* __restrict__ biasp, int bias_stride,
             const float* __restrict__ slot_wp,
             const int* __restrict__ tokidx,
             const int2* __restrict__ tilesp, const int* __restrict__ ntilesp,
             int Ksz)
{
  int e = 0, row0;
  if constexpr (GROUPED) {
    if ((int)blockIdx.x >= *ntilesp) return;
    const int2 dsc = tilesp[blockIdx.x];
    e = dsc.x; row0 = dsc.y;
  } else {
    row0 = blockIdx.x * 128;
  }
  const int col0 = blockIdx.y * 128;

  __shared__ __align__(16) u16 AhS[128 * 32];
  __shared__ __align__(16) u16 BhS[128 * 32];
  __shared__ __align__(16) u16 AlS[SPLIT ? 128 * 32 : 8];
  __shared__ __align__(16) u16 BlS[SPLIT ? 128 * 32 : 8];

  const int tid = threadIdx.x;
  const int rr = tid >> 1;            // staging row (A row / B^T row)
  const int c2 = (tid & 1) << 1;      // 16B-chunk pair base

  long long arow;
  if constexpr (GATHER) arow = tokidx[row0 + rr];
  else                  arow = row0 + rr;
  const char* Arow = (const char*)Ap + arow * (long long)lda * (ABF ? 2 : 4);
  const u16* Bhrow = Bhp + (long long)e * bstride + (long long)(col0 + rr) * Ksz;
  const u16* Blrow = nullptr;
  if constexpr (SPLIT) Blrow = Blp + (long long)e * bstride + (long long)(col0 + rr) * Ksz;
  const float* bias = biasp + (long long)e * bias_stride + col0;

  const int wid = tid >> 6, lane = tid & 63;
  const int wm = (wid >> 1) << 6, wn = (wid & 1) << 6;
  const int l15 = lane & 15, l4 = lane >> 4;

  f32x4 acc[4][4] = {};

  uint4 sah0, sah1, sal0, sal1, sbh0, sbh1, sbl0, sbl1;

  auto gload = [&](int k0) {
    if constexpr (ABF) {
      const uint4* ap = (const uint4*)(Arow + (long long)(k0 + c2 * 8) * 2);
      sah0 = ap[0]; sah1 = ap[1];
    } else {
      const float4* ap = (const float4*)(Arow + (long long)(k0 + c2 * 8) * 4);
      float4 f0 = ap[0], f1 = ap[1], f2 = ap[2], f3 = ap[3];
      if constexpr (SPLIT) {
        float h0 = bfhi_f(f0.x), h1 = bfhi_f(f0.y), h2 = bfhi_f(f0.z), h3 = bfhi_f(f0.w);
        float h4 = bfhi_f(f1.x), h5 = bfhi_f(f1.y), h6 = bfhi_f(f1.z), h7 = bfhi_f(f1.w);
        sah0 = make_uint4(rne2(h0, h1), rne2(h2, h3), rne2(h4, h5), rne2(h6, h7));
        sal0 = make_uint4(rne2(f0.x - h0, f0.y - h1), rne2(f0.z - h2, f0.w - h3),
                          rne2(f1.x - h4, f1.y - h5), rne2(f1.z - h6, f1.w - h7));
        h0 = bfhi_f(f2.x); h1 = bfhi_f(f2.y); h2 = bfhi_f(f2.z); h3 = bfhi_f(f2.w);
        h4 = bfhi_f(f3.x); h5 = bfhi_f(f3.y); h6 = bfhi_f(f3.z); h7 = bfhi_f(f3.w);
        sah1 = make_uint4(rne2(h0, h1), rne2(h2, h3), rne2(h4, h5), rne2(h6, h7));
        sal1 = make_uint4(rne2(f2.x - h0, f2.y - h1), rne2(f2.z - h2, f2.w - h3),
                          rne2(f3.x - h4, f3.y - h5), rne2(f3.z - h6, f3.w - h7));
      } else {
        sah0 = make_uint4(rne2(f0.x, f0.y), rne2(f0.z, f0.w), rne2(f1.x, f1.y), rne2(f1.z, f1.w));
        sah1 = make_uint4(rne2(f2.x, f2.y), rne2(f2.z, f2.w), rne2(f3.x, f3.y), rne2(f3.z, f3.w));
      }
    }
    {
      const uint4* bp = (const uint4*)(Bhrow + k0 + c2 * 8);
      sbh0 = bp[0]; sbh1 = bp[1];
    }
    if constexpr (SPLIT) {
      const uint4* bp = (const uint4*)(Blrow + k0 + c2 * 8);
      sbl0 = bp[0]; sbl1 = bp[1];
    }
  };

  gload(0);
  const int nk = Ksz >> 5;
  for (int kt = 0; kt < nk; kt++) {
    __syncthreads();
    *(uint4*)&AhS[swz(rr, c2)]     = sah0;
    *(uint4*)&AhS[swz(rr, c2 + 1)] = sah1;
    *(uint4*)&BhS[swz(rr, c2)]     = sbh0;
    *(uint4*)&BhS[swz(rr, c2 + 1)] = sbh1;
    if constexpr (SPLIT) {
      *(uint4*)&AlS[swz(rr, c2)]     = sal0;
      *(uint4*)&AlS[swz(rr, c2 + 1)] = sal1;
      *(uint4*)&BlS[swz(rr, c2)]     = sbl0;
      *(uint4*)&BlS[swz(rr, c2 + 1)] = sbl1;
    }
    __syncthreads();
    if (kt + 1 < nk) gload((kt + 1) << 5);

    bf16x8 ah[4], bh[4], al[SPLIT ? 4 : 1], bl[SPLIT ? 4 : 1];
    #pragma unroll
    for (int i = 0; i < 4; i++) {
      const int ar = wm + i * 16 + l15;
      const int br = wn + i * 16 + l15;
      ah[i] = *(const bf16x8*)&AhS[swz(ar, l4)];
      bh[i] = *(const bf16x8*)&BhS[swz(br, l4)];
      if constexpr (SPLIT) {
        al[i] = *(const bf16x8*)&AlS[swz(ar, l4)];
        bl[i] = *(const bf16x8*)&BlS[swz(br, l4)];
      }
    }
    #pragma unroll
    for (int i = 0; i < 4; i++) {
      #pragma unroll
      for (int j = 0; j < 4; j++) {
        acc[i][j] = mfma16(ah[i], bh[j], acc[i][j]);
        if constexpr (SPLIT) {
          acc[i][j] = mfma16(ah[i], bl[j], acc[i][j]);
          acc[i][j] = mfma16(al[i], bh[j], acc[i][j]);
          acc[i][j] = mfma16(al[i], bl[j], acc[i][j]);
        }
      }
    }
  }

  #pragma unroll
  for (int i = 0; i < 4; i++) {
    #pragma unroll
    for (int j = 0; j < 4; j++) {
      const int orow0 = row0 + wm + i * 16 + (l4 << 2);
      const int ocol  = col0 + wn + j * 16 + l15;
      const float bv = bias[wn + j * 16 + l15];
      #pragma unroll
      for (int q = 0; q < 4; q++) {
        float v = acc[i][j][q] + bv;
        if constexpr (DORELU) v = fmaxf(v, 0.f);
        const long long orow = orow0 + q;
        if constexpr (DOSCALE) v *= slot_wp[orow];
        if constexpr (OBF) ((u16*)Cp)[orow * ldc + ocol] = rne1(v);
        else               ((float*)Cp)[orow * ldc + ocol] = v;
      }
    }
  }
}

// ---------------- fp32 flash attention with stoichiometric bias ----------------
// grid (B*H, T/128), block 128: one thread = one q row; K/V tiles (64 rows) staged in LDS.
__global__ __launch_bounds__(128, 2)
void attn_fwd(const float* __restrict__ Q, const float* __restrict__ Kc,
              const float* __restrict__ Vc, const float* __restrict__ frac,
              const float* __restrict__ apos, const float* __restrict__ aneg,
              float* __restrict__ ctx)
{
  __shared__ float Kl[64][68];
  __shared__ float Vl[64][68];
  __shared__ float fj[64];
  const int bh = blockIdx.x;
  const int b = bh >> 4, h = bh & 15;
  const int t = blockIdx.y * 128 + threadIdx.x;
  const long long qoff = ((long long)(b * N_T + t)) * N_D + h * N_HD;
  float4 q4[16], o4[16];
  #pragma unroll
  for (int i = 0; i < 16; i++) {
    float4 v = *(const float4*)(Q + qoff + i * 4);
    q4[i] = make_float4(v.x * 0.125f, v.y * 0.125f, v.z * 0.125f, v.w * 0.125f);
    o4[i] = make_float4(0.f, 0.f, 0.f, 0.f);
  }
  const float fi = frac[b * N_T + t];
  const float ap = apos[h], an = aneg[h];
  float m = -__builtin_inff(), l = 0.f;

  const int sr = threadIdx.x >> 1, sh = (threadIdx.x & 1) * 8;
  for (int kt = 0; kt < N_T; kt += 64) {
    __syncthreads();
    const long long koff = ((long long)(b * N_T + kt + sr)) * N_D + h * N_HD + sh * 4;
    const float4* kp = (const float4*)(Kc + koff);
    const float4* vp = (const float4*)(Vc + koff);
    #pragma unroll
    for (int i = 0; i < 8; i++) *(float4*)&Kl[sr][(sh + i) * 4] = kp[i];
    #pragma unroll
    for (int i = 0; i < 8; i++) *(float4*)&Vl[sr][(sh + i) * 4] = vp[i];
    if (threadIdx.x < 64) fj[threadIdx.x] = frac[b * N_T + kt + threadIdx.x];
    __syncthreads();
    for (int j = 0; j < 64; j++) {
      const float4* kr = (const float4*)&Kl[j][0];
      float sp[4] = {0.f, 0.f, 0.f, 0.f};
      #pragma unroll
      for (int i = 0; i < 16; i++) {
        float4 kv = kr[i];
        sp[i & 3] += q4[i].x * kv.x + q4[i].y * kv.y + q4[i].z * kv.z + q4[i].w * kv.w;
      }
      float s = (sp[0] + sp[1]) + (sp[2] + sp[3]);
      const float dm = fj[j] - fi;
      s += (dm > 0.f ? ap : an) * dm;   // ap*relu(dm) - an*relu(-dm)
      const float nm = fmaxf(m, s);
      if (nm > m) {
        const float cor = __expf(m - nm);
        l *= cor;
        #pragma unroll
        for (int i = 0; i < 16; i++) {
          o4[i].x *= cor; o4[i].y *= cor; o4[i].z *= cor; o4[i].w *= cor;
        }
        m = nm;
      }
      const float p = __expf(s - m);
      l += p;
      const float4* vr = (const float4*)&Vl[j][0];
      #pragma unroll
      for (int i = 0; i < 16; i++) {
        float4 vv = vr[i];
        o4[i].x += p * vv.x; o4[i].y += p * vv.y; o4[i].z += p * vv.z; o4[i].w += p * vv.w;
      }
    }
  }
  const float inv = 1.f / l;
  #pragma unroll
  for (int i = 0; i < 16; i++)
    *(float4*)(ctx + qoff + i * 4) =
        make_float4(o4[i].x * inv, o4[i].y * inv, o4[i].z * inv, o4[i].w * inv);
}

// ---------------- LN1 + gate softmax + top2 (wave per token) ----------------
__global__ __launch_bounds__(256, 4)
void ln1_gate(const float* __restrict__ src, const float* __restrict__ attnout,
              const float* __restrict__ g, const float* __restrict__ bb,
              const float* __restrict__ gateW, const float* __restrict__ gateb,
              float* __restrict__ xout, int* __restrict__ counts,
              int2* __restrict__ tok_top, float2* __restrict__ tok_w)
{
  const int wid = threadIdx.x >> 6, lane = threadIdx.x & 63;
  const int t = blockIdx.x * 4 + wid;
  const float4* s4 = (const float4*)(src + (long long)t * N_D);
  const float4* a4 = (const float4*)(attnout + (long long)t * N_D);
  float4 v[4];
  float sum = 0.f;
  #pragma unroll
  for (int c = 0; c < 4; c++) {
    const int idx = c * 64 + lane;
    float4 a = s4[idx], b2 = a4[idx];
    v[c] = make_float4(a.x + b2.x, a.y + b2.y, a.z + b2.z, a.w + b2.w);
    sum += v[c].x + v[c].y + v[c].z + v[c].w;
  }
  sum = wred(sum);
  const float mu = sum * (1.f / 1024.f);
  float s2 = 0.f;
  #pragma unroll
  for (int c = 0; c < 4; c++) {
    float dx = v[c].x - mu, dy = v[c].y - mu, dz = v[c].z - mu, dw = v[c].w - mu;
    s2 += dx * dx + dy * dy + dz * dz + dw * dw;
  }
  s2 = wred(s2);
  const float rs = rsqrtf(s2 * (1.f / 1024.f) + LNEPS);
  float acc[8];
  #pragma unroll
  for (int e2 = 0; e2 < 8; e2++) acc[e2] = 0.f;
  #pragma unroll
  for (int c = 0; c < 4; c++) {
    const int idx = c * 64 + lane;
    float4 gv = ((const float4*)g)[idx], bv = ((const float4*)bb)[idx];
    float xa[4];
    xa[0] = (v[c].x - mu) * rs * gv.x + bv.x;
    xa[1] = (v[c].y - mu) * rs * gv.y + bv.y;
    xa[2] = (v[c].z - mu) * rs * gv.z + bv.z;
    xa[3] = (v[c].w - mu) * rs * gv.w + bv.w;
    ((float4*)(xout + (long long)t * N_D))[idx] = make_float4(xa[0], xa[1], xa[2], xa[3]);
    #pragma unroll
    for (int ii = 0; ii < 4; ii++) {
      const float xs = xa[ii];
      const float4* gw = (const float4*)(gateW + ((long long)(idx * 4 + ii)) * N_E);
      float4 w0 = gw[0], w1 = gw[1];
      acc[0] += xs * w0.x; acc[1] += xs * w0.y; acc[2] += xs * w0.z; acc[3] += xs * w0.w;
      acc[4] += xs * w1.x; acc[5] += xs * w1.y; acc[6] += xs * w1.z; acc[7] += xs * w1.w;
    }
  }
  #pragma unroll
  for (int e2 = 0; e2 < 8; e2++) acc[e2] = wred(acc[e2]);
  if (lane == 0) {
    float lg[8];
    #pragma unroll
    for (int e2 = 0; e2 < 8; e2++) lg[e2] = acc[e2] + gateb[e2];
    float mx = lg[0];
    #pragma unroll
    for (int e2 = 1; e2 < 8; e2++) mx = fmaxf(mx, lg[e2]);
    float Z = 0.f;
    #pragma unroll
    for (int e2 = 0; e2 < 8; e2++) Z += __expf(lg[e2] - mx);
    int e0 = 0; float v0 = lg[0];
    #pragma unroll
    for (int e2 = 1; e2 < 8; e2++) if (lg[e2] > v0) { v0 = lg[e2]; e0 = e2; }
    int e1 = -1; float v1 = -3.4e38f;
    #pragma unroll
    for (int e2 = 0; e2 < 8; e2++) if (e2 != e0 && lg[e2] > v1) { v1 = lg[e2]; e1 = e2; }
    atomicAdd(&counts[e0], 1);
    atomicAdd(&counts[e1], 1);
    tok_top[t] = make_int2(e0, e1);
    tok_w[t] = make_float2(__expf(v0 - mx) / Z, __expf(v1 - mx) / Z);
  }
}

// ---------------- routing: offsets, tile descriptors, padding fill ----------------
__global__ void route_build(const int* __restrict__ counts, int* __restrict__ offsets,
                            int* __restrict__ cursors, int* __restrict__ ntiles,
                            int2* __restrict__ tiles, int* __restrict__ token_idx,
                            float* __restrict__ slot_w)
{
  __shared__ int soff[N_E + 1];
  __shared__ int scnt[N_E];
  if (threadIdx.x == 0) {
    int off = 0, nt = 0;
    for (int ex = 0; ex < N_E; ex++) {
      soff[ex] = off; offsets[ex] = off; cursors[ex] = 0;
      const int cnt = counts[ex];
      scnt[ex] = cnt;
      const int pt = (cnt + 127) >> 7;
      for (int i = 0; i < pt; i++) { tiles[nt] = make_int2(ex, off + i * 128); nt++; }
      off += pt << 7;
    }
    soff[N_E] = off; offsets[N_E] = off;
    *ntiles = nt;
  }
  __syncthreads();
  for (int ex = 0; ex < N_E; ex++)
    for (int s = soff[ex] + scnt[ex] + (int)threadIdx.x; s < soff[ex + 1]; s += (int)blockDim.x) {
      token_idx[s] = 0; slot_w[s] = 0.f;
    }
}

__global__ __launch_bounds__(256)
void route_scatter(const int2* __restrict__ tok_top, const float2* __restrict__ tok_w,
                   const int* __restrict__ offsets, int* __restrict__ cursors,
                   int* __restrict__ token_idx, float* __restrict__ slot_w,
                   int* __restrict__ slotA, int* __restrict__ slotB)
{
  const int t = blockIdx.x * 256 + threadIdx.x;
  if (t >= N_BT) return;
  const int2 ee = tok_top[t];
  const float2 ww = tok_w[t];
  int p = atomicAdd(&cursors[ee.x], 1);
  int s = offsets[ee.x] + p;
  token_idx[s] = t; slot_w[s] = ww.x; slotA[t] = s;
  p = atomicAdd(&cursors[ee.y], 1);
  s = offsets[ee.y] + p;
  token_idx[s] = t; slot_w[s] = ww.y; slotB[t] = s;
}

// ---------------- final: y = LN2(x + out2[sA] + out2[sB]) ----------------
__global__ __launch_bounds__(256, 4)
void final_ln2(const float* __restrict__ x, const float* __restrict__ out2,
               const int* __restrict__ slotA, const int* __restrict__ slotB,
               const float* __restrict__ g, const float* __restrict__ bb,
               float* __restrict__ out)
{
  const int wid = threadIdx.x >> 6, lane = threadIdx.x & 63;
  const int t = blockIdx.x * 4 + wid;
  const int sA = slotA[t], sB = slotB[t];
  const float4* xr = (const float4*)(x + (long long)t * N_D);
  const float4* pa = (const float4*)(out2 + (long long)sA * N_D);
  const float4* pb = (const float4*)(out2 + (long long)sB * N_D);
  float4 v[4];
  float sum = 0.f;
  #pragma unroll
  for (int c = 0; c < 4; c++) {
    const int idx = c * 64 + lane;
    float4 a = xr[idx], b2 = pa[idx], c2 = pb[idx];
    v[c] = make_float4(a.x + b2.x + c2.x, a.y + b2.y + c2.y,
                       a.z + b2.z + c2.z, a.w + b2.w + c2.w);
    sum += v[c].x + v[c].y + v[c].z + v[c].w;
  }
  sum = wred(sum);
  const float mu = sum * (1.f / 1024.f);
  float s2 = 0.f;
  #pragma unroll
  for (int c = 0; c < 4; c++) {
    float dx = v[c].x - mu, dy = v[c].y - mu, dz = v[c].z - mu, dw = v[c].w - mu;
    s2 += dx * dx + dy * dy + dz * dz + dw * dw;
  }
  s2 = wred(s2);
  const float rs = rsqrtf(s2 * (1.f / 1024.f) + LNEPS);
  #pragma unroll
  for (int c = 0; c < 4; c++) {
    const int idx = c * 64 + lane;
    float4 gv = ((const float4*)g)[idx], bv = ((const float4*)bb)[idx];
    float4 o;
    o.x = (v[c].x - mu) * rs * gv.x + bv.x;
    o.y = (v[c].y - mu) * rs * gv.y + bv.y;
    o.z = (v[c].z - mu) * rs * gv.z + bv.z;
    o.w = (v[c].w - mu) * rs * gv.w + bv.w;
    ((float4*)(out + (long long)t * N_D))[idx] = o;
  }
}

// ---------------- launch ----------------
extern "C" void kernel_launch(void* const* d_in, const int* in_sizes, int n_in,
                              void* d_out, int out_size, void* d_ws, size_t ws_size,
                              hipStream_t stream)
{
  const float* src   = (const float*)d_in[0];
  const float* frac  = (const float*)d_in[1];
  const float* Wq    = (const float*)d_in[2];
  const float* bq    = (const float*)d_in[3];
  const float* Wk    = (const float*)d_in[4];
  const float* bk    = (const float*)d_in[5];
  const float* Wv    = (const float*)d_in[6];
  const float* bv    = (const float*)d_in[7];
  const float* Wo    = (const float*)d_in[8];
  const float* bo    = (const float*)d_in[9];
  const float* apos  = (const float*)d_in[10];
  const float* aneg  = (const float*)d_in[11];
  const float* gateW = (const float*)d_in[12];
  const float* gateb = (const float*)d_in[13];
  const float* W1    = (const float*)d_in[14];
  const float* b1    = (const float*)d_in[15];
  const float* W2    = (const float*)d_in[16];
  const float* b2    = (const float*)d_in[17];
  const float* ln1g  = (const float*)d_in[18];
  const float* ln1b  = (const float*)d_in[19];
  const float* ln2g  = (const float*)d_in[20];
  const float* ln2b  = (const float*)d_in[21];
  float* out = (float*)d_out;

  char* ws = (char*)d_ws;
  const size_t MB = 1ull << 20;
  // phase-aliased workspace (~241 MB total)
  u16* WqTh = (u16*)(ws + 0 * MB);   u16* WqTl = (u16*)(ws + 2 * MB);
  u16* WkTh = (u16*)(ws + 4 * MB);   u16* WkTl = (u16*)(ws + 6 * MB);
  u16* WvTh = (u16*)(ws + 8 * MB);   u16* WvTl = (u16*)(ws + 10 * MB);
  u16* WoTh = (u16*)(ws + 12 * MB);  u16* WoTl = (u16*)(ws + 14 * MB);
  u16*   W1T  = (u16*)(ws + 16 * MB);    // 64 MB, dead after GEMM1
  float* out2 = (float*)(ws + 16 * MB);  // 36 MB, alias of W1T (written after)
  u16*   W2T  = (u16*)(ws + 80 * MB);    // 64 MB
  float* Qb    = (float*)(ws + 144 * MB);
  float* Kb    = (float*)(ws + 160 * MB);
  float* Vb    = (float*)(ws + 176 * MB);
  float* ctxb  = (float*)(ws + 192 * MB);
  float* attnb = (float*)(ws + 208 * MB);
  u16*   hb    = (u16*)(ws + 144 * MB);  // 72 MB, alias of Q/K/V/ctx/attn (dead by then)
  float* xb    = (float*)(ws + 224 * MB);
  char* misc = ws + 240 * MB;
  int*    counts    = (int*)(misc);
  int*    cursors   = (int*)(misc + 64);
  int*    offsets   = (int*)(misc + 128);
  int*    ntiles    = (int*)(misc + 256);
  int2*   tiles     = (int2*)(misc + 512);
  int2*   tok_top   = (int2*)(misc + 2048);
  float2* tok_w     = (float2*)(misc + 2048 + 32768);
  int*    token_idx = (int*)(misc + 2048 + 65536);
  float*  slot_w    = (float*)(misc + 2048 + 65536 + 36864);
  int*    slotA     = (int*)(misc + 2048 + 65536 + 73728);
  int*    slotB     = (int*)(misc + 2048 + 65536 + 73728 + 16384);

  hipMemsetAsync(counts, 0, 32, stream);

  dim3 b256(256);
  // weight transposes (fp32 -> bf16 [n][k]; hi/lo split for precision-critical path)
  transpose_bf16<1><<<dim3(16, 16, 1), b256, 0, stream>>>(Wq, WqTh, WqTl, 1024, 1024);
  transpose_bf16<1><<<dim3(16, 16, 1), b256, 0, stream>>>(Wk, WkTh, WkTl, 1024, 1024);
  transpose_bf16<1><<<dim3(16, 16, 1), b256, 0, stream>>>(Wv, WvTh, WvTl, 1024, 1024);
  transpose_bf16<1><<<dim3(16, 16, 1), b256, 0, stream>>>(Wo, WoTh, WoTl, 1024, 1024);
  transpose_bf16<0><<<dim3(64, 16, 8), b256, 0, stream>>>(W1, W1T, nullptr, 1024, 4096);
  transpose_bf16<0><<<dim3(16, 64, 8), b256, 0, stream>>>(W2, W2T, nullptr, 4096, 1024);

  // QKV projections (split-bf16, fp32-accurate)
  gemm128<1, 0, 0, 0, 0, 0, 0><<<dim3(32, 8), b256, 0, stream>>>(
      src, 1024, WqTh, WqTl, 0, Qb, 1024, bq, 0, nullptr, nullptr, nullptr, nullptr, 1024);
  gemm128<1, 0, 0, 0, 0, 0, 0><<<dim3(32, 8), b256, 0, stream>>>(
      src, 1024, WkTh, WkTl, 0, Kb, 1024, bk, 0, nullptr, nullptr, nullptr, nullptr, 1024);
  gemm128<1, 0, 0, 0, 0, 0, 0><<<dim3(32, 8), b256, 0, stream>>>(
      src, 1024, WvTh, WvTl, 0, Vb, 1024, bv, 0, nullptr, nullptr, nullptr, nullptr, 1024);

  attn_fwd<<<dim3(64, 8), dim3(128), 0, stream>>>(Qb, Kb, Vb, frac, apos, aneg, ctxb);

  gemm128<1, 0, 0, 0, 0, 0, 0><<<dim3(32, 8), b256, 0, stream>>>(
      ctxb, 1024, WoTh, WoTl, 0, attnb, 1024, bo, 0, nullptr, nullptr, nullptr, nullptr, 1024);

  ln1_gate<<<dim3(1024), b256, 0, stream>>>(src, attnb, ln1g, ln1b, gateW, gateb,
                                            xb, counts, tok_top, tok_w);
  route_build<<<dim3(1), dim3(64), 0, stream>>>(counts, offsets, cursors, ntiles,
                                                tiles, token_idx, slot_w);
  route_scatter<<<dim3(16), b256, 0, stream>>>(tok_top, tok_w, offsets, cursors,
                                               token_idx, slot_w, slotA, slotB);

  // grouped MoE FFN: h = relu(x[tok] @ W1[e] + b1[e]) ; out2 = w * (h @ W2[e] + b2[e])
  gemm128<0, 0, 1, 1, 0, 1, 1><<<dim3(72, 32), b256, 0, stream>>>(
      xb, 1024, W1T, nullptr, 4096ll * 1024, hb, 4096, b1, 4096,
      nullptr, token_idx, tiles, ntiles, 1024);
  gemm128<0, 1, 0, 0, 1, 0, 1><<<dim3(72, 8), b256, 0, stream>>>(
      hb, 4096, W2T, nullptr, 1024ll * 4096, out2, 1024, b2, 1024,
      slot_w, nullptr, tiles, ntiles, 4096);

  final_ln2<<<dim3(1024), b256, 0, stream>>>(xb, out2, slotA, slotB, ln2g, ln2b, out);
}

// Round 4
// 874.584 us; speedup vs baseline: 1.7744x; 1.7744x over previous
//
// CustomTransformerEncoderMoELayerStoich — MI355X (gfx950)
// Round 4: MFMA flash attention, verified-primitive-only data paths.
//   - QKV GEMM: split-bf16 4-term MFMA; epilogue writes Q,K as hi/lo bf16 (Q pre-scaled 1/8)
//   - V: fp32 -> per-head transposed hi/lo bf16 [d][kv] (plain transpose, no permutation)
//   - attention: S^T = K*Q^T (split 3-term); scalar fjS bias reads; softmax lane-local;
//     P -> per-wave LDS roundtrip (hi/lo) -> standard B-frag reads; O^T = V^T*P^T (3-term)
//   - LN1 + gate + top2 routing fp32; MoE FFN grouped bf16 MFMA; LN2 gather epilogue

#include <hip/hip_runtime.h>
#include <stdint.h>

typedef unsigned short u16;
typedef unsigned int   u32;

using bf16x8 = __attribute__((ext_vector_type(8))) short;
using f32x4  = __attribute__((ext_vector_type(4))) float;

#define N_T   1024
#define N_D   1024
#define N_E   8
#define N_BT  4096
#define LNEPS 1e-5f

// ---------------- helpers ----------------
__device__ __forceinline__ u32 rne2(float a, float b) {
  u32 ua = __float_as_uint(a); ua = (ua + 0x7fffu + ((ua >> 16) & 1u)) >> 16;
  u32 ub = __float_as_uint(b); ub = (ub + 0x7fffu + ((ub >> 16) & 1u)) >> 16;
  return ua | (ub << 16);
}
__device__ __forceinline__ u16 rne1(float a) {
  u32 ua = __float_as_uint(a);
  return (u16)((ua + 0x7fffu + ((ua >> 16) & 1u)) >> 16);
}
__device__ __forceinline__ float bfhi_f(float a) {   // nearest-bf16 value as fp32
  u32 ua = __float_as_uint(a);
  ua = (ua + 0x7fffu + ((ua >> 16) & 1u)) & 0xffff0000u;
  return __uint_as_float(ua);
}
__device__ __forceinline__ int swz(int row, int chunk) {
  return row * 32 + (((chunk ^ (row & 3) ^ ((row >> 2) & 3)) & 3) << 3);
}
__device__ __forceinline__ float wred(float v) {
  #pragma unroll
  for (int o2 = 32; o2 > 0; o2 >>= 1) v += __shfl_xor(v, o2, 64);
  return v;
}
__device__ __forceinline__ f32x4 mfma16(bf16x8 a, bf16x8 b, f32x4 c) {
  return __builtin_amdgcn_mfma_f32_16x16x32_bf16(a, b, c, 0, 0, 0);
}

// ---------------- transpose fp32 [R][C] -> bf16 [C][R] (optional hi/lo split) ----------------
template<int SPLIT>
__global__ __launch_bounds__(256)
void transpose_bf16(const float* __restrict__ in, u16* __restrict__ outh,
                    u16* __restrict__ outl, int R, int C)
{
  __shared__ u16 th[64][68];
  __shared__ u16 tl[SPLIT ? 64 : 1][SPLIT ? 68 : 1];
  const long long zb = (long long)blockIdx.z * R * C;
  const float* srcp = in + zb;
  const int r0 = blockIdx.y * 64, c0 = blockIdx.x * 64;
  const int t = threadIdx.x;
  {
    const int rr = t >> 4, cc = (t & 15) << 2;
    #pragma unroll
    for (int i = 0; i < 4; i++) {
      const int r = rr + i * 16;
      float4 v = *(const float4*)(srcp + (long long)(r0 + r) * C + c0 + cc);
      if constexpr (SPLIT) {
        float hx = bfhi_f(v.x), hy = bfhi_f(v.y), hz = bfhi_f(v.z), hw = bfhi_f(v.w);
        *(uint2*)&th[r][cc] = make_uint2(rne2(hx, hy), rne2(hz, hw));
        *(uint2*)&tl[r][cc] = make_uint2(rne2(v.x - hx, v.y - hy), rne2(v.z - hz, v.w - hw));
      } else {
        *(uint2*)&th[r][cc] = make_uint2(rne2(v.x, v.y), rne2(v.z, v.w));
      }
    }
  }
  __syncthreads();
  {
    const int c = t >> 2, rs = (t & 3) << 4;
    const long long ob = zb + (long long)(c0 + c) * R + r0 + rs;
    u32 w[8];
    #pragma unroll
    for (int i = 0; i < 8; i++)
      w[i] = (u32)th[rs + 2*i][c] | ((u32)th[rs + 2*i + 1][c] << 16);
    *(uint4*)(outh + ob)     = make_uint4(w[0], w[1], w[2], w[3]);
    *(uint4*)(outh + ob + 8) = make_uint4(w[4], w[5], w[6], w[7]);
    if constexpr (SPLIT) {
      #pragma unroll
      for (int i = 0; i < 8; i++)
        w[i] = (u32)tl[rs + 2*i][c] | ((u32)tl[rs + 2*i + 1][c] << 16);
      *(uint4*)(outl + ob)     = make_uint4(w[0], w[1], w[2], w[3]);
      *(uint4*)(outl + ob + 8) = make_uint4(w[4], w[5], w[6], w[7]);
    }
  }
}

// ---------------- V per-head transpose fp32 [kv][d] -> hi/lo bf16 [d][kv] ----------------
__global__ __launch_bounds__(256)
void vtrans_split(const float* __restrict__ V, u16* __restrict__ Vth, u16* __restrict__ Vtl)
{
  __shared__ u16 th[64][72];
  __shared__ u16 tl[64][72];
  const int bh = blockIdx.y, b = bh >> 4, h = bh & 15;
  const int kt = blockIdx.x, tid = threadIdx.x;
  {
    const int sr = tid >> 2, scb = (tid & 3) << 4;   // kv row, d col base
    const float4* vp = (const float4*)(V + (long long)(b * N_T + kt * 64 + sr) * N_D + h * 64 + scb);
    float4 f0 = vp[0], f1 = vp[1], f2 = vp[2], f3 = vp[3];
    float a[16] = {f0.x, f0.y, f0.z, f0.w, f1.x, f1.y, f1.z, f1.w,
                   f2.x, f2.y, f2.z, f2.w, f3.x, f3.y, f3.z, f3.w};
    u16 hh[16], ll[16];
    #pragma unroll
    for (int i = 0; i < 16; i++) {
      float hi = bfhi_f(a[i]);
      hh[i] = (u16)(__float_as_uint(hi) >> 16);
      ll[i] = rne1(a[i] - hi);
    }
    #pragma unroll
    for (int j = 0; j < 2; j++) {
      *(uint4*)&th[sr][scb + j * 8] =
          make_uint4((u32)hh[j*8+0] | ((u32)hh[j*8+1] << 16), (u32)hh[j*8+2] | ((u32)hh[j*8+3] << 16),
                     (u32)hh[j*8+4] | ((u32)hh[j*8+5] << 16), (u32)hh[j*8+6] | ((u32)hh[j*8+7] << 16));
      *(uint4*)&tl[sr][scb + j * 8] =
          make_uint4((u32)ll[j*8+0] | ((u32)ll[j*8+1] << 16), (u32)ll[j*8+2] | ((u32)ll[j*8+3] << 16),
                     (u32)ll[j*8+4] | ((u32)ll[j*8+5] << 16), (u32)ll[j*8+6] | ((u32)ll[j*8+7] << 16));
    }
  }
  __syncthreads();
  {
    const int od = tid >> 2, os0 = (tid & 3) << 4;   // d row, kv col base
    u16 wh[16], wl[16];
    #pragma unroll
    for (int i = 0; i < 16; i++) { wh[i] = th[os0 + i][od]; wl[i] = tl[os0 + i][od]; }
    u16* oph = Vth + (long long)(bh * 64 + od) * N_T + kt * 64 + os0;
    u16* opl = Vtl + (long long)(bh * 64 + od) * N_T + kt * 64 + os0;
    *(uint4*)oph = make_uint4((u32)wh[0] | ((u32)wh[1] << 16), (u32)wh[2] | ((u32)wh[3] << 16),
                              (u32)wh[4] | ((u32)wh[5] << 16), (u32)wh[6] | ((u32)wh[7] << 16));
    *(uint4*)(oph + 8) = make_uint4((u32)wh[8] | ((u32)wh[9] << 16), (u32)wh[10] | ((u32)wh[11] << 16),
                                    (u32)wh[12] | ((u32)wh[13] << 16), (u32)wh[14] | ((u32)wh[15] << 16));
    *(uint4*)opl = make_uint4((u32)wl[0] | ((u32)wl[1] << 16), (u32)wl[2] | ((u32)wl[3] << 16),
                              (u32)wl[4] | ((u32)wl[5] << 16), (u32)wl[6] | ((u32)wl[7] << 16));
    *(uint4*)(opl + 8) = make_uint4((u32)wl[8] | ((u32)wl[9] << 16), (u32)wl[10] | ((u32)wl[11] << 16),
                                    (u32)wl[12] | ((u32)wl[13] << 16), (u32)wl[14] | ((u32)wl[15] << 16));
  }
}

// ---------------- 128x128x32 MFMA GEMM (4 waves, 4x4 16x16 frags each) ----------------
// OBF: 0 = fp32 out, 1 = bf16 out, 2 = split hi/lo bf16 out (Cp, Cp2) with cscale folded.
template<int SPLIT, int ABF, int GATHER, int DORELU, int DOSCALE, int OBF, int GROUPED>
__global__ __launch_bounds__(256, 2)
void gemm128(const void* __restrict__ Ap, int lda,
             const u16* __restrict__ Bhp, const u16* __restrict__ Blp,
             long long bstride,
             void* __restrict__ Cp, int ldc,
             const float* __restrict__ biasp, int bias_stride,
             const float* __restrict__ slot_wp,
             const int* __restrict__ tokidx,
             const int2* __restrict__ tilesp, const int* __restrict__ ntilesp,
             int Ksz, void* __restrict__ Cp2, float cscale)
{
  int e = 0, row0;
  if constexpr (GROUPED) {
    if ((int)blockIdx.x >= *ntilesp) return;
    const int2 dsc = tilesp[blockIdx.x];
    e = dsc.x; row0 = dsc.y;
  } else {
    row0 = blockIdx.x * 128;
  }
  const int col0 = blockIdx.y * 128;

  __shared__ __align__(16) u16 AhS[128 * 32];
  __shared__ __align__(16) u16 BhS[128 * 32];
  __shared__ __align__(16) u16 AlS[SPLIT ? 128 * 32 : 8];
  __shared__ __align__(16) u16 BlS[SPLIT ? 128 * 32 : 8];

  const int tid = threadIdx.x;
  const int rr = tid >> 1;
  const int c2 = (tid & 1) << 1;

  long long arow;
  if constexpr (GATHER) arow = tokidx[row0 + rr];
  else                  arow = row0 + rr;
  const char* Arow = (const char*)Ap + arow * (long long)lda * (ABF ? 2 : 4);
  const u16* Bhrow = Bhp + (long long)e * bstride + (long long)(col0 + rr) * Ksz;
  const u16* Blrow = nullptr;
  if constexpr (SPLIT) Blrow = Blp + (long long)e * bstride + (long long)(col0 + rr) * Ksz;
  const float* bias = biasp + (long long)e * bias_stride + col0;

  const int wid = tid >> 6, lane = tid & 63;
  const int wm = (wid >> 1) << 6, wn = (wid & 1) << 6;
  const int l15 = lane & 15, l4 = lane >> 4;

  f32x4 acc[4][4] = {};

  uint4 sah0, sah1, sal0, sal1, sbh0, sbh1, sbl0, sbl1;

  auto gload = [&](int k0) {
    if constexpr (ABF) {
      const uint4* ap = (const uint4*)(Arow + (long long)(k0 + c2 * 8) * 2);
      sah0 = ap[0]; sah1 = ap[1];
    } else {
      const float4* ap = (const float4*)(Arow + (long long)(k0 + c2 * 8) * 4);
      float4 f0 = ap[0], f1 = ap[1], f2 = ap[2], f3 = ap[3];
      if constexpr (SPLIT) {
        float h0 = bfhi_f(f0.x), h1 = bfhi_f(f0.y), h2 = bfhi_f(f0.z), h3 = bfhi_f(f0.w);
        float h4 = bfhi_f(f1.x), h5 = bfhi_f(f1.y), h6 = bfhi_f(f1.z), h7 = bfhi_f(f1.w);
        sah0 = make_uint4(rne2(h0, h1), rne2(h2, h3), rne2(h4, h5), rne2(h6, h7));
        sal0 = make_uint4(rne2(f0.x - h0, f0.y - h1), rne2(f0.z - h2, f0.w - h3),
                          rne2(f1.x - h4, f1.y - h5), rne2(f1.z - h6, f1.w - h7));
        h0 = bfhi_f(f2.x); h1 = bfhi_f(f2.y); h2 = bfhi_f(f2.z); h3 = bfhi_f(f2.w);
        h4 = bfhi_f(f3.x); h5 = bfhi_f(f3.y); h6 = bfhi_f(f3.z); h7 = bfhi_f(f3.w);
        sah1 = make_uint4(rne2(h0, h1), rne2(h2, h3), rne2(h4, h5), rne2(h6, h7));
        sal1 = make_uint4(rne2(f2.x - h0, f2.y - h1), rne2(f2.z - h2, f2.w - h3),
                          rne2(f3.x - h4, f3.y - h5), rne2(f3.z - h6, f3.w - h7));
      } else {
        sah0 = make_uint4(rne2(f0.x, f0.y), rne2(f0.z, f0.w), rne2(f1.x, f1.y), rne2(f1.z, f1.w));
        sah1 = make_uint4(rne2(f2.x, f2.y), rne2(f2.z, f2.w), rne2(f3.x, f3.y), rne2(f3.z, f3.w));
      }
    }
    {
      const uint4* bp = (const uint4*)(Bhrow + k0 + c2 * 8);
      sbh0 = bp[0]; sbh1 = bp[1];
    }
    if constexpr (SPLIT) {
      const uint4* bp = (const uint4*)(Blrow + k0 + c2 * 8);
      sbl0 = bp[0]; sbl1 = bp[1];
    }
  };

  gload(0);
  const int nk = Ksz >> 5;
  for (int kt = 0; kt < nk; kt++) {
    __syncthreads();
    *(uint4*)&AhS[swz(rr, c2)]     = sah0;
    *(uint4*)&AhS[swz(rr, c2 + 1)] = sah1;
    *(uint4*)&BhS[swz(rr, c2)]     = sbh0;
    *(uint4*)&BhS[swz(rr, c2 + 1)] = sbh1;
    if constexpr (SPLIT) {
      *(uint4*)&AlS[swz(rr, c2)]     = sal0;
      *(uint4*)&AlS[swz(rr, c2 + 1)] = sal1;
      *(uint4*)&BlS[swz(rr, c2)]     = sbl0;
      *(uint4*)&BlS[swz(rr, c2 + 1)] = sbl1;
    }
    __syncthreads();
    if (kt + 1 < nk) gload((kt + 1) << 5);

    bf16x8 ah[4], bh[4], al[SPLIT ? 4 : 1], bl[SPLIT ? 4 : 1];
    #pragma unroll
    for (int i = 0; i < 4; i++) {
      const int ar = wm + i * 16 + l15;
      const int br = wn + i * 16 + l15;
      ah[i] = *(const bf16x8*)&AhS[swz(ar, l4)];
      bh[i] = *(const bf16x8*)&BhS[swz(br, l4)];
      if constexpr (SPLIT) {
        al[i] = *(const bf16x8*)&AlS[swz(ar, l4)];
        bl[i] = *(const bf16x8*)&BlS[swz(br, l4)];
      }
    }
    #pragma unroll
    for (int i = 0; i < 4; i++) {
      #pragma unroll
      for (int j = 0; j < 4; j++) {
        acc[i][j] = mfma16(ah[i], bh[j], acc[i][j]);
        if constexpr (SPLIT) {
          acc[i][j] = mfma16(ah[i], bl[j], acc[i][j]);
          acc[i][j] = mfma16(al[i], bh[j], acc[i][j]);
          acc[i][j] = mfma16(al[i], bl[j], acc[i][j]);
        }
      }
    }
  }

  #pragma unroll
  for (int i = 0; i < 4; i++) {
    #pragma unroll
    for (int j = 0; j < 4; j++) {
      const int orow0 = row0 + wm + i * 16 + (l4 << 2);
      const int ocol  = col0 + wn + j * 16 + l15;
      const float bv = bias[wn + j * 16 + l15];
      #pragma unroll
      for (int q = 0; q < 4; q++) {
        float v = acc[i][j][q] + bv;
        if constexpr (DORELU) v = fmaxf(v, 0.f);
        const long long orow = orow0 + q;
        if constexpr (DOSCALE) v *= slot_wp[orow];
        if constexpr (OBF == 2) {
          const float vs = v * cscale;
          const float hi = bfhi_f(vs);
          ((u16*)Cp )[orow * ldc + ocol] = (u16)(__float_as_uint(hi) >> 16);
          ((u16*)Cp2)[orow * ldc + ocol] = rne1(vs - hi);
        } else if constexpr (OBF == 1) {
          ((u16*)Cp)[orow * ldc + ocol] = rne1(v);
        } else {
          ((float*)Cp)[orow * ldc + ocol] = v;
        }
      }
    }
  }
}

// ---------------- MFMA flash attention with stoichiometric bias ----------------
// grid (B*H=64, T/128=8), block 256 (4 waves); wave handles 32 q rows.
// S^T = K*Q^T (hi/lo split, 3 terms). Softmax lane-local (q = lane&15).
// P written to per-wave LDS as P[q][kv] (hi then lo) via the verified C-write
// mapping, re-read as standard B-operand frags (linear kv columns — no k-slot
// order assumptions). O^T = V^T*P^T with plain-transposed V^T (hi/lo, 3 terms).
__global__ __launch_bounds__(256, 2)
void attn_mfma(const u16* __restrict__ Qh, const u16* __restrict__ Ql,
               const u16* __restrict__ Kh, const u16* __restrict__ Kl,
               const u16* __restrict__ Vth, const u16* __restrict__ Vtl,
               const float* __restrict__ frac,
               const float* __restrict__ apos, const float* __restrict__ aneg,
               float* __restrict__ ctx)
{
  __shared__ __align__(16) u16 KhS[64 * 64];   // [kv][d], chunk^(kv&7) swizzle
  __shared__ __align__(16) u16 KlS[64 * 64];
  __shared__ __align__(16) u16 VhS[64 * 64];   // [d][kv], same swizzle
  __shared__ __align__(16) u16 VlS[64 * 64];
  __shared__ __align__(16) u16 PS[4][32][72];  // per-wave P[q][kv], +8 pad
  __shared__ __align__(16) float fjS[64];

  const int bh = blockIdx.x, b = bh >> 4, h = bh & 15;
  const int tid = threadIdx.x, wid = tid >> 6, lane = tid & 63;
  const int l15 = lane & 15, l4 = lane >> 4;
  const int q0 = blockIdx.y * 128 + wid * 32;

  // Q fragments (B-operand: n = q = l15, k-chunk = l4), pre-scaled & pre-split
  bf16x8 qh[2][2], ql[2][2];
  #pragma unroll
  for (int ni = 0; ni < 2; ni++) {
    const long long qoff = (long long)(b * N_T + q0 + ni * 16 + l15) * N_D + h * 64 + l4 * 8;
    #pragma unroll
    for (int ks = 0; ks < 2; ks++) {
      qh[ni][ks] = *(const bf16x8*)(Qh + qoff + ks * 32);
      ql[ni][ks] = *(const bf16x8*)(Ql + qoff + ks * 32);
    }
  }
  float fq[2];
  #pragma unroll
  for (int ni = 0; ni < 2; ni++) fq[ni] = frac[b * N_T + q0 + ni * 16 + l15];
  const float ap = apos[h], an = aneg[h];

  f32x4 acc[4][2] = {};                 // O^T: d = md*16+l4*4+reg, q = nq*16+l15
  float mrun[2] = {-3.0e38f, -3.0e38f}, lrun[2] = {0.f, 0.f};

  const int sr = tid >> 2, scb = (tid & 3) << 4;
  const int ch0 = ((scb >> 3) ^ (sr & 7)) << 3;
  const int ch1 = (((scb >> 3) + 1) ^ (sr & 7)) << 3;

  for (int kt = 0; kt < 16; kt++) {
    __syncthreads();
    {
      const long long koff = (long long)(b * N_T + kt * 64 + sr) * N_D + h * 64 + scb;
      const uint4* khp = (const uint4*)(Kh + koff);
      const uint4* klp = (const uint4*)(Kl + koff);
      const long long voff = (long long)(bh * 64 + sr) * N_T + kt * 64 + scb;
      const uint4* vhp = (const uint4*)(Vth + voff);
      const uint4* vlp = (const uint4*)(Vtl + voff);
      *(uint4*)&KhS[sr * 64 + ch0] = khp[0];
      *(uint4*)&KhS[sr * 64 + ch1] = khp[1];
      *(uint4*)&KlS[sr * 64 + ch0] = klp[0];
      *(uint4*)&KlS[sr * 64 + ch1] = klp[1];
      *(uint4*)&VhS[sr * 64 + ch0] = vhp[0];
      *(uint4*)&VhS[sr * 64 + ch1] = vhp[1];
      *(uint4*)&VlS[sr * 64 + ch0] = vlp[0];
      *(uint4*)&VlS[sr * 64 + ch1] = vlp[1];
    }
    if (tid < 64) fjS[tid] = frac[b * N_T + kt * 64 + tid];
    __syncthreads();

    // ---- S^T = K * Q^T (3-term split)
    f32x4 s[4][2] = {};
    #pragma unroll
    for (int ks = 0; ks < 2; ks++) {
      bf16x8 kh[4], kl[4];
      #pragma unroll
      for (int mj = 0; mj < 4; mj++) {
        const int row = mj * 16 + l15;
        const int ch = (((ks << 2) + l4) ^ (row & 7)) << 3;
        kh[mj] = *(const bf16x8*)&KhS[row * 64 + ch];
        kl[mj] = *(const bf16x8*)&KlS[row * 64 + ch];
      }
      #pragma unroll
      for (int mj = 0; mj < 4; mj++) {
        #pragma unroll
        for (int ni = 0; ni < 2; ni++) {
          s[mj][ni] = mfma16(kh[mj], qh[ni][ks], s[mj][ni]);
          s[mj][ni] = mfma16(kh[mj], ql[ni][ks], s[mj][ni]);
          s[mj][ni] = mfma16(kl[mj], qh[ni][ks], s[mj][ni]);
        }
      }
    }

    // ---- bias (scalar fjS reads) ; kv = mj*16 + l4*4 + r, q = ni*16 + l15
    #pragma unroll
    for (int mj = 0; mj < 4; mj++) {
      const int kvb = mj * 16 + l4 * 4;
      const float f0 = fjS[kvb], f1 = fjS[kvb + 1], f2 = fjS[kvb + 2], f3 = fjS[kvb + 3];
      #pragma unroll
      for (int ni = 0; ni < 2; ni++) {
        float d0 = f0 - fq[ni], d1 = f1 - fq[ni], d2 = f2 - fq[ni], d3 = f3 - fq[ni];
        s[mj][ni][0] += (d0 > 0.f ? ap : an) * d0;
        s[mj][ni][1] += (d1 > 0.f ? ap : an) * d1;
        s[mj][ni][2] += (d2 > 0.f ? ap : an) * d2;
        s[mj][ni][3] += (d3 > 0.f ? ap : an) * d3;
      }
    }

    // ---- online softmax
    #pragma unroll
    for (int ni = 0; ni < 2; ni++) {
      float tm = s[0][ni][0];
      #pragma unroll
      for (int mj = 0; mj < 4; mj++) {
        tm = fmaxf(tm, fmaxf(fmaxf(s[mj][ni][0], s[mj][ni][1]),
                             fmaxf(s[mj][ni][2], s[mj][ni][3])));
      }
      tm = fmaxf(tm, __shfl_xor(tm, 16, 64));
      tm = fmaxf(tm, __shfl_xor(tm, 32, 64));
      const float nm = fmaxf(mrun[ni], tm);
      const float cor = __expf(mrun[ni] - nm);
      mrun[ni] = nm;
      lrun[ni] *= cor;
      #pragma unroll
      for (int md = 0; md < 4; md++) {
        acc[md][ni][0] *= cor; acc[md][ni][1] *= cor;
        acc[md][ni][2] *= cor; acc[md][ni][3] *= cor;
      }
      float rsum = 0.f;
      #pragma unroll
      for (int mj = 0; mj < 4; mj++) {
        #pragma unroll
        for (int r = 0; r < 4; r++) {
          const float p = __expf(s[mj][ni][r] - nm);
          s[mj][ni][r] = p;
          rsum += p;
        }
      }
      rsum += __shfl_xor(rsum, 16, 64);
      rsum += __shfl_xor(rsum, 32, 64);
      lrun[ni] += rsum;
    }

    // ---- P hi -> per-wave LDS (C-write-verified mapping), read B-frags
    #pragma unroll
    for (int ni = 0; ni < 2; ni++) {
      #pragma unroll
      for (int mj = 0; mj < 4; mj++) {
        float h0 = bfhi_f(s[mj][ni][0]), h1 = bfhi_f(s[mj][ni][1]);
        float h2 = bfhi_f(s[mj][ni][2]), h3 = bfhi_f(s[mj][ni][3]);
        u32* dst = (u32*)&PS[wid][ni * 16 + l15][mj * 16 + l4 * 4];
        dst[0] = rne2(h0, h1); dst[1] = rne2(h2, h3);
      }
    }
    bf16x8 pbh[2][2];
    #pragma unroll
    for (int ni = 0; ni < 2; ni++)
      #pragma unroll
      for (int ks = 0; ks < 2; ks++)
        pbh[ni][ks] = *(const bf16x8*)&PS[wid][ni * 16 + l15][ks * 32 + l4 * 8];

    // ---- P lo -> same LDS buffer, read B-frags
    #pragma unroll
    for (int ni = 0; ni < 2; ni++) {
      #pragma unroll
      for (int mj = 0; mj < 4; mj++) {
        float p0 = s[mj][ni][0], p1 = s[mj][ni][1], p2 = s[mj][ni][2], p3 = s[mj][ni][3];
        float h0 = bfhi_f(p0), h1 = bfhi_f(p1), h2 = bfhi_f(p2), h3 = bfhi_f(p3);
        u32* dst = (u32*)&PS[wid][ni * 16 + l15][mj * 16 + l4 * 4];
        dst[0] = rne2(p0 - h0, p1 - h1); dst[1] = rne2(p2 - h2, p3 - h3);
      }
    }
    bf16x8 pbl[2][2];
    #pragma unroll
    for (int ni = 0; ni < 2; ni++)
      #pragma unroll
      for (int ks = 0; ks < 2; ks++)
        pbl[ni][ks] = *(const bf16x8*)&PS[wid][ni * 16 + l15][ks * 32 + l4 * 8];

    // ---- O^T += V^T * P^T (3-term split; linear kv pairing)
    #pragma unroll
    for (int md = 0; md < 4; md++) {
      #pragma unroll
      for (int ks = 0; ks < 2; ks++) {
        const int row = md * 16 + l15;
        const int ch = (((ks << 2) + l4) ^ (row & 7)) << 3;
        const bf16x8 vh = *(const bf16x8*)&VhS[row * 64 + ch];
        const bf16x8 vl = *(const bf16x8*)&VlS[row * 64 + ch];
        #pragma unroll
        for (int nq = 0; nq < 2; nq++) {
          acc[md][nq] = mfma16(vh, pbh[nq][ks], acc[md][nq]);
          acc[md][nq] = mfma16(vh, pbl[nq][ks], acc[md][nq]);
          acc[md][nq] = mfma16(vl, pbh[nq][ks], acc[md][nq]);
        }
      }
    }
  }

  // ---- epilogue: ctx[q][d] = O^T[d][q] / l[q]
  const float inv[2] = {1.f / lrun[0], 1.f / lrun[1]};
  #pragma unroll
  for (int nq = 0; nq < 2; nq++) {
    #pragma unroll
    for (int md = 0; md < 4; md++) {
      float4 o;
      o.x = acc[md][nq][0] * inv[nq];
      o.y = acc[md][nq][1] * inv[nq];
      o.z = acc[md][nq][2] * inv[nq];
      o.w = acc[md][nq][3] * inv[nq];
      *(float4*)(ctx + (long long)(b * N_T + q0 + nq * 16 + l15) * N_D +
                 h * 64 + md * 16 + l4 * 4) = o;
    }
  }
}

// ---------------- LN1 + gate softmax + top2 (wave per token) ----------------
__global__ __launch_bounds__(256, 4)
void ln1_gate(const float* __restrict__ src, const float* __restrict__ attnout,
              const float* __restrict__ g, const float* __restrict__ bb,
              const float* __restrict__ gateW, const float* __restrict__ gateb,
              float* __restrict__ xout, int* __restrict__ counts,
              int2* __restrict__ tok_top, float2* __restrict__ tok_w)
{
  const int wid = threadIdx.x >> 6, lane = threadIdx.x & 63;
  const int t = blockIdx.x * 4 + wid;
  const float4* s4 = (const float4*)(src + (long long)t * N_D);
  const float4* a4 = (const float4*)(attnout + (long long)t * N_D);
  float4 v[4];
  float sum = 0.f;
  #pragma unroll
  for (int c = 0; c < 4; c++) {
    const int idx = c * 64 + lane;
    float4 a = s4[idx], b2 = a4[idx];
    v[c] = make_float4(a.x + b2.x, a.y + b2.y, a.z + b2.z, a.w + b2.w);
    sum += v[c].x + v[c].y + v[c].z + v[c].w;
  }
  sum = wred(sum);
  const float mu = sum * (1.f / 1024.f);
  float s2 = 0.f;
  #pragma unroll
  for (int c = 0; c < 4; c++) {
    float dx = v[c].x - mu, dy = v[c].y - mu, dz = v[c].z - mu, dw = v[c].w - mu;
    s2 += dx * dx + dy * dy + dz * dz + dw * dw;
  }
  s2 = wred(s2);
  const float rs = rsqrtf(s2 * (1.f / 1024.f) + LNEPS);
  float acc[8];
  #pragma unroll
  for (int e2 = 0; e2 < 8; e2++) acc[e2] = 0.f;
  #pragma unroll
  for (int c = 0; c < 4; c++) {
    const int idx = c * 64 + lane;
    float4 gv = ((const float4*)g)[idx], bv = ((const float4*)bb)[idx];
    float xa[4];
    xa[0] = (v[c].x - mu) * rs * gv.x + bv.x;
    xa[1] = (v[c].y - mu) * rs * gv.y + bv.y;
    xa[2] = (v[c].z - mu) * rs * gv.z + bv.z;
    xa[3] = (v[c].w - mu) * rs * gv.w + bv.w;
    ((float4*)(xout + (long long)t * N_D))[idx] = make_float4(xa[0], xa[1], xa[2], xa[3]);
    #pragma unroll
    for (int ii = 0; ii < 4; ii++) {
      const float xs = xa[ii];
      const float4* gw = (const float4*)(gateW + ((long long)(idx * 4 + ii)) * N_E);
      float4 w0 = gw[0], w1 = gw[1];
      acc[0] += xs * w0.x; acc[1] += xs * w0.y; acc[2] += xs * w0.z; acc[3] += xs * w0.w;
      acc[4] += xs * w1.x; acc[5] += xs * w1.y; acc[6] += xs * w1.z; acc[7] += xs * w1.w;
    }
  }
  #pragma unroll
  for (int e2 = 0; e2 < 8; e2++) acc[e2] = wred(acc[e2]);
  if (lane == 0) {
    float lg[8];
    #pragma unroll
    for (int e2 = 0; e2 < 8; e2++) lg[e2] = acc[e2] + gateb[e2];
    float mx = lg[0];
    #pragma unroll
    for (int e2 = 1; e2 < 8; e2++) mx = fmaxf(mx, lg[e2]);
    float Z = 0.f;
    #pragma unroll
    for (int e2 = 0; e2 < 8; e2++) Z += __expf(lg[e2] - mx);
    int e0 = 0; float v0 = lg[0];
    #pragma unroll
    for (int e2 = 1; e2 < 8; e2++) if (lg[e2] > v0) { v0 = lg[e2]; e0 = e2; }
    int e1 = -1; float v1 = -3.4e38f;
    #pragma unroll
    for (int e2 = 0; e2 < 8; e2++) if (e2 != e0 && lg[e2] > v1) { v1 = lg[e2]; e1 = e2; }
    atomicAdd(&counts[e0], 1);
    atomicAdd(&counts[e1], 1);
    tok_top[t] = make_int2(e0, e1);
    tok_w[t] = make_float2(__expf(v0 - mx) / Z, __expf(v1 - mx) / Z);
  }
}

// ---------------- routing: offsets, tile descriptors, padding fill ----------------
__global__ void route_build(const int* __restrict__ counts, int* __restrict__ offsets,
                            int* __restrict__ cursors, int* __restrict__ ntiles,
                            int2* __restrict__ tiles, int* __restrict__ token_idx,
                            float* __restrict__ slot_w)
{
  __shared__ int soff[N_E + 1];
  __shared__ int scnt[N_E];
  if (threadIdx.x == 0) {
    int off = 0, nt = 0;
    for (int ex = 0; ex < N_E; ex++) {
      soff[ex] = off; offsets[ex] = off; cursors[ex] = 0;
      const int cnt = counts[ex];
      scnt[ex] = cnt;
      const int pt = (cnt + 127) >> 7;
      for (int i = 0; i < pt; i++) { tiles[nt] = make_int2(ex, off + i * 128); nt++; }
      off += pt << 7;
    }
    soff[N_E] = off; offsets[N_E] = off;
    *ntiles = nt;
  }
  __syncthreads();
  for (int ex = 0; ex < N_E; ex++)
    for (int s = soff[ex] + scnt[ex] + (int)threadIdx.x; s < soff[ex + 1]; s += (int)blockDim.x) {
      token_idx[s] = 0; slot_w[s] = 0.f;
    }
}

__global__ __launch_bounds__(256)
void route_scatter(const int2* __restrict__ tok_top, const float2* __restrict__ tok_w,
                   const int* __restrict__ offsets, int* __restrict__ cursors,
                   int* __restrict__ token_idx, float* __restrict__ slot_w,
                   int* __restrict__ slotA, int* __restrict__ slotB)
{
  const int t = blockIdx.x * 256 + threadIdx.x;
  if (t >= N_BT) return;
  const int2 ee = tok_top[t];
  const float2 ww = tok_w[t];
  int p = atomicAdd(&cursors[ee.x], 1);
  int s = offsets[ee.x] + p;
  token_idx[s] = t; slot_w[s] = ww.x; slotA[t] = s;
  p = atomicAdd(&cursors[ee.y], 1);
  s = offsets[ee.y] + p;
  token_idx[s] = t; slot_w[s] = ww.y; slotB[t] = s;
}

// ---------------- final: y = LN2(x + out2[sA] + out2[sB]) ----------------
__global__ __launch_bounds__(256, 4)
void final_ln2(const float* __restrict__ x, const float* __restrict__ out2,
               const int* __restrict__ slotA, const int* __restrict__ slotB,
               const float* __restrict__ g, const float* __restrict__ bb,
               float* __restrict__ out)
{
  const int wid = threadIdx.x >> 6, lane = threadIdx.x & 63;
  const int t = blockIdx.x * 4 + wid;
  const int sA = slotA[t], sB = slotB[t];
  const float4* xr = (const float4*)(x + (long long)t * N_D);
  const float4* pa = (const float4*)(out2 + (long long)sA * N_D);
  const float4* pb = (const float4*)(out2 + (long long)sB * N_D);
  float4 v[4];
  float sum = 0.f;
  #pragma unroll
  for (int c = 0; c < 4; c++) {
    const int idx = c * 64 + lane;
    float4 a = xr[idx], b2 = pa[idx], c2 = pb[idx];
    v[c] = make_float4(a.x + b2.x + c2.x, a.y + b2.y + c2.y,
                       a.z + b2.z + c2.z, a.w + b2.w + c2.w);
    sum += v[c].x + v[c].y + v[c].z + v[c].w;
  }
  sum = wred(sum);
  const float mu = sum * (1.f / 1024.f);
  float s2 = 0.f;
  #pragma unroll
  for (int c = 0; c < 4; c++) {
    float dx = v[c].x - mu, dy = v[c].y - mu, dz = v[c].z - mu, dw = v[c].w - mu;
    s2 += dx * dx + dy * dy + dz * dz + dw * dw;
  }
  s2 = wred(s2);
  const float rs = rsqrtf(s2 * (1.f / 1024.f) + LNEPS);
  #pragma unroll
  for (int c = 0; c < 4; c++) {
    const int idx = c * 64 + lane;
    float4 gv = ((const float4*)g)[idx], bv = ((const float4*)bb)[idx];
    float4 o;
    o.x = (v[c].x - mu) * rs * gv.x + bv.x;
    o.y = (v[c].y - mu) * rs * gv.y + bv.y;
    o.z = (v[c].z - mu) * rs * gv.z + bv.z;
    o.w = (v[c].w - mu) * rs * gv.w + bv.w;
    ((float4*)(out + (long long)t * N_D))[idx] = o;
  }
}

// ---------------- launch ----------------
extern "C" void kernel_launch(void* const* d_in, const int* in_sizes, int n_in,
                              void* d_out, int out_size, void* d_ws, size_t ws_size,
                              hipStream_t stream)
{
  const float* src   = (const float*)d_in[0];
  const float* frac  = (const float*)d_in[1];
  const float* Wq    = (const float*)d_in[2];
  const float* bq    = (const float*)d_in[3];
  const float* Wk    = (const float*)d_in[4];
  const float* bk    = (const float*)d_in[5];
  const float* Wv    = (const float*)d_in[6];
  const float* bv    = (const float*)d_in[7];
  const float* Wo    = (const float*)d_in[8];
  const float* bo    = (const float*)d_in[9];
  const float* apos  = (const float*)d_in[10];
  const float* aneg  = (const float*)d_in[11];
  const float* gateW = (const float*)d_in[12];
  const float* gateb = (const float*)d_in[13];
  const float* W1    = (const float*)d_in[14];
  const float* b1    = (const float*)d_in[15];
  const float* W2    = (const float*)d_in[16];
  const float* b2    = (const float*)d_in[17];
  const float* ln1g  = (const float*)d_in[18];
  const float* ln1b  = (const float*)d_in[19];
  const float* ln2g  = (const float*)d_in[20];
  const float* ln2b  = (const float*)d_in[21];
  float* out = (float*)d_out;

  char* ws = (char*)d_ws;
  const size_t MB = 1ull << 20;
  // 0-16 MB: weight transposes (dead after Wo GEMM; misc routing block aliases ws+0 after)
  u16* WqTh = (u16*)(ws + 0 * MB);   u16* WqTl = (u16*)(ws + 2 * MB);
  u16* WkTh = (u16*)(ws + 4 * MB);   u16* WkTl = (u16*)(ws + 6 * MB);
  u16* WvTh = (u16*)(ws + 8 * MB);   u16* WvTl = (u16*)(ws + 10 * MB);
  u16* WoTh = (u16*)(ws + 12 * MB);  u16* WoTl = (u16*)(ws + 14 * MB);
  u16*   W1T  = (u16*)(ws + 16 * MB);    // 64 MB, dead after FFN GEMM1
  float* out2 = (float*)(ws + 16 * MB);  // <=38 MB, alias (written after W1T dead)
  u16*   W2T  = (u16*)(ws + 80 * MB);    // 64 MB
  u16*   Qhb  = (u16*)(ws + 144 * MB);   // 8 MB each (bf16 hi/lo)
  u16*   Qlb  = (u16*)(ws + 152 * MB);
  u16*   Khb  = (u16*)(ws + 160 * MB);
  u16*   Klb  = (u16*)(ws + 168 * MB);
  float* Vb   = (float*)(ws + 176 * MB); // 16 MB fp32 (dead after vtrans)
  float* attnb= (float*)(ws + 176 * MB); // alias: written by Wo GEMM after attn
  u16*   Vth  = (u16*)(ws + 192 * MB);   // 8 MB per-head V^T hi
  u16*   Vtl  = (u16*)(ws + 200 * MB);   // 8 MB per-head V^T lo
  float* ctxb = (float*)(ws + 208 * MB); // 16 MB
  u16*   hb   = (u16*)(ws + 144 * MB);   // <=72 MB alias (Qhb..ctxb dead by FFN)
  float* xb   = (float*)(ws + 224 * MB); // 16 MB -> total 240 MB
  char* misc = ws + 0;                   // aliases W-transpose region (dead by then)
  int*    counts    = (int*)(misc);
  int*    cursors   = (int*)(misc + 64);
  int*    offsets   = (int*)(misc + 128);
  int*    ntiles    = (int*)(misc + 256);
  int2*   tiles     = (int2*)(misc + 512);
  int2*   tok_top   = (int2*)(misc + 2048);
  float2* tok_w     = (float2*)(misc + 2048 + 32768);
  int*    token_idx = (int*)(misc + 2048 + 65536);
  float*  slot_w    = (float*)(misc + 2048 + 65536 + 36864);
  int*    slotA     = (int*)(misc + 2048 + 65536 + 73728);
  int*    slotB     = (int*)(misc + 2048 + 65536 + 73728 + 16384);

  dim3 b256(256);
  transpose_bf16<1><<<dim3(16, 16, 1), b256, 0, stream>>>(Wq, WqTh, WqTl, 1024, 1024);
  transpose_bf16<1><<<dim3(16, 16, 1), b256, 0, stream>>>(Wk, WkTh, WkTl, 1024, 1024);
  transpose_bf16<1><<<dim3(16, 16, 1), b256, 0, stream>>>(Wv, WvTh, WvTl, 1024, 1024);
  transpose_bf16<1><<<dim3(16, 16, 1), b256, 0, stream>>>(Wo, WoTh, WoTl, 1024, 1024);
  transpose_bf16<0><<<dim3(64, 16, 8), b256, 0, stream>>>(W1, W1T, nullptr, 1024, 4096);
  transpose_bf16<0><<<dim3(16, 64, 8), b256, 0, stream>>>(W2, W2T, nullptr, 4096, 1024);

  // QKV projections: Q,K -> split bf16 (Q pre-scaled by 1/8); V -> fp32
  gemm128<1, 0, 0, 0, 0, 2, 0><<<dim3(32, 8), b256, 0, stream>>>(
      src, 1024, WqTh, WqTl, 0, Qhb, 1024, bq, 0, nullptr, nullptr, nullptr, nullptr,
      1024, Qlb, 0.125f);
  gemm128<1, 0, 0, 0, 0, 2, 0><<<dim3(32, 8), b256, 0, stream>>>(
      src, 1024, WkTh, WkTl, 0, Khb, 1024, bk, 0, nullptr, nullptr, nullptr, nullptr,
      1024, Klb, 1.0f);
  gemm128<1, 0, 0, 0, 0, 0, 0><<<dim3(32, 8), b256, 0, stream>>>(
      src, 1024, WvTh, WvTl, 0, Vb, 1024, bv, 0, nullptr, nullptr, nullptr, nullptr,
      1024, nullptr, 1.0f);

  vtrans_split<<<dim3(16, 64), b256, 0, stream>>>(Vb, Vth, Vtl);

  attn_mfma<<<dim3(64, 8), b256, 0, stream>>>(Qhb, Qlb, Khb, Klb, Vth, Vtl,
                                              frac, apos, aneg, ctxb);

  gemm128<1, 0, 0, 0, 0, 0, 0><<<dim3(32, 8), b256, 0, stream>>>(
      ctxb, 1024, WoTh, WoTl, 0, attnb, 1024, bo, 0, nullptr, nullptr, nullptr, nullptr,
      1024, nullptr, 1.0f);

  hipMemsetAsync(counts, 0, 32, stream);   // after Wo GEMM: misc aliases W-transpose region
  ln1_gate<<<dim3(1024), b256, 0, stream>>>(src, attnb, ln1g, ln1b, gateW, gateb,
                                            xb, counts, tok_top, tok_w);
  route_build<<<dim3(1), dim3(64), 0, stream>>>(counts, offsets, cursors, ntiles,
                                                tiles, token_idx, slot_w);
  route_scatter<<<dim3(16), b256, 0, stream>>>(tok_top, tok_w, offsets, cursors,
                                               token_idx, slot_w, slotA, slotB);

  gemm128<0, 0, 1, 1, 0, 1, 1><<<dim3(72, 32), b256, 0, stream>>>(
      xb, 1024, W1T, nullptr, 4096ll * 1024, hb, 4096, b1, 4096,
      nullptr, token_idx, tiles, ntiles, 1024, nullptr, 1.0f);
  gemm128<0, 1, 0, 0, 1, 0, 1><<<dim3(72, 8), b256, 0, stream>>>(
      hb, 4096, W2T, nullptr, 1024ll * 4096, out2, 1024, b2, 1024,
      slot_w, nullptr, tiles, ntiles, 4096, nullptr, 1.0f);

  final_ln2<<<dim3(1024), b256, 0, stream>>>(xb, out2, slotA, slotB, ln2g, ln2b, out);
}

// Round 5
// 762.107 us; speedup vs baseline: 2.0362x; 1.1476x over previous
//
// CustomTransformerEncoderMoELayerStoich — MI355X (gfx950)
// Round 5: R4 (passing) + three throughput edits, attention core untouched.
//   1) split GEMMs 4-term -> 3-term (drop al*bl, ~4e-6 rel)
//   2) QKV fused into one GEMM: B=concat(WqT*0.125, WkT, WvT) hi/lo, bias concat,
//      single [4096][3072] hi/lo bf16 output (2 blocks/CU occupancy)
//   3) FFN GEMM1 consumes bf16 x (ABF path): ln1_gate writes fp32 + bf16 copies

#include <hip/hip_runtime.h>
#include <stdint.h>

typedef unsigned short u16;
typedef unsigned int   u32;

using bf16x8 = __attribute__((ext_vector_type(8))) short;
using f32x4  = __attribute__((ext_vector_type(4))) float;

#define N_T   1024
#define N_D   1024
#define N_E   8
#define N_BT  4096
#define LNEPS 1e-5f

// ---------------- helpers ----------------
__device__ __forceinline__ u32 rne2(float a, float b) {
  u32 ua = __float_as_uint(a); ua = (ua + 0x7fffu + ((ua >> 16) & 1u)) >> 16;
  u32 ub = __float_as_uint(b); ub = (ub + 0x7fffu + ((ub >> 16) & 1u)) >> 16;
  return ua | (ub << 16);
}
__device__ __forceinline__ u16 rne1(float a) {
  u32 ua = __float_as_uint(a);
  return (u16)((ua + 0x7fffu + ((ua >> 16) & 1u)) >> 16);
}
__device__ __forceinline__ float bfhi_f(float a) {   // nearest-bf16 value as fp32
  u32 ua = __float_as_uint(a);
  ua = (ua + 0x7fffu + ((ua >> 16) & 1u)) & 0xffff0000u;
  return __uint_as_float(ua);
}
__device__ __forceinline__ int swz(int row, int chunk) {
  return row * 32 + (((chunk ^ (row & 3) ^ ((row >> 2) & 3)) & 3) << 3);
}
__device__ __forceinline__ float wred(float v) {
  #pragma unroll
  for (int o2 = 32; o2 > 0; o2 >>= 1) v += __shfl_xor(v, o2, 64);
  return v;
}
__device__ __forceinline__ f32x4 mfma16(bf16x8 a, bf16x8 b, f32x4 c) {
  return __builtin_amdgcn_mfma_f32_16x16x32_bf16(a, b, c, 0, 0, 0);
}

// ---------------- transpose fp32 [R][C] -> bf16 [C][R] (scale, optional hi/lo split) ---------
template<int SPLIT>
__global__ __launch_bounds__(256)
void transpose_bf16(const float* __restrict__ in, u16* __restrict__ outh,
                    u16* __restrict__ outl, int R, int C, float scale)
{
  __shared__ u16 th[64][68];
  __shared__ u16 tl[SPLIT ? 64 : 1][SPLIT ? 68 : 1];
  const long long zb = (long long)blockIdx.z * R * C;
  const float* srcp = in + zb;
  const int r0 = blockIdx.y * 64, c0 = blockIdx.x * 64;
  const int t = threadIdx.x;
  {
    const int rr = t >> 4, cc = (t & 15) << 2;
    #pragma unroll
    for (int i = 0; i < 4; i++) {
      const int r = rr + i * 16;
      float4 v = *(const float4*)(srcp + (long long)(r0 + r) * C + c0 + cc);
      v.x *= scale; v.y *= scale; v.z *= scale; v.w *= scale;
      if constexpr (SPLIT) {
        float hx = bfhi_f(v.x), hy = bfhi_f(v.y), hz = bfhi_f(v.z), hw = bfhi_f(v.w);
        *(uint2*)&th[r][cc] = make_uint2(rne2(hx, hy), rne2(hz, hw));
        *(uint2*)&tl[r][cc] = make_uint2(rne2(v.x - hx, v.y - hy), rne2(v.z - hz, v.w - hw));
      } else {
        *(uint2*)&th[r][cc] = make_uint2(rne2(v.x, v.y), rne2(v.z, v.w));
      }
    }
  }
  __syncthreads();
  {
    const int c = t >> 2, rs = (t & 3) << 4;
    const long long ob = zb + (long long)(c0 + c) * R + r0 + rs;
    u32 w[8];
    #pragma unroll
    for (int i = 0; i < 8; i++)
      w[i] = (u32)th[rs + 2*i][c] | ((u32)th[rs + 2*i + 1][c] << 16);
    *(uint4*)(outh + ob)     = make_uint4(w[0], w[1], w[2], w[3]);
    *(uint4*)(outh + ob + 8) = make_uint4(w[4], w[5], w[6], w[7]);
    if constexpr (SPLIT) {
      #pragma unroll
      for (int i = 0; i < 8; i++)
        w[i] = (u32)tl[rs + 2*i][c] | ((u32)tl[rs + 2*i + 1][c] << 16);
      *(uint4*)(outl + ob)     = make_uint4(w[0], w[1], w[2], w[3]);
      *(uint4*)(outl + ob + 8) = make_uint4(w[4], w[5], w[6], w[7]);
    }
  }
}

// ---------------- concat scaled QKV bias: [bq*0.125; bk; bv] ----------------
__global__ __launch_bounds__(256)
void bias_cat(const float* __restrict__ bq, const float* __restrict__ bk,
              const float* __restrict__ bv, float* __restrict__ bcat)
{
  const int i = blockIdx.x * 256 + threadIdx.x;
  if (i < 1024)       bcat[i] = bq[i] * 0.125f;
  else if (i < 2048)  bcat[i] = bk[i - 1024];
  else if (i < 3072)  bcat[i] = bv[i - 2048];
}

// ---------------- V^T per-head transpose: hi/lo bf16 [kv][d] (strided) -> [d][kv] ------------
__global__ __launch_bounds__(256)
void vtrans_bf16(const u16* __restrict__ Vh, const u16* __restrict__ Vl, int ldv,
                 u16* __restrict__ Vth, u16* __restrict__ Vtl)
{
  __shared__ u16 th[64][72];
  __shared__ u16 tl[64][72];
  const int bh = blockIdx.y, b = bh >> 4, h = bh & 15;
  const int kt = blockIdx.x, tid = threadIdx.x;
  {
    const int sr = tid >> 2, scb = (tid & 3) << 4;   // kv row, d col base
    const long long off = (long long)(b * N_T + kt * 64 + sr) * ldv + h * 64 + scb;
    const uint4* vh = (const uint4*)(Vh + off);
    const uint4* vl = (const uint4*)(Vl + off);
    *(uint4*)&th[sr][scb]     = vh[0];
    *(uint4*)&th[sr][scb + 8] = vh[1];
    *(uint4*)&tl[sr][scb]     = vl[0];
    *(uint4*)&tl[sr][scb + 8] = vl[1];
  }
  __syncthreads();
  {
    const int od = tid >> 2, os0 = (tid & 3) << 4;   // d row, kv col base
    u16 wh[16], wl[16];
    #pragma unroll
    for (int i = 0; i < 16; i++) { wh[i] = th[os0 + i][od]; wl[i] = tl[os0 + i][od]; }
    u16* oph = Vth + (long long)(bh * 64 + od) * N_T + kt * 64 + os0;
    u16* opl = Vtl + (long long)(bh * 64 + od) * N_T + kt * 64 + os0;
    *(uint4*)oph = make_uint4((u32)wh[0] | ((u32)wh[1] << 16), (u32)wh[2] | ((u32)wh[3] << 16),
                              (u32)wh[4] | ((u32)wh[5] << 16), (u32)wh[6] | ((u32)wh[7] << 16));
    *(uint4*)(oph + 8) = make_uint4((u32)wh[8] | ((u32)wh[9] << 16), (u32)wh[10] | ((u32)wh[11] << 16),
                                    (u32)wh[12] | ((u32)wh[13] << 16), (u32)wh[14] | ((u32)wh[15] << 16));
    *(uint4*)opl = make_uint4((u32)wl[0] | ((u32)wl[1] << 16), (u32)wl[2] | ((u32)wl[3] << 16),
                              (u32)wl[4] | ((u32)wl[5] << 16), (u32)wl[6] | ((u32)wl[7] << 16));
    *(uint4*)(opl + 8) = make_uint4((u32)wl[8] | ((u32)wl[9] << 16), (u32)wl[10] | ((u32)wl[11] << 16),
                                    (u32)wl[12] | ((u32)wl[13] << 16), (u32)wl[14] | ((u32)wl[15] << 16));
  }
}

// ---------------- 128x128x32 MFMA GEMM (4 waves, 4x4 16x16 frags each) ----------------
// SPLIT: hi/lo 3-term (al*bl dropped, ~4e-6 rel). OBF: 0 fp32, 1 bf16, 2 split hi/lo (+cscale).
template<int SPLIT, int ABF, int GATHER, int DORELU, int DOSCALE, int OBF, int GROUPED>
__global__ __launch_bounds__(256, 2)
void gemm128(const void* __restrict__ Ap, int lda,
             const u16* __restrict__ Bhp, const u16* __restrict__ Blp,
             long long bstride,
             void* __restrict__ Cp, int ldc,
             const float* __restrict__ biasp, int bias_stride,
             const float* __restrict__ slot_wp,
             const int* __restrict__ tokidx,
             const int2* __restrict__ tilesp, const int* __restrict__ ntilesp,
             int Ksz, void* __restrict__ Cp2, float cscale)
{
  int e = 0, row0;
  if constexpr (GROUPED) {
    if ((int)blockIdx.x >= *ntilesp) return;
    const int2 dsc = tilesp[blockIdx.x];
    e = dsc.x; row0 = dsc.y;
  } else {
    row0 = blockIdx.x * 128;
  }
  const int col0 = blockIdx.y * 128;

  __shared__ __align__(16) u16 AhS[128 * 32];
  __shared__ __align__(16) u16 BhS[128 * 32];
  __shared__ __align__(16) u16 AlS[SPLIT ? 128 * 32 : 8];
  __shared__ __align__(16) u16 BlS[SPLIT ? 128 * 32 : 8];

  const int tid = threadIdx.x;
  const int rr = tid >> 1;
  const int c2 = (tid & 1) << 1;

  long long arow;
  if constexpr (GATHER) arow = tokidx[row0 + rr];
  else                  arow = row0 + rr;
  const char* Arow = (const char*)Ap + arow * (long long)lda * (ABF ? 2 : 4);
  const u16* Bhrow = Bhp + (long long)e * bstride + (long long)(col0 + rr) * Ksz;
  const u16* Blrow = nullptr;
  if constexpr (SPLIT) Blrow = Blp + (long long)e * bstride + (long long)(col0 + rr) * Ksz;
  const float* bias = biasp + (long long)e * bias_stride + col0;

  const int wid = tid >> 6, lane = tid & 63;
  const int wm = (wid >> 1) << 6, wn = (wid & 1) << 6;
  const int l15 = lane & 15, l4 = lane >> 4;

  f32x4 acc[4][4] = {};

  uint4 sah0, sah1, sal0, sal1, sbh0, sbh1, sbl0, sbl1;

  auto gload = [&](int k0) {
    if constexpr (ABF) {
      const uint4* ap = (const uint4*)(Arow + (long long)(k0 + c2 * 8) * 2);
      sah0 = ap[0]; sah1 = ap[1];
    } else {
      const float4* ap = (const float4*)(Arow + (long long)(k0 + c2 * 8) * 4);
      float4 f0 = ap[0], f1 = ap[1], f2 = ap[2], f3 = ap[3];
      if constexpr (SPLIT) {
        float h0 = bfhi_f(f0.x), h1 = bfhi_f(f0.y), h2 = bfhi_f(f0.z), h3 = bfhi_f(f0.w);
        float h4 = bfhi_f(f1.x), h5 = bfhi_f(f1.y), h6 = bfhi_f(f1.z), h7 = bfhi_f(f1.w);
        sah0 = make_uint4(rne2(h0, h1), rne2(h2, h3), rne2(h4, h5), rne2(h6, h7));
        sal0 = make_uint4(rne2(f0.x - h0, f0.y - h1), rne2(f0.z - h2, f0.w - h3),
                          rne2(f1.x - h4, f1.y - h5), rne2(f1.z - h6, f1.w - h7));
        h0 = bfhi_f(f2.x); h1 = bfhi_f(f2.y); h2 = bfhi_f(f2.z); h3 = bfhi_f(f2.w);
        h4 = bfhi_f(f3.x); h5 = bfhi_f(f3.y); h6 = bfhi_f(f3.z); h7 = bfhi_f(f3.w);
        sah1 = make_uint4(rne2(h0, h1), rne2(h2, h3), rne2(h4, h5), rne2(h6, h7));
        sal1 = make_uint4(rne2(f2.x - h0, f2.y - h1), rne2(f2.z - h2, f2.w - h3),
                          rne2(f3.x - h4, f3.y - h5), rne2(f3.z - h6, f3.w - h7));
      } else {
        sah0 = make_uint4(rne2(f0.x, f0.y), rne2(f0.z, f0.w), rne2(f1.x, f1.y), rne2(f1.z, f1.w));
        sah1 = make_uint4(rne2(f2.x, f2.y), rne2(f2.z, f2.w), rne2(f3.x, f3.y), rne2(f3.z, f3.w));
      }
    }
    {
      const uint4* bp = (const uint4*)(Bhrow + k0 + c2 * 8);
      sbh0 = bp[0]; sbh1 = bp[1];
    }
    if constexpr (SPLIT) {
      const uint4* bp = (const uint4*)(Blrow + k0 + c2 * 8);
      sbl0 = bp[0]; sbl1 = bp[1];
    }
  };

  gload(0);
  const int nk = Ksz >> 5;
  for (int kt = 0; kt < nk; kt++) {
    __syncthreads();
    *(uint4*)&AhS[swz(rr, c2)]     = sah0;
    *(uint4*)&AhS[swz(rr, c2 + 1)] = sah1;
    *(uint4*)&BhS[swz(rr, c2)]     = sbh0;
    *(uint4*)&BhS[swz(rr, c2 + 1)] = sbh1;
    if constexpr (SPLIT) {
      *(uint4*)&AlS[swz(rr, c2)]     = sal0;
      *(uint4*)&AlS[swz(rr, c2 + 1)] = sal1;
      *(uint4*)&BlS[swz(rr, c2)]     = sbl0;
      *(uint4*)&BlS[swz(rr, c2 + 1)] = sbl1;
    }
    __syncthreads();
    if (kt + 1 < nk) gload((kt + 1) << 5);

    bf16x8 ah[4], bh[4], al[SPLIT ? 4 : 1], bl[SPLIT ? 4 : 1];
    #pragma unroll
    for (int i = 0; i < 4; i++) {
      const int ar = wm + i * 16 + l15;
      const int br = wn + i * 16 + l15;
      ah[i] = *(const bf16x8*)&AhS[swz(ar, l4)];
      bh[i] = *(const bf16x8*)&BhS[swz(br, l4)];
      if constexpr (SPLIT) {
        al[i] = *(const bf16x8*)&AlS[swz(ar, l4)];
        bl[i] = *(const bf16x8*)&BlS[swz(br, l4)];
      }
    }
    #pragma unroll
    for (int i = 0; i < 4; i++) {
      #pragma unroll
      for (int j = 0; j < 4; j++) {
        acc[i][j] = mfma16(ah[i], bh[j], acc[i][j]);
        if constexpr (SPLIT) {
          acc[i][j] = mfma16(ah[i], bl[j], acc[i][j]);
          acc[i][j] = mfma16(al[i], bh[j], acc[i][j]);
        }
      }
    }
  }

  #pragma unroll
  for (int i = 0; i < 4; i++) {
    #pragma unroll
    for (int j = 0; j < 4; j++) {
      const int orow0 = row0 + wm + i * 16 + (l4 << 2);
      const int ocol  = col0 + wn + j * 16 + l15;
      const float bv = bias[wn + j * 16 + l15];
      #pragma unroll
      for (int q = 0; q < 4; q++) {
        float v = acc[i][j][q] + bv;
        if constexpr (DORELU) v = fmaxf(v, 0.f);
        const long long orow = orow0 + q;
        if constexpr (DOSCALE) v *= slot_wp[orow];
        if constexpr (OBF == 2) {
          const float vs = v * cscale;
          const float hi = bfhi_f(vs);
          ((u16*)Cp )[orow * ldc + ocol] = (u16)(__float_as_uint(hi) >> 16);
          ((u16*)Cp2)[orow * ldc + ocol] = rne1(vs - hi);
        } else if constexpr (OBF == 1) {
          ((u16*)Cp)[orow * ldc + ocol] = rne1(v);
        } else {
          ((float*)Cp)[orow * ldc + ocol] = v;
        }
      }
    }
  }
}

// ---------------- MFMA flash attention with stoichiometric bias ----------------
// grid (B*H=64, T/128=8), block 256 (4 waves); wave handles 32 q rows.
// Q/K pointers are column-offset views into the fused QKV hi/lo buffers (stride ldq).
__global__ __launch_bounds__(256, 2)
void attn_mfma(const u16* __restrict__ Qh, const u16* __restrict__ Ql,
               const u16* __restrict__ Kh, const u16* __restrict__ Kl, int ldq,
               const u16* __restrict__ Vth, const u16* __restrict__ Vtl,
               const float* __restrict__ frac,
               const float* __restrict__ apos, const float* __restrict__ aneg,
               float* __restrict__ ctx)
{
  __shared__ __align__(16) u16 KhS[64 * 64];   // [kv][d], chunk^(kv&7) swizzle
  __shared__ __align__(16) u16 KlS[64 * 64];
  __shared__ __align__(16) u16 VhS[64 * 64];   // [d][kv], same swizzle
  __shared__ __align__(16) u16 VlS[64 * 64];
  __shared__ __align__(16) u16 PS[4][32][72];  // per-wave P[q][kv], +8 pad
  __shared__ __align__(16) float fjS[64];

  const int bh = blockIdx.x, b = bh >> 4, h = bh & 15;
  const int tid = threadIdx.x, wid = tid >> 6, lane = tid & 63;
  const int l15 = lane & 15, l4 = lane >> 4;
  const int q0 = blockIdx.y * 128 + wid * 32;

  // Q fragments (B-operand: n = q = l15, k-chunk = l4), pre-scaled & pre-split
  bf16x8 qh[2][2], ql[2][2];
  #pragma unroll
  for (int ni = 0; ni < 2; ni++) {
    const long long qoff = (long long)(b * N_T + q0 + ni * 16 + l15) * ldq + h * 64 + l4 * 8;
    #pragma unroll
    for (int ks = 0; ks < 2; ks++) {
      qh[ni][ks] = *(const bf16x8*)(Qh + qoff + ks * 32);
      ql[ni][ks] = *(const bf16x8*)(Ql + qoff + ks * 32);
    }
  }
  float fq[2];
  #pragma unroll
  for (int ni = 0; ni < 2; ni++) fq[ni] = frac[b * N_T + q0 + ni * 16 + l15];
  const float ap = apos[h], an = aneg[h];

  f32x4 acc[4][2] = {};                 // O^T: d = md*16+l4*4+reg, q = nq*16+l15
  float mrun[2] = {-3.0e38f, -3.0e38f}, lrun[2] = {0.f, 0.f};

  const int sr = tid >> 2, scb = (tid & 3) << 4;
  const int ch0 = ((scb >> 3) ^ (sr & 7)) << 3;
  const int ch1 = (((scb >> 3) + 1) ^ (sr & 7)) << 3;

  for (int kt = 0; kt < 16; kt++) {
    __syncthreads();
    {
      const long long koff = (long long)(b * N_T + kt * 64 + sr) * ldq + h * 64 + scb;
      const uint4* khp = (const uint4*)(Kh + koff);
      const uint4* klp = (const uint4*)(Kl + koff);
      const long long voff = (long long)(bh * 64 + sr) * N_T + kt * 64 + scb;
      const uint4* vhp = (const uint4*)(Vth + voff);
      const uint4* vlp = (const uint4*)(Vtl + voff);
      *(uint4*)&KhS[sr * 64 + ch0] = khp[0];
      *(uint4*)&KhS[sr * 64 + ch1] = khp[1];
      *(uint4*)&KlS[sr * 64 + ch0] = klp[0];
      *(uint4*)&KlS[sr * 64 + ch1] = klp[1];
      *(uint4*)&VhS[sr * 64 + ch0] = vhp[0];
      *(uint4*)&VhS[sr * 64 + ch1] = vhp[1];
      *(uint4*)&VlS[sr * 64 + ch0] = vlp[0];
      *(uint4*)&VlS[sr * 64 + ch1] = vlp[1];
    }
    if (tid < 64) fjS[tid] = frac[b * N_T + kt * 64 + tid];
    __syncthreads();

    // ---- S^T = K * Q^T (3-term split)
    f32x4 s[4][2] = {};
    #pragma unroll
    for (int ks = 0; ks < 2; ks++) {
      bf16x8 kh[4], kl[4];
      #pragma unroll
      for (int mj = 0; mj < 4; mj++) {
        const int row = mj * 16 + l15;
        const int ch = (((ks << 2) + l4) ^ (row & 7)) << 3;
        kh[mj] = *(const bf16x8*)&KhS[row * 64 + ch];
        kl[mj] = *(const bf16x8*)&KlS[row * 64 + ch];
      }
      #pragma unroll
      for (int mj = 0; mj < 4; mj++) {
        #pragma unroll
        for (int ni = 0; ni < 2; ni++) {
          s[mj][ni] = mfma16(kh[mj], qh[ni][ks], s[mj][ni]);
          s[mj][ni] = mfma16(kh[mj], ql[ni][ks], s[mj][ni]);
          s[mj][ni] = mfma16(kl[mj], qh[ni][ks], s[mj][ni]);
        }
      }
    }

    // ---- bias (scalar fjS reads) ; kv = mj*16 + l4*4 + r, q = ni*16 + l15
    #pragma unroll
    for (int mj = 0; mj < 4; mj++) {
      const int kvb = mj * 16 + l4 * 4;
      const float f0 = fjS[kvb], f1 = fjS[kvb + 1], f2 = fjS[kvb + 2], f3 = fjS[kvb + 3];
      #pragma unroll
      for (int ni = 0; ni < 2; ni++) {
        float d0 = f0 - fq[ni], d1 = f1 - fq[ni], d2 = f2 - fq[ni], d3 = f3 - fq[ni];
        s[mj][ni][0] += (d0 > 0.f ? ap : an) * d0;
        s[mj][ni][1] += (d1 > 0.f ? ap : an) * d1;
        s[mj][ni][2] += (d2 > 0.f ? ap : an) * d2;
        s[mj][ni][3] += (d3 > 0.f ? ap : an) * d3;
      }
    }

    // ---- online softmax
    #pragma unroll
    for (int ni = 0; ni < 2; ni++) {
      float tm = s[0][ni][0];
      #pragma unroll
      for (int mj = 0; mj < 4; mj++) {
        tm = fmaxf(tm, fmaxf(fmaxf(s[mj][ni][0], s[mj][ni][1]),
                             fmaxf(s[mj][ni][2], s[mj][ni][3])));
      }
      tm = fmaxf(tm, __shfl_xor(tm, 16, 64));
      tm = fmaxf(tm, __shfl_xor(tm, 32, 64));
      const float nm = fmaxf(mrun[ni], tm);
      const float cor = __expf(mrun[ni] - nm);
      mrun[ni] = nm;
      lrun[ni] *= cor;
      #pragma unroll
      for (int md = 0; md < 4; md++) {
        acc[md][ni][0] *= cor; acc[md][ni][1] *= cor;
        acc[md][ni][2] *= cor; acc[md][ni][3] *= cor;
      }
      float rsum = 0.f;
      #pragma unroll
      for (int mj = 0; mj < 4; mj++) {
        #pragma unroll
        for (int r = 0; r < 4; r++) {
          const float p = __expf(s[mj][ni][r] - nm);
          s[mj][ni][r] = p;
          rsum += p;
        }
      }
      rsum += __shfl_xor(rsum, 16, 64);
      rsum += __shfl_xor(rsum, 32, 64);
      lrun[ni] += rsum;
    }

    // ---- P hi -> per-wave LDS (C-write-verified mapping), read B-frags
    #pragma unroll
    for (int ni = 0; ni < 2; ni++) {
      #pragma unroll
      for (int mj = 0; mj < 4; mj++) {
        float h0 = bfhi_f(s[mj][ni][0]), h1 = bfhi_f(s[mj][ni][1]);
        float h2 = bfhi_f(s[mj][ni][2]), h3 = bfhi_f(s[mj][ni][3]);
        u32* dst = (u32*)&PS[wid][ni * 16 + l15][mj * 16 + l4 * 4];
        dst[0] = rne2(h0, h1); dst[1] = rne2(h2, h3);
      }
    }
    bf16x8 pbh[2][2];
    #pragma unroll
    for (int ni = 0; ni < 2; ni++)
      #pragma unroll
      for (int ks = 0; ks < 2; ks++)
        pbh[ni][ks] = *(const bf16x8*)&PS[wid][ni * 16 + l15][ks * 32 + l4 * 8];

    // ---- P lo -> same LDS buffer, read B-frags
    #pragma unroll
    for (int ni = 0; ni < 2; ni++) {
      #pragma unroll
      for (int mj = 0; mj < 4; mj++) {
        float p0 = s[mj][ni][0], p1 = s[mj][ni][1], p2 = s[mj][ni][2], p3 = s[mj][ni][3];
        float h0 = bfhi_f(p0), h1 = bfhi_f(p1), h2 = bfhi_f(p2), h3 = bfhi_f(p3);
        u32* dst = (u32*)&PS[wid][ni * 16 + l15][mj * 16 + l4 * 4];
        dst[0] = rne2(p0 - h0, p1 - h1); dst[1] = rne2(p2 - h2, p3 - h3);
      }
    }
    bf16x8 pbl[2][2];
    #pragma unroll
    for (int ni = 0; ni < 2; ni++)
      #pragma unroll
      for (int ks = 0; ks < 2; ks++)
        pbl[ni][ks] = *(const bf16x8*)&PS[wid][ni * 16 + l15][ks * 32 + l4 * 8];

    // ---- O^T += V^T * P^T (3-term split; linear kv pairing)
    #pragma unroll
    for (int md = 0; md < 4; md++) {
      #pragma unroll
      for (int ks = 0; ks < 2; ks++) {
        const int row = md * 16 + l15;
        const int ch = (((ks << 2) + l4) ^ (row & 7)) << 3;
        const bf16x8 vh = *(const bf16x8*)&VhS[row * 64 + ch];
        const bf16x8 vl = *(const bf16x8*)&VlS[row * 64 + ch];
        #pragma unroll
        for (int nq = 0; nq < 2; nq++) {
          acc[md][nq] = mfma16(vh, pbh[nq][ks], acc[md][nq]);
          acc[md][nq] = mfma16(vh, pbl[nq][ks], acc[md][nq]);
          acc[md][nq] = mfma16(vl, pbh[nq][ks], acc[md][nq]);
        }
      }
    }
  }

  // ---- epilogue: ctx[q][d] = O^T[d][q] / l[q]
  const float inv[2] = {1.f / lrun[0], 1.f / lrun[1]};
  #pragma unroll
  for (int nq = 0; nq < 2; nq++) {
    #pragma unroll
    for (int md = 0; md < 4; md++) {
      float4 o;
      o.x = acc[md][nq][0] * inv[nq];
      o.y = acc[md][nq][1] * inv[nq];
      o.z = acc[md][nq][2] * inv[nq];
      o.w = acc[md][nq][3] * inv[nq];
      *(float4*)(ctx + (long long)(b * N_T + q0 + nq * 16 + l15) * N_D +
                 h * 64 + md * 16 + l4 * 4) = o;
    }
  }
}

// ---------------- LN1 + gate softmax + top2 (wave per token) ----------------
__global__ __launch_bounds__(256, 4)
void ln1_gate(const float* __restrict__ src, const float* __restrict__ attnout,
              const float* __restrict__ g, const float* __restrict__ bb,
              const float* __restrict__ gateW, const float* __restrict__ gateb,
              float* __restrict__ xout, u16* __restrict__ xbf,
              int* __restrict__ counts,
              int2* __restrict__ tok_top, float2* __restrict__ tok_w)
{
  const int wid = threadIdx.x >> 6, lane = threadIdx.x & 63;
  const int t = blockIdx.x * 4 + wid;
  const float4* s4 = (const float4*)(src + (long long)t * N_D);
  const float4* a4 = (const float4*)(attnout + (long long)t * N_D);
  float4 v[4];
  float sum = 0.f;
  #pragma unroll
  for (int c = 0; c < 4; c++) {
    const int idx = c * 64 + lane;
    float4 a = s4[idx], b2 = a4[idx];
    v[c] = make_float4(a.x + b2.x, a.y + b2.y, a.z + b2.z, a.w + b2.w);
    sum += v[c].x + v[c].y + v[c].z + v[c].w;
  }
  sum = wred(sum);
  const float mu = sum * (1.f / 1024.f);
  float s2 = 0.f;
  #pragma unroll
  for (int c = 0; c < 4; c++) {
    float dx = v[c].x - mu, dy = v[c].y - mu, dz = v[c].z - mu, dw = v[c].w - mu;
    s2 += dx * dx + dy * dy + dz * dz + dw * dw;
  }
  s2 = wred(s2);
  const float rs = rsqrtf(s2 * (1.f / 1024.f) + LNEPS);
  float acc[8];
  #pragma unroll
  for (int e2 = 0; e2 < 8; e2++) acc[e2] = 0.f;
  #pragma unroll
  for (int c = 0; c < 4; c++) {
    const int idx = c * 64 + lane;
    float4 gv = ((const float4*)g)[idx], bv = ((const float4*)bb)[idx];
    float xa[4];
    xa[0] = (v[c].x - mu) * rs * gv.x + bv.x;
    xa[1] = (v[c].y - mu) * rs * gv.y + bv.y;
    xa[2] = (v[c].z - mu) * rs * gv.z + bv.z;
    xa[3] = (v[c].w - mu) * rs * gv.w + bv.w;
    ((float4*)(xout + (long long)t * N_D))[idx] = make_float4(xa[0], xa[1], xa[2], xa[3]);
    *(uint2*)&xbf[(long long)t * N_D + idx * 4] =
        make_uint2(rne2(xa[0], xa[1]), rne2(xa[2], xa[3]));
    #pragma unroll
    for (int ii = 0; ii < 4; ii++) {
      const float xs = xa[ii];
      const float4* gw = (const float4*)(gateW + ((long long)(idx * 4 + ii)) * N_E);
      float4 w0 = gw[0], w1 = gw[1];
      acc[0] += xs * w0.x; acc[1] += xs * w0.y; acc[2] += xs * w0.z; acc[3] += xs * w0.w;
      acc[4] += xs * w1.x; acc[5] += xs * w1.y; acc[6] += xs * w1.z; acc[7] += xs * w1.w;
    }
  }
  #pragma unroll
  for (int e2 = 0; e2 < 8; e2++) acc[e2] = wred(acc[e2]);
  if (lane == 0) {
    float lg[8];
    #pragma unroll
    for (int e2 = 0; e2 < 8; e2++) lg[e2] = acc[e2] + gateb[e2];
    float mx = lg[0];
    #pragma unroll
    for (int e2 = 1; e2 < 8; e2++) mx = fmaxf(mx, lg[e2]);
    float Z = 0.f;
    #pragma unroll
    for (int e2 = 0; e2 < 8; e2++) Z += __expf(lg[e2] - mx);
    int e0 = 0; float v0 = lg[0];
    #pragma unroll
    for (int e2 = 1; e2 < 8; e2++) if (lg[e2] > v0) { v0 = lg[e2]; e0 = e2; }
    int e1 = -1; float v1 = -3.4e38f;
    #pragma unroll
    for (int e2 = 0; e2 < 8; e2++) if (e2 != e0 && lg[e2] > v1) { v1 = lg[e2]; e1 = e2; }
    atomicAdd(&counts[e0], 1);
    atomicAdd(&counts[e1], 1);
    tok_top[t] = make_int2(e0, e1);
    tok_w[t] = make_float2(__expf(v0 - mx) / Z, __expf(v1 - mx) / Z);
  }
}

// ---------------- routing: offsets, tile descriptors, padding fill ----------------
__global__ void route_build(const int* __restrict__ counts, int* __restrict__ offsets,
                            int* __restrict__ cursors, int* __restrict__ ntiles,
                            int2* __restrict__ tiles, int* __restrict__ token_idx,
                            float* __restrict__ slot_w)
{
  __shared__ int soff[N_E + 1];
  __shared__ int scnt[N_E];
  if (threadIdx.x == 0) {
    int off = 0, nt = 0;
    for (int ex = 0; ex < N_E; ex++) {
      soff[ex] = off; offsets[ex] = off; cursors[ex] = 0;
      const int cnt = counts[ex];
      scnt[ex] = cnt;
      const int pt = (cnt + 127) >> 7;
      for (int i = 0; i < pt; i++) { tiles[nt] = make_int2(ex, off + i * 128); nt++; }
      off += pt << 7;
    }
    soff[N_E] = off; offsets[N_E] = off;
    *ntiles = nt;
  }
  __syncthreads();
  for (int ex = 0; ex < N_E; ex++)
    for (int s = soff[ex] + scnt[ex] + (int)threadIdx.x; s < soff[ex + 1]; s += (int)blockDim.x) {
      token_idx[s] = 0; slot_w[s] = 0.f;
    }
}

__global__ __launch_bounds__(256)
void route_scatter(const int2* __restrict__ tok_top, const float2* __restrict__ tok_w,
                   const int* __restrict__ offsets, int* __restrict__ cursors,
                   int* __restrict__ token_idx, float* __restrict__ slot_w,
                   int* __restrict__ slotA, int* __restrict__ slotB)
{
  const int t = blockIdx.x * 256 + threadIdx.x;
  if (t >= N_BT) return;
  const int2 ee = tok_top[t];
  const float2 ww = tok_w[t];
  int p = atomicAdd(&cursors[ee.x], 1);
  int s = offsets[ee.x] + p;
  token_idx[s] = t; slot_w[s] = ww.x; slotA[t] = s;
  p = atomicAdd(&cursors[ee.y], 1);
  s = offsets[ee.y] + p;
  token_idx[s] = t; slot_w[s] = ww.y; slotB[t] = s;
}

// ---------------- final: y = LN2(x + out2[sA] + out2[sB]) ----------------
__global__ __launch_bounds__(256, 4)
void final_ln2(const float* __restrict__ x, const float* __restrict__ out2,
               const int* __restrict__ slotA, const int* __restrict__ slotB,
               const float* __restrict__ g, const float* __restrict__ bb,
               float* __restrict__ out)
{
  const int wid = threadIdx.x >> 6, lane = threadIdx.x & 63;
  const int t = blockIdx.x * 4 + wid;
  const int sA = slotA[t], sB = slotB[t];
  const float4* xr = (const float4*)(x + (long long)t * N_D);
  const float4* pa = (const float4*)(out2 + (long long)sA * N_D);
  const float4* pb = (const float4*)(out2 + (long long)sB * N_D);
  float4 v[4];
  float sum = 0.f;
  #pragma unroll
  for (int c = 0; c < 4; c++) {
    const int idx = c * 64 + lane;
    float4 a = xr[idx], b2 = pa[idx], c2 = pb[idx];
    v[c] = make_float4(a.x + b2.x + c2.x, a.y + b2.y + c2.y,
                       a.z + b2.z + c2.z, a.w + b2.w + c2.w);
    sum += v[c].x + v[c].y + v[c].z + v[c].w;
  }
  sum = wred(sum);
  const float mu = sum * (1.f / 1024.f);
  float s2 = 0.f;
  #pragma unroll
  for (int c = 0; c < 4; c++) {
    float dx = v[c].x - mu, dy = v[c].y - mu, dz = v[c].z - mu, dw = v[c].w - mu;
    s2 += dx * dx + dy * dy + dz * dz + dw * dw;
  }
  s2 = wred(s2);
  const float rs = rsqrtf(s2 * (1.f / 1024.f) + LNEPS);
  #pragma unroll
  for (int c = 0; c < 4; c++) {
    const int idx = c * 64 + lane;
    float4 gv = ((const float4*)g)[idx], bv = ((const float4*)bb)[idx];
    float4 o;
    o.x = (v[c].x - mu) * rs * gv.x + bv.x;
    o.y = (v[c].y - mu) * rs * gv.y + bv.y;
    o.z = (v[c].z - mu) * rs * gv.z + bv.z;
    o.w = (v[c].w - mu) * rs * gv.w + bv.w;
    ((float4*)(out + (long long)t * N_D))[idx] = o;
  }
}

// ---------------- launch ----------------
extern "C" void kernel_launch(void* const* d_in, const int* in_sizes, int n_in,
                              void* d_out, int out_size, void* d_ws, size_t ws_size,
                              hipStream_t stream)
{
  const float* src   = (const float*)d_in[0];
  const float* frac  = (const float*)d_in[1];
  const float* Wq    = (const float*)d_in[2];
  const float* bq    = (const float*)d_in[3];
  const float* Wk    = (const float*)d_in[4];
  const float* bk    = (const float*)d_in[5];
  const float* Wv    = (const float*)d_in[6];
  const float* bv    = (const float*)d_in[7];
  const float* Wo    = (const float*)d_in[8];
  const float* bo    = (const float*)d_in[9];
  const float* apos  = (const float*)d_in[10];
  const float* aneg  = (const float*)d_in[11];
  const float* gateW = (const float*)d_in[12];
  const float* gateb = (const float*)d_in[13];
  const float* W1    = (const float*)d_in[14];
  const float* b1    = (const float*)d_in[15];
  const float* W2    = (const float*)d_in[16];
  const float* b2    = (const float*)d_in[17];
  const float* ln1g  = (const float*)d_in[18];
  const float* ln1b  = (const float*)d_in[19];
  const float* ln2g  = (const float*)d_in[20];
  const float* ln2b  = (const float*)d_in[21];
  float* out = (float*)d_out;

  char* ws = (char*)d_ws;
  const size_t MB = 1ull << 20;
  // 0-16 MB: QKV/Wo transposed weights (dead after respective GEMMs).
  //   Bcath [3072][1024] at 0-6, Bcatl at 6-12, WoTh 12-14, WoTl 14-16.
  //   misc (routing, ~140KB) aliases ws+0 after Wo GEMM; xbf aliases ws+4MB then.
  u16* Bcath = (u16*)(ws + 0 * MB);
  u16* Bcatl = (u16*)(ws + 6 * MB);
  u16* WoTh  = (u16*)(ws + 12 * MB);
  u16* WoTl  = (u16*)(ws + 14 * MB);
  u16*   W1T  = (u16*)(ws + 16 * MB);    // 64 MB, dead after FFN GEMM1
  float* out2 = (float*)(ws + 16 * MB);  // <=38 MB, alias (written after W1T dead)
  u16*   W2T  = (u16*)(ws + 80 * MB);    // 64 MB
  u16*   QKVh = (u16*)(ws + 144 * MB);   // 24 MB: [4096][3072] hi (Q|K|V)
  u16*   QKVl = (u16*)(ws + 168 * MB);   // 24 MB lo
  u16*   Vth  = (u16*)(ws + 192 * MB);   // 8 MB per-head V^T hi
  u16*   Vtl  = (u16*)(ws + 200 * MB);   // 8 MB per-head V^T lo
  float* ctxb = (float*)(ws + 208 * MB); // 16 MB
  float* attnb= (float*)(ws + 144 * MB); // 16 MB alias (QKVh dead after attn)
  u16*   hb   = (u16*)(ws + 144 * MB);   // <=72 MB alias (all of 144-216 dead by FFN1)
  float* xb   = (float*)(ws + 224 * MB); // 16 MB fp32 -> total 240 MB
  u16*   xbf  = (u16*)(ws + 4 * MB);     // 8 MB bf16 alias (Bcat dead by ln1_gate)
  float* bcat = (float*)(ws + 240 * MB); // 12 KB (R1/R4 precedent: misc lived at 240MB)
  char* misc = ws + 0;                   // aliases Bcat region (dead by routing phase)
  int*    counts    = (int*)(misc);
  int*    cursors   = (int*)(misc + 64);
  int*    offsets   = (int*)(misc + 128);
  int*    ntiles    = (int*)(misc + 256);
  int2*   tiles     = (int2*)(misc + 512);
  int2*   tok_top   = (int2*)(misc + 2048);
  float2* tok_w     = (float2*)(misc + 2048 + 32768);
  int*    token_idx = (int*)(misc + 2048 + 65536);
  float*  slot_w    = (float*)(misc + 2048 + 65536 + 36864);
  int*    slotA     = (int*)(misc + 2048 + 65536 + 73728);
  int*    slotB     = (int*)(misc + 2048 + 65536 + 73728 + 16384);

  dim3 b256(256);
  // weight transposes: Wq scaled by 0.125 into Bcat rows 0-1023; Wk, Wv follow
  transpose_bf16<1><<<dim3(16, 16, 1), b256, 0, stream>>>(Wq, Bcath, Bcatl,
                                                          1024, 1024, 0.125f);
  transpose_bf16<1><<<dim3(16, 16, 1), b256, 0, stream>>>(Wk, Bcath + 1024 * 1024,
                                                          Bcatl + 1024 * 1024, 1024, 1024, 1.0f);
  transpose_bf16<1><<<dim3(16, 16, 1), b256, 0, stream>>>(Wv, Bcath + 2048 * 1024,
                                                          Bcatl + 2048 * 1024, 1024, 1024, 1.0f);
  transpose_bf16<1><<<dim3(16, 16, 1), b256, 0, stream>>>(Wo, WoTh, WoTl, 1024, 1024, 1.0f);
  transpose_bf16<0><<<dim3(64, 16, 8), b256, 0, stream>>>(W1, W1T, nullptr, 1024, 4096, 1.0f);
  transpose_bf16<0><<<dim3(16, 64, 8), b256, 0, stream>>>(W2, W2T, nullptr, 4096, 1024, 1.0f);
  bias_cat<<<dim3(12), b256, 0, stream>>>(bq, bk, bv, bcat);

  // fused QKV projection: [4096][3072] hi/lo bf16 (Q cols pre-scaled via Wq/bq)
  gemm128<1, 0, 0, 0, 0, 2, 0><<<dim3(32, 24), b256, 0, stream>>>(
      src, 1024, Bcath, Bcatl, 0, QKVh, 3072, bcat, 0, nullptr, nullptr, nullptr, nullptr,
      1024, QKVl, 1.0f);

  vtrans_bf16<<<dim3(16, 64), b256, 0, stream>>>(QKVh + 2048, QKVl + 2048, 3072, Vth, Vtl);

  attn_mfma<<<dim3(64, 8), b256, 0, stream>>>(QKVh, QKVl, QKVh + 1024, QKVl + 1024, 3072,
                                              Vth, Vtl, frac, apos, aneg, ctxb);

  gemm128<1, 0, 0, 0, 0, 0, 0><<<dim3(32, 8), b256, 0, stream>>>(
      ctxb, 1024, WoTh, WoTl, 0, attnb, 1024, bo, 0, nullptr, nullptr, nullptr, nullptr,
      1024, nullptr, 1.0f);

  hipMemsetAsync(counts, 0, 32, stream);   // misc aliases Bcat region (dead after QKV/Wo)
  ln1_gate<<<dim3(1024), b256, 0, stream>>>(src, attnb, ln1g, ln1b, gateW, gateb,
                                            xb, xbf, counts, tok_top, tok_w);
  route_build<<<dim3(1), dim3(64), 0, stream>>>(counts, offsets, cursors, ntiles,
                                                tiles, token_idx, slot_w);
  route_scatter<<<dim3(16), b256, 0, stream>>>(tok_top, tok_w, offsets, cursors,
                                               token_idx, slot_w, slotA, slotB);

  // grouped MoE FFN (A now bf16 via ABF path for GEMM1)
  gemm128<0, 1, 1, 1, 0, 1, 1><<<dim3(72, 32), b256, 0, stream>>>(
      xbf, 1024, W1T, nullptr, 4096ll * 1024, hb, 4096, b1, 4096,
      nullptr, token_idx, tiles, ntiles, 1024, nullptr, 1.0f);
  gemm128<0, 1, 0, 0, 1, 0, 1><<<dim3(72, 8), b256, 0, stream>>>(
      hb, 4096, W2T, nullptr, 1024ll * 4096, out2, 1024, b2, 1024,
      slot_w, nullptr, tiles, ntiles, 4096, nullptr, 1.0f);

  final_ln2<<<dim3(1024), b256, 0, stream>>>(xb, out2, slotA, slotB, ln2g, ln2b, out);
}

// Round 6
// 723.624 us; speedup vs baseline: 2.1445x; 1.0532x over previous
//
// CustomTransformerEncoderMoELayerStoich — MI355X (gfx950)
// Round 6: R5 (passing) + GEMM staging/locality upgrades. Attention core untouched.
//   1) gemm128 bf16 paths: global_load_lds width=16 (m97 structure), linear LDS dest +
//      inverse-swizzled per-lane global source (read-side swz() unchanged)
//   2) gemm128 fp32-split paths: A keeps verified register staging; B hi/lo async
//   3) all GEMMs: bijective XCD col-chunked blockIdx remap (B-panel L2 locality)

#include <hip/hip_runtime.h>
#include <stdint.h>

typedef unsigned short u16;
typedef unsigned int   u32;

using bf16x8 = __attribute__((ext_vector_type(8))) short;
using f32x4  = __attribute__((ext_vector_type(4))) float;

#define N_T   1024
#define N_D   1024
#define N_E   8
#define N_BT  4096
#define LNEPS 1e-5f

// ---------------- helpers ----------------
__device__ __forceinline__ u32 rne2(float a, float b) {
  u32 ua = __float_as_uint(a); ua = (ua + 0x7fffu + ((ua >> 16) & 1u)) >> 16;
  u32 ub = __float_as_uint(b); ub = (ub + 0x7fffu + ((ub >> 16) & 1u)) >> 16;
  return ua | (ub << 16);
}
__device__ __forceinline__ u16 rne1(float a) {
  u32 ua = __float_as_uint(a);
  return (u16)((ua + 0x7fffu + ((ua >> 16) & 1u)) >> 16);
}
__device__ __forceinline__ float bfhi_f(float a) {   // nearest-bf16 value as fp32
  u32 ua = __float_as_uint(a);
  ua = (ua + 0x7fffu + ((ua >> 16) & 1u)) & 0xffff0000u;
  return __uint_as_float(ua);
}
__device__ __forceinline__ int fch(int row) { return (row & 3) ^ ((row >> 2) & 3); }
__device__ __forceinline__ int swz(int row, int chunk) {
  return row * 32 + (((chunk ^ fch(row)) & 3) << 3);
}
__device__ __forceinline__ float wred(float v) {
  #pragma unroll
  for (int o2 = 32; o2 > 0; o2 >>= 1) v += __shfl_xor(v, o2, 64);
  return v;
}
__device__ __forceinline__ f32x4 mfma16(bf16x8 a, bf16x8 b, f32x4 c) {
  return __builtin_amdgcn_mfma_f32_16x16x32_bf16(a, b, c, 0, 0, 0);
}
// async global->LDS, 16B per lane; LDS dest = wave-uniform base + lane*16
typedef __attribute__((address_space(1))) const u32 gas_u32;
typedef __attribute__((address_space(3))) u32 las_u32;
__device__ __forceinline__ void gl16(const void* g, void* l) {
  __builtin_amdgcn_global_load_lds((gas_u32*)g, (las_u32*)l, 16, 0, 0);
}

// ---------------- transpose fp32 [R][C] -> bf16 [C][R] (scale, optional hi/lo split) ---------
template<int SPLIT>
__global__ __launch_bounds__(256)
void transpose_bf16(const float* __restrict__ in, u16* __restrict__ outh,
                    u16* __restrict__ outl, int R, int C, float scale)
{
  __shared__ u16 th[64][68];
  __shared__ u16 tl[SPLIT ? 64 : 1][SPLIT ? 68 : 1];
  const long long zb = (long long)blockIdx.z * R * C;
  const float* srcp = in + zb;
  const int r0 = blockIdx.y * 64, c0 = blockIdx.x * 64;
  const int t = threadIdx.x;
  {
    const int rr = t >> 4, cc = (t & 15) << 2;
    #pragma unroll
    for (int i = 0; i < 4; i++) {
      const int r = rr + i * 16;
      float4 v = *(const float4*)(srcp + (long long)(r0 + r) * C + c0 + cc);
      v.x *= scale; v.y *= scale; v.z *= scale; v.w *= scale;
      if constexpr (SPLIT) {
        float hx = bfhi_f(v.x), hy = bfhi_f(v.y), hz = bfhi_f(v.z), hw = bfhi_f(v.w);
        *(uint2*)&th[r][cc] = make_uint2(rne2(hx, hy), rne2(hz, hw));
        *(uint2*)&tl[r][cc] = make_uint2(rne2(v.x - hx, v.y - hy), rne2(v.z - hz, v.w - hw));
      } else {
        *(uint2*)&th[r][cc] = make_uint2(rne2(v.x, v.y), rne2(v.z, v.w));
      }
    }
  }
  __syncthreads();
  {
    const int c = t >> 2, rs = (t & 3) << 4;
    const long long ob = zb + (long long)(c0 + c) * R + r0 + rs;
    u32 w[8];
    #pragma unroll
    for (int i = 0; i < 8; i++)
      w[i] = (u32)th[rs + 2*i][c] | ((u32)th[rs + 2*i + 1][c] << 16);
    *(uint4*)(outh + ob)     = make_uint4(w[0], w[1], w[2], w[3]);
    *(uint4*)(outh + ob + 8) = make_uint4(w[4], w[5], w[6], w[7]);
    if constexpr (SPLIT) {
      #pragma unroll
      for (int i = 0; i < 8; i++)
        w[i] = (u32)tl[rs + 2*i][c] | ((u32)tl[rs + 2*i + 1][c] << 16);
      *(uint4*)(outl + ob)     = make_uint4(w[0], w[1], w[2], w[3]);
      *(uint4*)(outl + ob + 8) = make_uint4(w[4], w[5], w[6], w[7]);
    }
  }
}

// ---------------- concat scaled QKV bias: [bq*0.125; bk; bv] ----------------
__global__ __launch_bounds__(256)
void bias_cat(const float* __restrict__ bq, const float* __restrict__ bk,
              const float* __restrict__ bv, float* __restrict__ bcat)
{
  const int i = blockIdx.x * 256 + threadIdx.x;
  if (i < 1024)       bcat[i] = bq[i] * 0.125f;
  else if (i < 2048)  bcat[i] = bk[i - 1024];
  else if (i < 3072)  bcat[i] = bv[i - 2048];
}

// ---------------- V^T per-head transpose: hi/lo bf16 [kv][d] (strided) -> [d][kv] ------------
__global__ __launch_bounds__(256)
void vtrans_bf16(const u16* __restrict__ Vh, const u16* __restrict__ Vl, int ldv,
                 u16* __restrict__ Vth, u16* __restrict__ Vtl)
{
  __shared__ u16 th[64][72];
  __shared__ u16 tl[64][72];
  const int bh = blockIdx.y, b = bh >> 4, h = bh & 15;
  const int kt = blockIdx.x, tid = threadIdx.x;
  {
    const int sr = tid >> 2, scb = (tid & 3) << 4;   // kv row, d col base
    const long long off = (long long)(b * N_T + kt * 64 + sr) * ldv + h * 64 + scb;
    const uint4* vh = (const uint4*)(Vh + off);
    const uint4* vl = (const uint4*)(Vl + off);
    *(uint4*)&th[sr][scb]     = vh[0];
    *(uint4*)&th[sr][scb + 8] = vh[1];
    *(uint4*)&tl[sr][scb]     = vl[0];
    *(uint4*)&tl[sr][scb + 8] = vl[1];
  }
  __syncthreads();
  {
    const int od = tid >> 2, os0 = (tid & 3) << 4;   // d row, kv col base
    u16 wh[16], wl[16];
    #pragma unroll
    for (int i = 0; i < 16; i++) { wh[i] = th[os0 + i][od]; wl[i] = tl[os0 + i][od]; }
    u16* oph = Vth + (long long)(bh * 64 + od) * N_T + kt * 64 + os0;
    u16* opl = Vtl + (long long)(bh * 64 + od) * N_T + kt * 64 + os0;
    *(uint4*)oph = make_uint4((u32)wh[0] | ((u32)wh[1] << 16), (u32)wh[2] | ((u32)wh[3] << 16),
                              (u32)wh[4] | ((u32)wh[5] << 16), (u32)wh[6] | ((u32)wh[7] << 16));
    *(uint4*)(oph + 8) = make_uint4((u32)wh[8] | ((u32)wh[9] << 16), (u32)wh[10] | ((u32)wh[11] << 16),
                                    (u32)wh[12] | ((u32)wh[13] << 16), (u32)wh[14] | ((u32)wh[15] << 16));
    *(uint4*)opl = make_uint4((u32)wl[0] | ((u32)wl[1] << 16), (u32)wl[2] | ((u32)wl[3] << 16),
                              (u32)wl[4] | ((u32)wl[5] << 16), (u32)wl[6] | ((u32)wl[7] << 16));
    *(uint4*)(opl + 8) = make_uint4((u32)wl[8] | ((u32)wl[9] << 16), (u32)wl[10] | ((u32)wl[11] << 16),
                                    (u32)wl[12] | ((u32)wl[13] << 16), (u32)wl[14] | ((u32)wl[15] << 16));
  }
}

// ---------------- 128x128x32 MFMA GEMM (4 waves, 4x4 16x16 frags each) ----------------
// ASPLIT: A fp32 -> hi/lo regs -> LDS (3-term with BSPL). Else A bf16 via global_load_lds.
// B always staged via global_load_lds (hi, + lo if BSPL), linear LDS dest with
// inverse-swizzled global source so the swz() read layout is unchanged.
// OBF: 0 fp32 out, 1 bf16 out, 2 split hi/lo bf16 out (Cp, Cp2) with cscale folded.
template<int ASPLIT, int GATHER, int DORELU, int DOSCALE, int OBF, int GROUPED, int BSPL>
__global__ __launch_bounds__(256, 2)
void gemm128(const void* __restrict__ Ap, int lda,
             const u16* __restrict__ Bhp, const u16* __restrict__ Blp,
             long long bstride,
             void* __restrict__ Cp, int ldc,
             const float* __restrict__ biasp, int bias_stride,
             const float* __restrict__ slot_wp,
             const int* __restrict__ tokidx,
             const int2* __restrict__ tilesp, const int* __restrict__ ntilesp,
             int Ksz, void* __restrict__ Cp2, float cscale)
{
  // bijective XCD col-chunked remap (m204): each XCD gets contiguous flat range;
  // flat = by*gx + bx so a chunk = few cols x all row-tiles -> B panels L2-resident.
  const int gx = gridDim.x, nwg = gx * gridDim.y;
  const int orig = blockIdx.y * gx + blockIdx.x;
  const int qq = nwg >> 3, rr8 = nwg & 7;
  const int xcd = orig & 7, slot = orig >> 3;
  const int flat = (xcd < rr8 ? xcd * (qq + 1) : rr8 * (qq + 1) + (xcd - rr8) * qq) + slot;
  const int bxx = flat % gx, byy = flat / gx;

  int e = 0, row0;
  if constexpr (GROUPED) {
    if (bxx >= *ntilesp) return;
    const int2 dsc = tilesp[bxx];
    e = dsc.x; row0 = dsc.y;
  } else {
    row0 = bxx * 128;
  }
  const int col0 = byy * 128;

  __shared__ __align__(16) u16 AhS[128 * 32];
  __shared__ __align__(16) u16 BhS[128 * 32];
  __shared__ __align__(16) u16 AlS[ASPLIT ? 128 * 32 : 8];
  __shared__ __align__(16) u16 BlS[BSPL ? 128 * 32 : 8];

  const int tid = threadIdx.x, wid = tid >> 6, lane = tid & 63;
  const int wm = (wid >> 1) << 6, wn = (wid & 1) << 6;
  const int l15 = lane & 15, l4 = lane >> 4;

  // ---- async staging geometry: wave w fills rows [w*32, w*32+32) of each tile;
  // lane -> row = w*32 + i*16 + (lane>>2), linear chunk = lane&3; global source
  // chunk = (lane&3) ^ fch(row)  (inverse swizzle; read side uses swz() as before)
  const int srow0 = wid * 32 + (lane >> 2);
  const int srow1 = srow0 + 16;
  const int sg0 = ((lane & 3) ^ fch(srow0)) << 3;   // u16 elems
  const int sg1 = ((lane & 3) ^ fch(srow1)) << 3;
  u16* lA0 = &AhS[wid * 1024]; u16* lA1 = &AhS[wid * 1024 + 512];
  u16* lB0 = &BhS[wid * 1024]; u16* lB1 = &BhS[wid * 1024 + 512];
  u16* lBl0 = &BlS[(BSPL ? wid : 0) * 1024];
  u16* lBl1 = &BlS[(BSPL ? wid : 0) * 1024 + (BSPL ? 512 : 0)];

  const u16* Bg0 = Bhp + (long long)e * bstride + (long long)(col0 + srow0) * Ksz + sg0;
  const u16* Bg1 = Bhp + (long long)e * bstride + (long long)(col0 + srow1) * Ksz + sg1;
  const u16* Blg0 = nullptr; const u16* Blg1 = nullptr;
  if constexpr (BSPL) {
    Blg0 = Blp + (long long)e * bstride + (long long)(col0 + srow0) * Ksz + sg0;
    Blg1 = Blp + (long long)e * bstride + (long long)(col0 + srow1) * Ksz + sg1;
  }

  const u16* Ag0 = nullptr; const u16* Ag1 = nullptr;
  if constexpr (!ASPLIT) {
    long long ar0, ar1;
    if constexpr (GATHER) { ar0 = tokidx[row0 + srow0]; ar1 = tokidx[row0 + srow1]; }
    else                  { ar0 = row0 + srow0;          ar1 = row0 + srow1; }
    Ag0 = (const u16*)Ap + ar0 * (long long)lda + sg0;
    Ag1 = (const u16*)Ap + ar1 * (long long)lda + sg1;
  }

  // ---- fp32-A register staging (verified path, QKV/Wo)
  const int prr = tid >> 1, pc2 = (tid & 1) << 1;
  const float* Arow = nullptr;
  uint4 sah0, sah1, sal0, sal1;
  if constexpr (ASPLIT) Arow = (const float*)Ap + (long long)(row0 + prr) * lda;

  auto gloadA = [&](int k0) {
    const float4* ap = (const float4*)(Arow + k0 + pc2 * 8);
    float4 f0 = ap[0], f1 = ap[1], f2 = ap[2], f3 = ap[3];
    float h0 = bfhi_f(f0.x), h1 = bfhi_f(f0.y), h2 = bfhi_f(f0.z), h3 = bfhi_f(f0.w);
    float h4 = bfhi_f(f1.x), h5 = bfhi_f(f1.y), h6 = bfhi_f(f1.z), h7 = bfhi_f(f1.w);
    sah0 = make_uint4(rne2(h0, h1), rne2(h2, h3), rne2(h4, h5), rne2(h6, h7));
    sal0 = make_uint4(rne2(f0.x - h0, f0.y - h1), rne2(f0.z - h2, f0.w - h3),
                      rne2(f1.x - h4, f1.y - h5), rne2(f1.z - h6, f1.w - h7));
    h0 = bfhi_f(f2.x); h1 = bfhi_f(f2.y); h2 = bfhi_f(f2.z); h3 = bfhi_f(f2.w);
    h4 = bfhi_f(f3.x); h5 = bfhi_f(f3.y); h6 = bfhi_f(f3.z); h7 = bfhi_f(f3.w);
    sah1 = make_uint4(rne2(h0, h1), rne2(h2, h3), rne2(h4, h5), rne2(h6, h7));
    sal1 = make_uint4(rne2(f2.x - h0, f2.y - h1), rne2(f2.z - h2, f2.w - h3),
                      rne2(f3.x - h4, f3.y - h5), rne2(f3.z - h6, f3.w - h7));
  };

  f32x4 acc[4][4] = {};

  if constexpr (ASPLIT) gloadA(0);
  const int nk = Ksz >> 5;
  for (int kt = 0; kt < nk; kt++) {
    __syncthreads();                       // readers done with LDS
    const int ko = kt << 5;
    if constexpr (ASPLIT) {
      *(uint4*)&AhS[swz(prr, pc2)]     = sah0;
      *(uint4*)&AhS[swz(prr, pc2 + 1)] = sah1;
      *(uint4*)&AlS[swz(prr, pc2)]     = sal0;
      *(uint4*)&AlS[swz(prr, pc2 + 1)] = sal1;
    } else {
      gl16(Ag0 + ko, lA0);
      gl16(Ag1 + ko, lA1);
    }
    gl16(Bg0 + ko, lB0);
    gl16(Bg1 + ko, lB1);
    if constexpr (BSPL) {
      gl16(Blg0 + ko, lBl0);
      gl16(Blg1 + ko, lBl1);
    }
    asm volatile("s_waitcnt vmcnt(0)" ::: "memory");
    __syncthreads();                       // LDS tile ready for all waves
    if constexpr (ASPLIT) if (kt + 1 < nk) gloadA((kt + 1) << 5);

    bf16x8 ah[4], bh[4], al[ASPLIT ? 4 : 1], bl[BSPL ? 4 : 1];
    #pragma unroll
    for (int i = 0; i < 4; i++) {
      const int ar = wm + i * 16 + l15;
      const int br = wn + i * 16 + l15;
      ah[i] = *(const bf16x8*)&AhS[swz(ar, l4)];
      bh[i] = *(const bf16x8*)&BhS[swz(br, l4)];
      if constexpr (ASPLIT) al[i] = *(const bf16x8*)&AlS[swz(ar, l4)];
      if constexpr (BSPL)   bl[i] = *(const bf16x8*)&BlS[swz(br, l4)];
    }
    #pragma unroll
    for (int i = 0; i < 4; i++) {
      #pragma unroll
      for (int j = 0; j < 4; j++) {
        acc[i][j] = mfma16(ah[i], bh[j], acc[i][j]);
        if constexpr (ASPLIT && BSPL) {
          acc[i][j] = mfma16(ah[i], bl[j], acc[i][j]);
          acc[i][j] = mfma16(al[i], bh[j], acc[i][j]);
        }
      }
    }
  }

  #pragma unroll
  for (int i = 0; i < 4; i++) {
    #pragma unroll
    for (int j = 0; j < 4; j++) {
      const int orow0 = row0 + wm + i * 16 + (l4 << 2);
      const int ocol  = col0 + wn + j * 16 + l15;
      const float bv = biasp[(long long)e * bias_stride + col0 + wn + j * 16 + l15];
      #pragma unroll
      for (int q = 0; q < 4; q++) {
        float v = acc[i][j][q] + bv;
        if constexpr (DORELU) v = fmaxf(v, 0.f);
        const long long orow = orow0 + q;
        if constexpr (DOSCALE) v *= slot_wp[orow];
        if constexpr (OBF == 2) {
          const float vs = v * cscale;
          const float hi = bfhi_f(vs);
          ((u16*)Cp )[orow * ldc + ocol] = (u16)(__float_as_uint(hi) >> 16);
          ((u16*)Cp2)[orow * ldc + ocol] = rne1(vs - hi);
        } else if constexpr (OBF == 1) {
          ((u16*)Cp)[orow * ldc + ocol] = rne1(v);
        } else {
          ((float*)Cp)[orow * ldc + ocol] = v;
        }
      }
    }
  }
}

// ---------------- MFMA flash attention with stoichiometric bias ----------------
// grid (B*H=64, T/128=8), block 256 (4 waves); wave handles 32 q rows.
// Q/K pointers are column-offset views into the fused QKV hi/lo buffers (stride ldq).
__global__ __launch_bounds__(256, 2)
void attn_mfma(const u16* __restrict__ Qh, const u16* __restrict__ Ql,
               const u16* __restrict__ Kh, const u16* __restrict__ Kl, int ldq,
               const u16* __restrict__ Vth, const u16* __restrict__ Vtl,
               const float* __restrict__ frac,
               const float* __restrict__ apos, const float* __restrict__ aneg,
               float* __restrict__ ctx)
{
  __shared__ __align__(16) u16 KhS[64 * 64];   // [kv][d], chunk^(kv&7) swizzle
  __shared__ __align__(16) u16 KlS[64 * 64];
  __shared__ __align__(16) u16 VhS[64 * 64];   // [d][kv], same swizzle
  __shared__ __align__(16) u16 VlS[64 * 64];
  __shared__ __align__(16) u16 PS[4][32][72];  // per-wave P[q][kv], +8 pad
  __shared__ __align__(16) float fjS[64];

  const int bh = blockIdx.x, b = bh >> 4, h = bh & 15;
  const int tid = threadIdx.x, wid = tid >> 6, lane = tid & 63;
  const int l15 = lane & 15, l4 = lane >> 4;
  const int q0 = blockIdx.y * 128 + wid * 32;

  // Q fragments (B-operand: n = q = l15, k-chunk = l4), pre-scaled & pre-split
  bf16x8 qh[2][2], ql[2][2];
  #pragma unroll
  for (int ni = 0; ni < 2; ni++) {
    const long long qoff = (long long)(b * N_T + q0 + ni * 16 + l15) * ldq + h * 64 + l4 * 8;
    #pragma unroll
    for (int ks = 0; ks < 2; ks++) {
      qh[ni][ks] = *(const bf16x8*)(Qh + qoff + ks * 32);
      ql[ni][ks] = *(const bf16x8*)(Ql + qoff + ks * 32);
    }
  }
  float fq[2];
  #pragma unroll
  for (int ni = 0; ni < 2; ni++) fq[ni] = frac[b * N_T + q0 + ni * 16 + l15];
  const float ap = apos[h], an = aneg[h];

  f32x4 acc[4][2] = {};                 // O^T: d = md*16+l4*4+reg, q = nq*16+l15
  float mrun[2] = {-3.0e38f, -3.0e38f}, lrun[2] = {0.f, 0.f};

  const int sr = tid >> 2, scb = (tid & 3) << 4;
  const int ch0 = ((scb >> 3) ^ (sr & 7)) << 3;
  const int ch1 = (((scb >> 3) + 1) ^ (sr & 7)) << 3;

  for (int kt = 0; kt < 16; kt++) {
    __syncthreads();
    {
      const long long koff = (long long)(b * N_T + kt * 64 + sr) * ldq + h * 64 + scb;
      const uint4* khp = (const uint4*)(Kh + koff);
      const uint4* klp = (const uint4*)(Kl + koff);
      const long long voff = (long long)(bh * 64 + sr) * N_T + kt * 64 + scb;
      const uint4* vhp = (const uint4*)(Vth + voff);
      const uint4* vlp = (const uint4*)(Vtl + voff);
      *(uint4*)&KhS[sr * 64 + ch0] = khp[0];
      *(uint4*)&KhS[sr * 64 + ch1] = khp[1];
      *(uint4*)&KlS[sr * 64 + ch0] = klp[0];
      *(uint4*)&KlS[sr * 64 + ch1] = klp[1];
      *(uint4*)&VhS[sr * 64 + ch0] = vhp[0];
      *(uint4*)&VhS[sr * 64 + ch1] = vhp[1];
      *(uint4*)&VlS[sr * 64 + ch0] = vlp[0];
      *(uint4*)&VlS[sr * 64 + ch1] = vlp[1];
    }
    if (tid < 64) fjS[tid] = frac[b * N_T + kt * 64 + tid];
    __syncthreads();

    // ---- S^T = K * Q^T (3-term split)
    f32x4 s[4][2] = {};
    #pragma unroll
    for (int ks = 0; ks < 2; ks++) {
      bf16x8 kh[4], kl[4];
      #pragma unroll
      for (int mj = 0; mj < 4; mj++) {
        const int row = mj * 16 + l15;
        const int ch = (((ks << 2) + l4) ^ (row & 7)) << 3;
        kh[mj] = *(const bf16x8*)&KhS[row * 64 + ch];
        kl[mj] = *(const bf16x8*)&KlS[row * 64 + ch];
      }
      #pragma unroll
      for (int mj = 0; mj < 4; mj++) {
        #pragma unroll
        for (int ni = 0; ni < 2; ni++) {
          s[mj][ni] = mfma16(kh[mj], qh[ni][ks], s[mj][ni]);
          s[mj][ni] = mfma16(kh[mj], ql[ni][ks], s[mj][ni]);
          s[mj][ni] = mfma16(kl[mj], qh[ni][ks], s[mj][ni]);
        }
      }
    }

    // ---- bias (scalar fjS reads) ; kv = mj*16 + l4*4 + r, q = ni*16 + l15
    #pragma unroll
    for (int mj = 0; mj < 4; mj++) {
      const int kvb = mj * 16 + l4 * 4;
      const float f0 = fjS[kvb], f1 = fjS[kvb + 1], f2 = fjS[kvb + 2], f3 = fjS[kvb + 3];
      #pragma unroll
      for (int ni = 0; ni < 2; ni++) {
        float d0 = f0 - fq[ni], d1 = f1 - fq[ni], d2 = f2 - fq[ni], d3 = f3 - fq[ni];
        s[mj][ni][0] += (d0 > 0.f ? ap : an) * d0;
        s[mj][ni][1] += (d1 > 0.f ? ap : an) * d1;
        s[mj][ni][2] += (d2 > 0.f ? ap : an) * d2;
        s[mj][ni][3] += (d3 > 0.f ? ap : an) * d3;
      }
    }

    // ---- online softmax
    #pragma unroll
    for (int ni = 0; ni < 2; ni++) {
      float tm = s[0][ni][0];
      #pragma unroll
      for (int mj = 0; mj < 4; mj++) {
        tm = fmaxf(tm, fmaxf(fmaxf(s[mj][ni][0], s[mj][ni][1]),
                             fmaxf(s[mj][ni][2], s[mj][ni][3])));
      }
      tm = fmaxf(tm, __shfl_xor(tm, 16, 64));
      tm = fmaxf(tm, __shfl_xor(tm, 32, 64));
      const float nm = fmaxf(mrun[ni], tm);
      const float cor = __expf(mrun[ni] - nm);
      mrun[ni] = nm;
      lrun[ni] *= cor;
      #pragma unroll
      for (int md = 0; md < 4; md++) {
        acc[md][ni][0] *= cor; acc[md][ni][1] *= cor;
        acc[md][ni][2] *= cor; acc[md][ni][3] *= cor;
      }
      float rsum = 0.f;
      #pragma unroll
      for (int mj = 0; mj < 4; mj++) {
        #pragma unroll
        for (int r = 0; r < 4; r++) {
          const float p = __expf(s[mj][ni][r] - nm);
          s[mj][ni][r] = p;
          rsum += p;
        }
      }
      rsum += __shfl_xor(rsum, 16, 64);
      rsum += __shfl_xor(rsum, 32, 64);
      lrun[ni] += rsum;
    }

    // ---- P hi -> per-wave LDS (C-write-verified mapping), read B-frags
    #pragma unroll
    for (int ni = 0; ni < 2; ni++) {
      #pragma unroll
      for (int mj = 0; mj < 4; mj++) {
        float h0 = bfhi_f(s[mj][ni][0]), h1 = bfhi_f(s[mj][ni][1]);
        float h2 = bfhi_f(s[mj][ni][2]), h3 = bfhi_f(s[mj][ni][3]);
        u32* dst = (u32*)&PS[wid][ni * 16 + l15][mj * 16 + l4 * 4];
        dst[0] = rne2(h0, h1); dst[1] = rne2(h2, h3);
      }
    }
    bf16x8 pbh[2][2];
    #pragma unroll
    for (int ni = 0; ni < 2; ni++)
      #pragma unroll
      for (int ks = 0; ks < 2; ks++)
        pbh[ni][ks] = *(const bf16x8*)&PS[wid][ni * 16 + l15][ks * 32 + l4 * 8];

    // ---- P lo -> same LDS buffer, read B-frags
    #pragma unroll
    for (int ni = 0; ni < 2; ni++) {
      #pragma unroll
      for (int mj = 0; mj < 4; mj++) {
        float p0 = s[mj][ni][0], p1 = s[mj][ni][1], p2 = s[mj][ni][2], p3 = s[mj][ni][3];
        float h0 = bfhi_f(p0), h1 = bfhi_f(p1), h2 = bfhi_f(p2), h3 = bfhi_f(p3);
        u32* dst = (u32*)&PS[wid][ni * 16 + l15][mj * 16 + l4 * 4];
        dst[0] = rne2(p0 - h0, p1 - h1); dst[1] = rne2(p2 - h2, p3 - h3);
      }
    }
    bf16x8 pbl[2][2];
    #pragma unroll
    for (int ni = 0; ni < 2; ni++)
      #pragma unroll
      for (int ks = 0; ks < 2; ks++)
        pbl[ni][ks] = *(const bf16x8*)&PS[wid][ni * 16 + l15][ks * 32 + l4 * 8];

    // ---- O^T += V^T * P^T (3-term split; linear kv pairing)
    #pragma unroll
    for (int md = 0; md < 4; md++) {
      #pragma unroll
      for (int ks = 0; ks < 2; ks++) {
        const int row = md * 16 + l15;
        const int ch = (((ks << 2) + l4) ^ (row & 7)) << 3;
        const bf16x8 vh = *(const bf16x8*)&VhS[row * 64 + ch];
        const bf16x8 vl = *(const bf16x8*)&VlS[row * 64 + ch];
        #pragma unroll
        for (int nq = 0; nq < 2; nq++) {
          acc[md][nq] = mfma16(vh, pbh[nq][ks], acc[md][nq]);
          acc[md][nq] = mfma16(vh, pbl[nq][ks], acc[md][nq]);
          acc[md][nq] = mfma16(vl, pbh[nq][ks], acc[md][nq]);
        }
      }
    }
  }

  // ---- epilogue: ctx[q][d] = O^T[d][q] / l[q]
  const float inv[2] = {1.f / lrun[0], 1.f / lrun[1]};
  #pragma unroll
  for (int nq = 0; nq < 2; nq++) {
    #pragma unroll
    for (int md = 0; md < 4; md++) {
      float4 o;
      o.x = acc[md][nq][0] * inv[nq];
      o.y = acc[md][nq][1] * inv[nq];
      o.z = acc[md][nq][2] * inv[nq];
      o.w = acc[md][nq][3] * inv[nq];
      *(float4*)(ctx + (long long)(b * N_T + q0 + nq * 16 + l15) * N_D +
                 h * 64 + md * 16 + l4 * 4) = o;
    }
  }
}

// ---------------- LN1 + gate softmax + top2 (wave per token) ----------------
__global__ __launch_bounds__(256, 4)
void ln1_gate(const float* __restrict__ src, const float* __restrict__ attnout,
              const float* __restrict__ g, const float* __restrict__ bb,
              const float* __restrict__ gateW, const float* __restrict__ gateb,
              float* __restrict__ xout, u16* __restrict__ xbf,
              int* __restrict__ counts,
              int2* __restrict__ tok_top, float2* __restrict__ tok_w)
{
  const int wid = threadIdx.x >> 6, lane = threadIdx.x & 63;
  const int t = blockIdx.x * 4 + wid;
  const float4* s4 = (const float4*)(src + (long long)t * N_D);
  const float4* a4 = (const float4*)(attnout + (long long)t * N_D);
  float4 v[4];
  float sum = 0.f;
  #pragma unroll
  for (int c = 0; c < 4; c++) {
    const int idx = c * 64 + lane;
    float4 a = s4[idx], b2 = a4[idx];
    v[c] = make_float4(a.x + b2.x, a.y + b2.y, a.z + b2.z, a.w + b2.w);
    sum += v[c].x + v[c].y + v[c].z + v[c].w;
  }
  sum = wred(sum);
  const float mu = sum * (1.f / 1024.f);
  float s2 = 0.f;
  #pragma unroll
  for (int c = 0; c < 4; c++) {
    float dx = v[c].x - mu, dy = v[c].y - mu, dz = v[c].z - mu, dw = v[c].w - mu;
    s2 += dx * dx + dy * dy + dz * dz + dw * dw;
  }
  s2 = wred(s2);
  const float rs = rsqrtf(s2 * (1.f / 1024.f) + LNEPS);
  float acc[8];
  #pragma unroll
  for (int e2 = 0; e2 < 8; e2++) acc[e2] = 0.f;
  #pragma unroll
  for (int c = 0; c < 4; c++) {
    const int idx = c * 64 + lane;
    float4 gv = ((const float4*)g)[idx], bv = ((const float4*)bb)[idx];
    float xa[4];
    xa[0] = (v[c].x - mu) * rs * gv.x + bv.x;
    xa[1] = (v[c].y - mu) * rs * gv.y + bv.y;
    xa[2] = (v[c].z - mu) * rs * gv.z + bv.z;
    xa[3] = (v[c].w - mu) * rs * gv.w + bv.w;
    ((float4*)(xout + (long long)t * N_D))[idx] = make_float4(xa[0], xa[1], xa[2], xa[3]);
    *(uint2*)&xbf[(long long)t * N_D + idx * 4] =
        make_uint2(rne2(xa[0], xa[1]), rne2(xa[2], xa[3]));
    #pragma unroll
    for (int ii = 0; ii < 4; ii++) {
      const float xs = xa[ii];
      const float4* gw = (const float4*)(gateW + ((long long)(idx * 4 + ii)) * N_E);
      float4 w0 = gw[0], w1 = gw[1];
      acc[0] += xs * w0.x; acc[1] += xs * w0.y; acc[2] += xs * w0.z; acc[3] += xs * w0.w;
      acc[4] += xs * w1.x; acc[5] += xs * w1.y; acc[6] += xs * w1.z; acc[7] += xs * w1.w;
    }
  }
  #pragma unroll
  for (int e2 = 0; e2 < 8; e2++) acc[e2] = wred(acc[e2]);
  if (lane == 0) {
    float lg[8];
    #pragma unroll
    for (int e2 = 0; e2 < 8; e2++) lg[e2] = acc[e2] + gateb[e2];
    float mx = lg[0];
    #pragma unroll
    for (int e2 = 1; e2 < 8; e2++) mx = fmaxf(mx, lg[e2]);
    float Z = 0.f;
    #pragma unroll
    for (int e2 = 0; e2 < 8; e2++) Z += __expf(lg[e2] - mx);
    int e0 = 0; float v0 = lg[0];
    #pragma unroll
    for (int e2 = 1; e2 < 8; e2++) if (lg[e2] > v0) { v0 = lg[e2]; e0 = e2; }
    int e1 = -1; float v1 = -3.4e38f;
    #pragma unroll
    for (int e2 = 0; e2 < 8; e2++) if (e2 != e0 && lg[e2] > v1) { v1 = lg[e2]; e1 = e2; }
    atomicAdd(&counts[e0], 1);
    atomicAdd(&counts[e1], 1);
    tok_top[t] = make_int2(e0, e1);
    tok_w[t] = make_float2(__expf(v0 - mx) / Z, __expf(v1 - mx) / Z);
  }
}

// ---------------- routing: offsets, tile descriptors, padding fill ----------------
__global__ void route_build(const int* __restrict__ counts, int* __restrict__ offsets,
                            int* __restrict__ cursors, int* __restrict__ ntiles,
                            int2* __restrict__ tiles, int* __restrict__ token_idx,
                            float* __restrict__ slot_w)
{
  __shared__ int soff[N_E + 1];
  __shared__ int scnt[N_E];
  if (threadIdx.x == 0) {
    int off = 0, nt = 0;
    for (int ex = 0; ex < N_E; ex++) {
      soff[ex] = off; offsets[ex] = off; cursors[ex] = 0;
      const int cnt = counts[ex];
      scnt[ex] = cnt;
      const int pt = (cnt + 127) >> 7;
      for (int i = 0; i < pt; i++) { tiles[nt] = make_int2(ex, off + i * 128); nt++; }
      off += pt << 7;
    }
    soff[N_E] = off; offsets[N_E] = off;
    *ntiles = nt;
  }
  __syncthreads();
  for (int ex = 0; ex < N_E; ex++)
    for (int s = soff[ex] + scnt[ex] + (int)threadIdx.x; s < soff[ex + 1]; s += (int)blockDim.x) {
      token_idx[s] = 0; slot_w[s] = 0.f;
    }
}

__global__ __launch_bounds__(256)
void route_scatter(const int2* __restrict__ tok_top, const float2* __restrict__ tok_w,
                   const int* __restrict__ offsets, int* __restrict__ cursors,
                   int* __restrict__ token_idx, float* __restrict__ slot_w,
                   int* __restrict__ slotA, int* __restrict__ slotB)
{
  const int t = blockIdx.x * 256 + threadIdx.x;
  if (t >= N_BT) return;
  const int2 ee = tok_top[t];
  const float2 ww = tok_w[t];
  int p = atomicAdd(&cursors[ee.x], 1);
  int s = offsets[ee.x] + p;
  token_idx[s] = t; slot_w[s] = ww.x; slotA[t] = s;
  p = atomicAdd(&cursors[ee.y], 1);
  s = offsets[ee.y] + p;
  token_idx[s] = t; slot_w[s] = ww.y; slotB[t] = s;
}

// ---------------- final: y = LN2(x + out2[sA] + out2[sB]) ----------------
__global__ __launch_bounds__(256, 4)
void final_ln2(const float* __restrict__ x, const float* __restrict__ out2,
               const int* __restrict__ slotA, const int* __restrict__ slotB,
               const float* __restrict__ g, const float* __restrict__ bb,
               float* __restrict__ out)
{
  const int wid = threadIdx.x >> 6, lane = threadIdx.x & 63;
  const int t = blockIdx.x * 4 + wid;
  const int sA = slotA[t], sB = slotB[t];
  const float4* xr = (const float4*)(x + (long long)t * N_D);
  const float4* pa = (const float4*)(out2 + (long long)sA * N_D);
  const float4* pb = (const float4*)(out2 + (long long)sB * N_D);
  float4 v[4];
  float sum = 0.f;
  #pragma unroll
  for (int c = 0; c < 4; c++) {
    const int idx = c * 64 + lane;
    float4 a = xr[idx], b2 = pa[idx], c2 = pb[idx];
    v[c] = make_float4(a.x + b2.x + c2.x, a.y + b2.y + c2.y,
                       a.z + b2.z + c2.z, a.w + b2.w + c2.w);
    sum += v[c].x + v[c].y + v[c].z + v[c].w;
  }
  sum = wred(sum);
  const float mu = sum * (1.f / 1024.f);
  float s2 = 0.f;
  #pragma unroll
  for (int c = 0; c < 4; c++) {
    float dx = v[c].x - mu, dy = v[c].y - mu, dz = v[c].z - mu, dw = v[c].w - mu;
    s2 += dx * dx + dy * dy + dz * dz + dw * dw;
  }
  s2 = wred(s2);
  const float rs = rsqrtf(s2 * (1.f / 1024.f) + LNEPS);
  #pragma unroll
  for (int c = 0; c < 4; c++) {
    const int idx = c * 64 + lane;
    float4 gv = ((const float4*)g)[idx], bv = ((const float4*)bb)[idx];
    float4 o;
    o.x = (v[c].x - mu) * rs * gv.x + bv.x;
    o.y = (v[c].y - mu) * rs * gv.y + bv.y;
    o.z = (v[c].z - mu) * rs * gv.z + bv.z;
    o.w = (v[c].w - mu) * rs * gv.w + bv.w;
    ((float4*)(out + (long long)t * N_D))[idx] = o;
  }
}

// ---------------- launch ----------------
extern "C" void kernel_launch(void* const* d_in, const int* in_sizes, int n_in,
                              void* d_out, int out_size, void* d_ws, size_t ws_size,
                              hipStream_t stream)
{
  const float* src   = (const float*)d_in[0];
  const float* frac  = (const float*)d_in[1];
  const float* Wq    = (const float*)d_in[2];
  const float* bq    = (const float*)d_in[3];
  const float* Wk    = (const float*)d_in[4];
  const float* bk    = (const float*)d_in[5];
  const float* Wv    = (const float*)d_in[6];
  const float* bv    = (const float*)d_in[7];
  const float* Wo    = (const float*)d_in[8];
  const float* bo    = (const float*)d_in[9];
  const float* apos  = (const float*)d_in[10];
  const float* aneg  = (const float*)d_in[11];
  const float* gateW = (const float*)d_in[12];
  const float* gateb = (const float*)d_in[13];
  const float* W1    = (const float*)d_in[14];
  const float* b1    = (const float*)d_in[15];
  const float* W2    = (const float*)d_in[16];
  const float* b2    = (const float*)d_in[17];
  const float* ln1g  = (const float*)d_in[18];
  const float* ln1b  = (const float*)d_in[19];
  const float* ln2g  = (const float*)d_in[20];
  const float* ln2b  = (const float*)d_in[21];
  float* out = (float*)d_out;

  char* ws = (char*)d_ws;
  const size_t MB = 1ull << 20;
  // 0-16 MB: QKV/Wo transposed weights (dead after respective GEMMs).
  //   Bcath [3072][1024] at 0-6, Bcatl at 6-12, WoTh 12-14, WoTl 14-16.
  //   misc (routing, ~140KB) aliases ws+0 after Wo GEMM; xbf aliases ws+4MB then.
  u16* Bcath = (u16*)(ws + 0 * MB);
  u16* Bcatl = (u16*)(ws + 6 * MB);
  u16* WoTh  = (u16*)(ws + 12 * MB);
  u16* WoTl  = (u16*)(ws + 14 * MB);
  u16*   W1T  = (u16*)(ws + 16 * MB);    // 64 MB, dead after FFN GEMM1
  float* out2 = (float*)(ws + 16 * MB);  // <=38 MB, alias (written after W1T dead)
  u16*   W2T  = (u16*)(ws + 80 * MB);    // 64 MB
  u16*   QKVh = (u16*)(ws + 144 * MB);   // 24 MB: [4096][3072] hi (Q|K|V)
  u16*   QKVl = (u16*)(ws + 168 * MB);   // 24 MB lo
  u16*   Vth  = (u16*)(ws + 192 * MB);   // 8 MB per-head V^T hi
  u16*   Vtl  = (u16*)(ws + 200 * MB);   // 8 MB per-head V^T lo
  float* ctxb = (float*)(ws + 208 * MB); // 16 MB
  float* attnb= (float*)(ws + 144 * MB); // 16 MB alias (QKVh dead after attn)
  u16*   hb   = (u16*)(ws + 144 * MB);   // <=72 MB alias (all of 144-216 dead by FFN1)
  float* xb   = (float*)(ws + 224 * MB); // 16 MB fp32 -> total 240 MB
  u16*   xbf  = (u16*)(ws + 4 * MB);     // 8 MB bf16 alias (Bcat dead by ln1_gate)
  float* bcat = (float*)(ws + 240 * MB); // 12 KB
  char* misc = ws + 0;                   // aliases Bcat region (dead by routing phase)
  int*    counts    = (int*)(misc);
  int*    cursors   = (int*)(misc + 64);
  int*    offsets   = (int*)(misc + 128);
  int*    ntiles    = (int*)(misc + 256);
  int2*   tiles     = (int2*)(misc + 512);
  int2*   tok_top   = (int2*)(misc + 2048);
  float2* tok_w     = (float2*)(misc + 2048 + 32768);
  int*    token_idx = (int*)(misc + 2048 + 65536);
  float*  slot_w    = (float*)(misc + 2048 + 65536 + 36864);
  int*    slotA     = (int*)(misc + 2048 + 65536 + 73728);
  int*    slotB     = (int*)(misc + 2048 + 65536 + 73728 + 16384);

  dim3 b256(256);
  // weight transposes: Wq scaled by 0.125 into Bcat rows 0-1023; Wk, Wv follow
  transpose_bf16<1><<<dim3(16, 16, 1), b256, 0, stream>>>(Wq, Bcath, Bcatl,
                                                          1024, 1024, 0.125f);
  transpose_bf16<1><<<dim3(16, 16, 1), b256, 0, stream>>>(Wk, Bcath + 1024 * 1024,
                                                          Bcatl + 1024 * 1024, 1024, 1024, 1.0f);
  transpose_bf16<1><<<dim3(16, 16, 1), b256, 0, stream>>>(Wv, Bcath + 2048 * 1024,
                                                          Bcatl + 2048 * 1024, 1024, 1024, 1.0f);
  transpose_bf16<1><<<dim3(16, 16, 1), b256, 0, stream>>>(Wo, WoTh, WoTl, 1024, 1024, 1.0f);
  transpose_bf16<0><<<dim3(64, 16, 8), b256, 0, stream>>>(W1, W1T, nullptr, 1024, 4096, 1.0f);
  transpose_bf16<0><<<dim3(16, 64, 8), b256, 0, stream>>>(W2, W2T, nullptr, 4096, 1024, 1.0f);
  bias_cat<<<dim3(12), b256, 0, stream>>>(bq, bk, bv, bcat);

  // fused QKV projection: [4096][3072] hi/lo bf16 (Q cols pre-scaled via Wq/bq)
  gemm128<1, 0, 0, 0, 2, 0, 1><<<dim3(32, 24), b256, 0, stream>>>(
      src, 1024, Bcath, Bcatl, 0, QKVh, 3072, bcat, 0, nullptr, nullptr, nullptr, nullptr,
      1024, QKVl, 1.0f);

  vtrans_bf16<<<dim3(16, 64), b256, 0, stream>>>(QKVh + 2048, QKVl + 2048, 3072, Vth, Vtl);

  attn_mfma<<<dim3(64, 8), b256, 0, stream>>>(QKVh, QKVl, QKVh + 1024, QKVl + 1024, 3072,
                                              Vth, Vtl, frac, apos, aneg, ctxb);

  gemm128<1, 0, 0, 0, 0, 0, 1><<<dim3(32, 8), b256, 0, stream>>>(
      ctxb, 1024, WoTh, WoTl, 0, attnb, 1024, bo, 0, nullptr, nullptr, nullptr, nullptr,
      1024, nullptr, 1.0f);

  hipMemsetAsync(counts, 0, 32, stream);   // misc aliases Bcat region (dead after QKV/Wo)
  ln1_gate<<<dim3(1024), b256, 0, stream>>>(src, attnb, ln1g, ln1b, gateW, gateb,
                                            xb, xbf, counts, tok_top, tok_w);
  route_build<<<dim3(1), dim3(64), 0, stream>>>(counts, offsets, cursors, ntiles,
                                                tiles, token_idx, slot_w);
  route_scatter<<<dim3(16), b256, 0, stream>>>(tok_top, tok_w, offsets, cursors,
                                               token_idx, slot_w, slotA, slotB);

  // grouped MoE FFN (bf16 A+B, global_load_lds staging)
  gemm128<0, 1, 1, 0, 1, 1, 0><<<dim3(72, 32), b256, 0, stream>>>(
      xbf, 1024, W1T, nullptr, 4096ll * 1024, hb, 4096, b1, 4096,
      nullptr, token_idx, tiles, ntiles, 1024, nullptr, 1.0f);
  gemm128<0, 0, 0, 1, 0, 1, 0><<<dim3(72, 8), b256, 0, stream>>>(
      hb, 4096, W2T, nullptr, 1024ll * 4096, out2, 1024, b2, 1024,
      slot_w, nullptr, tiles, ntiles, 4096, nullptr, 1.0f);

  final_ln2<<<dim3(1024), b256, 0, stream>>>(xb, out2, slotA, slotB, ln2g, ln2b, out);
}

// Round 7
// 670.108 us; speedup vs baseline: 2.3158x; 1.0799x over previous
//
// CustomTransformerEncoderMoELayerStoich — MI355X (gfx950)
// Round 7: R6 (passing) + double-buffered LDS K-loop (plain bf16 GEMM path) and
// CG-blocked XCD decode (per-XCD = CG columns x all tiles, tile-major traversal).
// Attention core and ASPLIT GEMM loop unchanged.

#include <hip/hip_runtime.h>
#include <stdint.h>

typedef unsigned short u16;
typedef unsigned int   u32;

using bf16x8 = __attribute__((ext_vector_type(8))) short;
using f32x4  = __attribute__((ext_vector_type(4))) float;

#define N_T   1024
#define N_D   1024
#define N_E   8
#define N_BT  4096
#define LNEPS 1e-5f

// ---------------- helpers ----------------
__device__ __forceinline__ u32 rne2(float a, float b) {
  u32 ua = __float_as_uint(a); ua = (ua + 0x7fffu + ((ua >> 16) & 1u)) >> 16;
  u32 ub = __float_as_uint(b); ub = (ub + 0x7fffu + ((ub >> 16) & 1u)) >> 16;
  return ua | (ub << 16);
}
__device__ __forceinline__ u16 rne1(float a) {
  u32 ua = __float_as_uint(a);
  return (u16)((ua + 0x7fffu + ((ua >> 16) & 1u)) >> 16);
}
__device__ __forceinline__ float bfhi_f(float a) {   // nearest-bf16 value as fp32
  u32 ua = __float_as_uint(a);
  ua = (ua + 0x7fffu + ((ua >> 16) & 1u)) & 0xffff0000u;
  return __uint_as_float(ua);
}
__device__ __forceinline__ int fch(int row) { return (row & 3) ^ ((row >> 2) & 3); }
__device__ __forceinline__ int swz(int row, int chunk) {
  return row * 32 + (((chunk ^ fch(row)) & 3) << 3);
}
__device__ __forceinline__ float wred(float v) {
  #pragma unroll
  for (int o2 = 32; o2 > 0; o2 >>= 1) v += __shfl_xor(v, o2, 64);
  return v;
}
__device__ __forceinline__ f32x4 mfma16(bf16x8 a, bf16x8 b, f32x4 c) {
  return __builtin_amdgcn_mfma_f32_16x16x32_bf16(a, b, c, 0, 0, 0);
}
// async global->LDS, 16B per lane; LDS dest = wave-uniform base + lane*16
typedef __attribute__((address_space(1))) const u32 gas_u32;
typedef __attribute__((address_space(3))) u32 las_u32;
__device__ __forceinline__ void gl16(const void* g, void* l) {
  __builtin_amdgcn_global_load_lds((gas_u32*)g, (las_u32*)l, 16, 0, 0);
}

// ---------------- transpose fp32 [R][C] -> bf16 [C][R] (scale, optional hi/lo split) ---------
template<int SPLIT>
__global__ __launch_bounds__(256)
void transpose_bf16(const float* __restrict__ in, u16* __restrict__ outh,
                    u16* __restrict__ outl, int R, int C, float scale)
{
  __shared__ u16 th[64][68];
  __shared__ u16 tl[SPLIT ? 64 : 1][SPLIT ? 68 : 1];
  const long long zb = (long long)blockIdx.z * R * C;
  const float* srcp = in + zb;
  const int r0 = blockIdx.y * 64, c0 = blockIdx.x * 64;
  const int t = threadIdx.x;
  {
    const int rr = t >> 4, cc = (t & 15) << 2;
    #pragma unroll
    for (int i = 0; i < 4; i++) {
      const int r = rr + i * 16;
      float4 v = *(const float4*)(srcp + (long long)(r0 + r) * C + c0 + cc);
      v.x *= scale; v.y *= scale; v.z *= scale; v.w *= scale;
      if constexpr (SPLIT) {
        float hx = bfhi_f(v.x), hy = bfhi_f(v.y), hz = bfhi_f(v.z), hw = bfhi_f(v.w);
        *(uint2*)&th[r][cc] = make_uint2(rne2(hx, hy), rne2(hz, hw));
        *(uint2*)&tl[r][cc] = make_uint2(rne2(v.x - hx, v.y - hy), rne2(v.z - hz, v.w - hw));
      } else {
        *(uint2*)&th[r][cc] = make_uint2(rne2(v.x, v.y), rne2(v.z, v.w));
      }
    }
  }
  __syncthreads();
  {
    const int c = t >> 2, rs = (t & 3) << 4;
    const long long ob = zb + (long long)(c0 + c) * R + r0 + rs;
    u32 w[8];
    #pragma unroll
    for (int i = 0; i < 8; i++)
      w[i] = (u32)th[rs + 2*i][c] | ((u32)th[rs + 2*i + 1][c] << 16);
    *(uint4*)(outh + ob)     = make_uint4(w[0], w[1], w[2], w[3]);
    *(uint4*)(outh + ob + 8) = make_uint4(w[4], w[5], w[6], w[7]);
    if constexpr (SPLIT) {
      #pragma unroll
      for (int i = 0; i < 8; i++)
        w[i] = (u32)tl[rs + 2*i][c] | ((u32)tl[rs + 2*i + 1][c] << 16);
      *(uint4*)(outl + ob)     = make_uint4(w[0], w[1], w[2], w[3]);
      *(uint4*)(outl + ob + 8) = make_uint4(w[4], w[5], w[6], w[7]);
    }
  }
}

// ---------------- concat scaled QKV bias: [bq*0.125; bk; bv] ----------------
__global__ __launch_bounds__(256)
void bias_cat(const float* __restrict__ bq, const float* __restrict__ bk,
              const float* __restrict__ bv, float* __restrict__ bcat)
{
  const int i = blockIdx.x * 256 + threadIdx.x;
  if (i < 1024)       bcat[i] = bq[i] * 0.125f;
  else if (i < 2048)  bcat[i] = bk[i - 1024];
  else if (i < 3072)  bcat[i] = bv[i - 2048];
}

// ---------------- V^T per-head transpose: hi/lo bf16 [kv][d] (strided) -> [d][kv] ------------
__global__ __launch_bounds__(256)
void vtrans_bf16(const u16* __restrict__ Vh, const u16* __restrict__ Vl, int ldv,
                 u16* __restrict__ Vth, u16* __restrict__ Vtl)
{
  __shared__ u16 th[64][72];
  __shared__ u16 tl[64][72];
  const int bh = blockIdx.y, b = bh >> 4, h = bh & 15;
  const int kt = blockIdx.x, tid = threadIdx.x;
  {
    const int sr = tid >> 2, scb = (tid & 3) << 4;   // kv row, d col base
    const long long off = (long long)(b * N_T + kt * 64 + sr) * ldv + h * 64 + scb;
    const uint4* vh = (const uint4*)(Vh + off);
    const uint4* vl = (const uint4*)(Vl + off);
    *(uint4*)&th[sr][scb]     = vh[0];
    *(uint4*)&th[sr][scb + 8] = vh[1];
    *(uint4*)&tl[sr][scb]     = vl[0];
    *(uint4*)&tl[sr][scb + 8] = vl[1];
  }
  __syncthreads();
  {
    const int od = tid >> 2, os0 = (tid & 3) << 4;   // d row, kv col base
    u16 wh[16], wl[16];
    #pragma unroll
    for (int i = 0; i < 16; i++) { wh[i] = th[os0 + i][od]; wl[i] = tl[os0 + i][od]; }
    u16* oph = Vth + (long long)(bh * 64 + od) * N_T + kt * 64 + os0;
    u16* opl = Vtl + (long long)(bh * 64 + od) * N_T + kt * 64 + os0;
    *(uint4*)oph = make_uint4((u32)wh[0] | ((u32)wh[1] << 16), (u32)wh[2] | ((u32)wh[3] << 16),
                              (u32)wh[4] | ((u32)wh[5] << 16), (u32)wh[6] | ((u32)wh[7] << 16));
    *(uint4*)(oph + 8) = make_uint4((u32)wh[8] | ((u32)wh[9] << 16), (u32)wh[10] | ((u32)wh[11] << 16),
                                    (u32)wh[12] | ((u32)wh[13] << 16), (u32)wh[14] | ((u32)wh[15] << 16));
    *(uint4*)opl = make_uint4((u32)wl[0] | ((u32)wl[1] << 16), (u32)wl[2] | ((u32)wl[3] << 16),
                              (u32)wl[4] | ((u32)wl[5] << 16), (u32)wl[6] | ((u32)wl[7] << 16));
    *(uint4*)(opl + 8) = make_uint4((u32)wl[8] | ((u32)wl[9] << 16), (u32)wl[10] | ((u32)wl[11] << 16),
                                    (u32)wl[12] | ((u32)wl[13] << 16), (u32)wl[14] | ((u32)wl[15] << 16));
  }
}

// ---------------- 128x128x32 MFMA GEMM (4 waves, 4x4 16x16 frags each) ----------------
// ASPLIT=1: A fp32 -> hi/lo regs -> LDS (3-term), B hi+lo via global_load_lds, single-buffer
//           2-barrier loop (A reg prefetch pipelines the latency).
// ASPLIT=0: A,B bf16 via global_load_lds into DOUBLE-BUFFERED LDS; next tile staged before
//           current tile's MFMAs (T3-min structure) -> HBM latency hidden under compute.
// CG-blocked XCD decode: per-XCD chunk = CG columns x all tiles, tile-major within chunk.
// OBF: 0 fp32 out, 1 bf16 out, 2 split hi/lo bf16 out (Cp, Cp2) with cscale folded.
template<int ASPLIT, int GATHER, int DORELU, int DOSCALE, int OBF, int GROUPED, int CG>
__global__ __launch_bounds__(256, 2)
void gemm128(const void* __restrict__ Ap, int lda,
             const u16* __restrict__ Bhp, const u16* __restrict__ Blp,
             long long bstride,
             void* __restrict__ Cp, int ldc,
             const float* __restrict__ biasp, int bias_stride,
             const float* __restrict__ slot_wp,
             const int* __restrict__ tokidx,
             const int2* __restrict__ tilesp, const int* __restrict__ ntilesp,
             int Ksz, void* __restrict__ Cp2, float cscale)
{
  // XCD remap (nwg % 8 == 0 for all grids used) + CG-blocked decode (CG | gridDim.y).
  const int gx = gridDim.x, nwg = gx * gridDim.y;
  const int orig = blockIdx.y * gx + blockIdx.x;
  const int flat = (orig & 7) * (nwg >> 3) + (orig >> 3);
  const int cgsz = gx * CG;
  const int colg = flat / cgsz, rem = flat % cgsz;
  const int bxx = rem / CG;
  const int byy = colg * CG + rem % CG;

  int e = 0, row0;
  if constexpr (GROUPED) {
    if (bxx >= *ntilesp) return;
    const int2 dsc = tilesp[bxx];
    e = dsc.x; row0 = dsc.y;
  } else {
    row0 = bxx * 128;
  }
  const int col0 = byy * 128;

  __shared__ __align__(16) u16 AhS[ASPLIT ? 1 : 2][128 * 32];
  __shared__ __align__(16) u16 BhS[ASPLIT ? 1 : 2][128 * 32];
  __shared__ __align__(16) u16 AlS[ASPLIT ? 128 * 32 : 8];
  __shared__ __align__(16) u16 BlS[ASPLIT ? 128 * 32 : 8];

  const int tid = threadIdx.x, wid = tid >> 6, lane = tid & 63;
  const int wm = (wid >> 1) << 6, wn = (wid & 1) << 6;
  const int l15 = lane & 15, l4 = lane >> 4;

  // async staging geometry: wave w fills rows [w*32, w*32+32); lane -> row, linear chunk
  // lane&3; global chunk = (lane&3)^fch(row) (inverse swizzle; read side uses swz()).
  const int srow0 = wid * 32 + (lane >> 2);
  const int srow1 = srow0 + 16;
  const int sg0 = ((lane & 3) ^ fch(srow0)) << 3;   // u16 elems
  const int sg1 = ((lane & 3) ^ fch(srow1)) << 3;
  const int lo0 = wid * 1024, lo1 = wid * 1024 + 512;

  const u16* Bg0 = Bhp + (long long)e * bstride + (long long)(col0 + srow0) * Ksz + sg0;
  const u16* Bg1 = Bhp + (long long)e * bstride + (long long)(col0 + srow1) * Ksz + sg1;
  const u16* Blg0 = nullptr; const u16* Blg1 = nullptr;
  if constexpr (ASPLIT) {
    Blg0 = Blp + (long long)e * bstride + (long long)(col0 + srow0) * Ksz + sg0;
    Blg1 = Blp + (long long)e * bstride + (long long)(col0 + srow1) * Ksz + sg1;
  }

  const u16* Ag0 = nullptr; const u16* Ag1 = nullptr;
  if constexpr (!ASPLIT) {
    long long ar0, ar1;
    if constexpr (GATHER) { ar0 = tokidx[row0 + srow0]; ar1 = tokidx[row0 + srow1]; }
    else                  { ar0 = row0 + srow0;          ar1 = row0 + srow1; }
    Ag0 = (const u16*)Ap + ar0 * (long long)lda + sg0;
    Ag1 = (const u16*)Ap + ar1 * (long long)lda + sg1;
  }

  f32x4 acc[4][4] = {};
  const int nk = Ksz >> 5;

  if constexpr (!ASPLIT) {
    // ===== double-buffered plain-bf16 path =====
    gl16(Ag0, &AhS[0][lo0]); gl16(Ag1, &AhS[0][lo1]);
    gl16(Bg0, &BhS[0][lo0]); gl16(Bg1, &BhS[0][lo1]);
    asm volatile("s_waitcnt vmcnt(0)" ::: "memory");
    __syncthreads();
    int cur = 0;
    for (int kt = 0; kt < nk; kt++) {
      if (kt + 1 < nk) {
        const int ko = (kt + 1) << 5;
        gl16(Ag0 + ko, &AhS[cur ^ 1][lo0]);
        gl16(Ag1 + ko, &AhS[cur ^ 1][lo1]);
        gl16(Bg0 + ko, &BhS[cur ^ 1][lo0]);
        gl16(Bg1 + ko, &BhS[cur ^ 1][lo1]);
      }
      bf16x8 ah[4], bh[4];
      #pragma unroll
      for (int i = 0; i < 4; i++) {
        ah[i] = *(const bf16x8*)&AhS[cur][swz(wm + i * 16 + l15, l4)];
        bh[i] = *(const bf16x8*)&BhS[cur][swz(wn + i * 16 + l15, l4)];
      }
      #pragma unroll
      for (int i = 0; i < 4; i++)
        #pragma unroll
        for (int j = 0; j < 4; j++)
          acc[i][j] = mfma16(ah[i], bh[j], acc[i][j]);
      asm volatile("s_waitcnt vmcnt(0)" ::: "memory");
      __syncthreads();
      cur ^= 1;
    }
  } else {
    // ===== fp32-A split path (verified R6 structure) =====
    const int prr = tid >> 1, pc2 = (tid & 1) << 1;
    const float* Arow = (const float*)Ap + (long long)(row0 + prr) * lda;
    uint4 sah0, sah1, sal0, sal1;
    auto gloadA = [&](int k0) {
      const float4* ap = (const float4*)(Arow + k0 + pc2 * 8);
      float4 f0 = ap[0], f1 = ap[1], f2 = ap[2], f3 = ap[3];
      float h0 = bfhi_f(f0.x), h1 = bfhi_f(f0.y), h2 = bfhi_f(f0.z), h3 = bfhi_f(f0.w);
      float h4 = bfhi_f(f1.x), h5 = bfhi_f(f1.y), h6 = bfhi_f(f1.z), h7 = bfhi_f(f1.w);
      sah0 = make_uint4(rne2(h0, h1), rne2(h2, h3), rne2(h4, h5), rne2(h6, h7));
      sal0 = make_uint4(rne2(f0.x - h0, f0.y - h1), rne2(f0.z - h2, f0.w - h3),
                        rne2(f1.x - h4, f1.y - h5), rne2(f1.z - h6, f1.w - h7));
      h0 = bfhi_f(f2.x); h1 = bfhi_f(f2.y); h2 = bfhi_f(f2.z); h3 = bfhi_f(f2.w);
      h4 = bfhi_f(f3.x); h5 = bfhi_f(f3.y); h6 = bfhi_f(f3.z); h7 = bfhi_f(f3.w);
      sah1 = make_uint4(rne2(h0, h1), rne2(h2, h3), rne2(h4, h5), rne2(h6, h7));
      sal1 = make_uint4(rne2(f2.x - h0, f2.y - h1), rne2(f2.z - h2, f2.w - h3),
                        rne2(f3.x - h4, f3.y - h5), rne2(f3.z - h6, f3.w - h7));
    };
    gloadA(0);
    for (int kt = 0; kt < nk; kt++) {
      __syncthreads();
      const int ko = kt << 5;
      *(uint4*)&AhS[0][swz(prr, pc2)]     = sah0;
      *(uint4*)&AhS[0][swz(prr, pc2 + 1)] = sah1;
      *(uint4*)&AlS[swz(prr, pc2)]        = sal0;
      *(uint4*)&AlS[swz(prr, pc2 + 1)]    = sal1;
      gl16(Bg0 + ko, &BhS[0][lo0]);
      gl16(Bg1 + ko, &BhS[0][lo1]);
      gl16(Blg0 + ko, &BlS[lo0]);
      gl16(Blg1 + ko, &BlS[lo1]);
      asm volatile("s_waitcnt vmcnt(0)" ::: "memory");
      __syncthreads();
      if (kt + 1 < nk) gloadA((kt + 1) << 5);

      bf16x8 ah[4], bh[4], al[4], bl[4];
      #pragma unroll
      for (int i = 0; i < 4; i++) {
        const int ar = wm + i * 16 + l15;
        const int br = wn + i * 16 + l15;
        ah[i] = *(const bf16x8*)&AhS[0][swz(ar, l4)];
        bh[i] = *(const bf16x8*)&BhS[0][swz(br, l4)];
        al[i] = *(const bf16x8*)&AlS[swz(ar, l4)];
        bl[i] = *(const bf16x8*)&BlS[swz(br, l4)];
      }
      #pragma unroll
      for (int i = 0; i < 4; i++) {
        #pragma unroll
        for (int j = 0; j < 4; j++) {
          acc[i][j] = mfma16(ah[i], bh[j], acc[i][j]);
          acc[i][j] = mfma16(ah[i], bl[j], acc[i][j]);
          acc[i][j] = mfma16(al[i], bh[j], acc[i][j]);
        }
      }
    }
  }

  #pragma unroll
  for (int i = 0; i < 4; i++) {
    #pragma unroll
    for (int j = 0; j < 4; j++) {
      const int orow0 = row0 + wm + i * 16 + (l4 << 2);
      const int ocol  = col0 + wn + j * 16 + l15;
      const float bv = biasp[(long long)e * bias_stride + col0 + wn + j * 16 + l15];
      #pragma unroll
      for (int q = 0; q < 4; q++) {
        float v = acc[i][j][q] + bv;
        if constexpr (DORELU) v = fmaxf(v, 0.f);
        const long long orow = orow0 + q;
        if constexpr (DOSCALE) v *= slot_wp[orow];
        if constexpr (OBF == 2) {
          const float vs = v * cscale;
          const float hi = bfhi_f(vs);
          ((u16*)Cp )[orow * ldc + ocol] = (u16)(__float_as_uint(hi) >> 16);
          ((u16*)Cp2)[orow * ldc + ocol] = rne1(vs - hi);
        } else if constexpr (OBF == 1) {
          ((u16*)Cp)[orow * ldc + ocol] = rne1(v);
        } else {
          ((float*)Cp)[orow * ldc + ocol] = v;
        }
      }
    }
  }
}

// ---------------- MFMA flash attention with stoichiometric bias ----------------
// grid (B*H=64, T/128=8), block 256 (4 waves); wave handles 32 q rows.
// Q/K pointers are column-offset views into the fused QKV hi/lo buffers (stride ldq).
__global__ __launch_bounds__(256, 2)
void attn_mfma(const u16* __restrict__ Qh, const u16* __restrict__ Ql,
               const u16* __restrict__ Kh, const u16* __restrict__ Kl, int ldq,
               const u16* __restrict__ Vth, const u16* __restrict__ Vtl,
               const float* __restrict__ frac,
               const float* __restrict__ apos, const float* __restrict__ aneg,
               float* __restrict__ ctx)
{
  __shared__ __align__(16) u16 KhS[64 * 64];   // [kv][d], chunk^(kv&7) swizzle
  __shared__ __align__(16) u16 KlS[64 * 64];
  __shared__ __align__(16) u16 VhS[64 * 64];   // [d][kv], same swizzle
  __shared__ __align__(16) u16 VlS[64 * 64];
  __shared__ __align__(16) u16 PS[4][32][72];  // per-wave P[q][kv], +8 pad
  __shared__ __align__(16) float fjS[64];

  const int bh = blockIdx.x, b = bh >> 4, h = bh & 15;
  const int tid = threadIdx.x, wid = tid >> 6, lane = tid & 63;
  const int l15 = lane & 15, l4 = lane >> 4;
  const int q0 = blockIdx.y * 128 + wid * 32;

  // Q fragments (B-operand: n = q = l15, k-chunk = l4), pre-scaled & pre-split
  bf16x8 qh[2][2], ql[2][2];
  #pragma unroll
  for (int ni = 0; ni < 2; ni++) {
    const long long qoff = (long long)(b * N_T + q0 + ni * 16 + l15) * ldq + h * 64 + l4 * 8;
    #pragma unroll
    for (int ks = 0; ks < 2; ks++) {
      qh[ni][ks] = *(const bf16x8*)(Qh + qoff + ks * 32);
      ql[ni][ks] = *(const bf16x8*)(Ql + qoff + ks * 32);
    }
  }
  float fq[2];
  #pragma unroll
  for (int ni = 0; ni < 2; ni++) fq[ni] = frac[b * N_T + q0 + ni * 16 + l15];
  const float ap = apos[h], an = aneg[h];

  f32x4 acc[4][2] = {};                 // O^T: d = md*16+l4*4+reg, q = nq*16+l15
  float mrun[2] = {-3.0e38f, -3.0e38f}, lrun[2] = {0.f, 0.f};

  const int sr = tid >> 2, scb = (tid & 3) << 4;
  const int ch0 = ((scb >> 3) ^ (sr & 7)) << 3;
  const int ch1 = (((scb >> 3) + 1) ^ (sr & 7)) << 3;

  for (int kt = 0; kt < 16; kt++) {
    __syncthreads();
    {
      const long long koff = (long long)(b * N_T + kt * 64 + sr) * ldq + h * 64 + scb;
      const uint4* khp = (const uint4*)(Kh + koff);
      const uint4* klp = (const uint4*)(Kl + koff);
      const long long voff = (long long)(bh * 64 + sr) * N_T + kt * 64 + scb;
      const uint4* vhp = (const uint4*)(Vth + voff);
      const uint4* vlp = (const uint4*)(Vtl + voff);
      *(uint4*)&KhS[sr * 64 + ch0] = khp[0];
      *(uint4*)&KhS[sr * 64 + ch1] = khp[1];
      *(uint4*)&KlS[sr * 64 + ch0] = klp[0];
      *(uint4*)&KlS[sr * 64 + ch1] = klp[1];
      *(uint4*)&VhS[sr * 64 + ch0] = vhp[0];
      *(uint4*)&VhS[sr * 64 + ch1] = vhp[1];
      *(uint4*)&VlS[sr * 64 + ch0] = vlp[0];
      *(uint4*)&VlS[sr * 64 + ch1] = vlp[1];
    }
    if (tid < 64) fjS[tid] = frac[b * N_T + kt * 64 + tid];
    __syncthreads();

    // ---- S^T = K * Q^T (3-term split)
    f32x4 s[4][2] = {};
    #pragma unroll
    for (int ks = 0; ks < 2; ks++) {
      bf16x8 kh[4], kl[4];
      #pragma unroll
      for (int mj = 0; mj < 4; mj++) {
        const int row = mj * 16 + l15;
        const int ch = (((ks << 2) + l4) ^ (row & 7)) << 3;
        kh[mj] = *(const bf16x8*)&KhS[row * 64 + ch];
        kl[mj] = *(const bf16x8*)&KlS[row * 64 + ch];
      }
      #pragma unroll
      for (int mj = 0; mj < 4; mj++) {
        #pragma unroll
        for (int ni = 0; ni < 2; ni++) {
          s[mj][ni] = mfma16(kh[mj], qh[ni][ks], s[mj][ni]);
          s[mj][ni] = mfma16(kh[mj], ql[ni][ks], s[mj][ni]);
          s[mj][ni] = mfma16(kl[mj], qh[ni][ks], s[mj][ni]);
        }
      }
    }

    // ---- bias (scalar fjS reads) ; kv = mj*16 + l4*4 + r, q = ni*16 + l15
    #pragma unroll
    for (int mj = 0; mj < 4; mj++) {
      const int kvb = mj * 16 + l4 * 4;
      const float f0 = fjS[kvb], f1 = fjS[kvb + 1], f2 = fjS[kvb + 2], f3 = fjS[kvb + 3];
      #pragma unroll
      for (int ni = 0; ni < 2; ni++) {
        float d0 = f0 - fq[ni], d1 = f1 - fq[ni], d2 = f2 - fq[ni], d3 = f3 - fq[ni];
        s[mj][ni][0] += (d0 > 0.f ? ap : an) * d0;
        s[mj][ni][1] += (d1 > 0.f ? ap : an) * d1;
        s[mj][ni][2] += (d2 > 0.f ? ap : an) * d2;
        s[mj][ni][3] += (d3 > 0.f ? ap : an) * d3;
      }
    }

    // ---- online softmax
    #pragma unroll
    for (int ni = 0; ni < 2; ni++) {
      float tm = s[0][ni][0];
      #pragma unroll
      for (int mj = 0; mj < 4; mj++) {
        tm = fmaxf(tm, fmaxf(fmaxf(s[mj][ni][0], s[mj][ni][1]),
                             fmaxf(s[mj][ni][2], s[mj][ni][3])));
      }
      tm = fmaxf(tm, __shfl_xor(tm, 16, 64));
      tm = fmaxf(tm, __shfl_xor(tm, 32, 64));
      const float nm = fmaxf(mrun[ni], tm);
      const float cor = __expf(mrun[ni] - nm);
      mrun[ni] = nm;
      lrun[ni] *= cor;
      #pragma unroll
      for (int md = 0; md < 4; md++) {
        acc[md][ni][0] *= cor; acc[md][ni][1] *= cor;
        acc[md][ni][2] *= cor; acc[md][ni][3] *= cor;
      }
      float rsum = 0.f;
      #pragma unroll
      for (int mj = 0; mj < 4; mj++) {
        #pragma unroll
        for (int r = 0; r < 4; r++) {
          const float p = __expf(s[mj][ni][r] - nm);
          s[mj][ni][r] = p;
          rsum += p;
        }
      }
      rsum += __shfl_xor(rsum, 16, 64);
      rsum += __shfl_xor(rsum, 32, 64);
      lrun[ni] += rsum;
    }

    // ---- P hi -> per-wave LDS (C-write-verified mapping), read B-frags
    #pragma unroll
    for (int ni = 0; ni < 2; ni++) {
      #pragma unroll
      for (int mj = 0; mj < 4; mj++) {
        float h0 = bfhi_f(s[mj][ni][0]), h1 = bfhi_f(s[mj][ni][1]);
        float h2 = bfhi_f(s[mj][ni][2]), h3 = bfhi_f(s[mj][ni][3]);
        u32* dst = (u32*)&PS[wid][ni * 16 + l15][mj * 16 + l4 * 4];
        dst[0] = rne2(h0, h1); dst[1] = rne2(h2, h3);
      }
    }
    bf16x8 pbh[2][2];
    #pragma unroll
    for (int ni = 0; ni < 2; ni++)
      #pragma unroll
      for (int ks = 0; ks < 2; ks++)
        pbh[ni][ks] = *(const bf16x8*)&PS[wid][ni * 16 + l15][ks * 32 + l4 * 8];

    // ---- P lo -> same LDS buffer, read B-frags
    #pragma unroll
    for (int ni = 0; ni < 2; ni++) {
      #pragma unroll
      for (int mj = 0; mj < 4; mj++) {
        float p0 = s[mj][ni][0], p1 = s[mj][ni][1], p2 = s[mj][ni][2], p3 = s[mj][ni][3];
        float h0 = bfhi_f(p0), h1 = bfhi_f(p1), h2 = bfhi_f(p2), h3 = bfhi_f(p3);
        u32* dst = (u32*)&PS[wid][ni * 16 + l15][mj * 16 + l4 * 4];
        dst[0] = rne2(p0 - h0, p1 - h1); dst[1] = rne2(p2 - h2, p3 - h3);
      }
    }
    bf16x8 pbl[2][2];
    #pragma unroll
    for (int ni = 0; ni < 2; ni++)
      #pragma unroll
      for (int ks = 0; ks < 2; ks++)
        pbl[ni][ks] = *(const bf16x8*)&PS[wid][ni * 16 + l15][ks * 32 + l4 * 8];

    // ---- O^T += V^T * P^T (3-term split; linear kv pairing)
    #pragma unroll
    for (int md = 0; md < 4; md++) {
      #pragma unroll
      for (int ks = 0; ks < 2; ks++) {
        const int row = md * 16 + l15;
        const int ch = (((ks << 2) + l4) ^ (row & 7)) << 3;
        const bf16x8 vh = *(const bf16x8*)&VhS[row * 64 + ch];
        const bf16x8 vl = *(const bf16x8*)&VlS[row * 64 + ch];
        #pragma unroll
        for (int nq = 0; nq < 2; nq++) {
          acc[md][nq] = mfma16(vh, pbh[nq][ks], acc[md][nq]);
          acc[md][nq] = mfma16(vh, pbl[nq][ks], acc[md][nq]);
          acc[md][nq] = mfma16(vl, pbh[nq][ks], acc[md][nq]);
        }
      }
    }
  }

  // ---- epilogue: ctx[q][d] = O^T[d][q] / l[q]
  const float inv[2] = {1.f / lrun[0], 1.f / lrun[1]};
  #pragma unroll
  for (int nq = 0; nq < 2; nq++) {
    #pragma unroll
    for (int md = 0; md < 4; md++) {
      float4 o;
      o.x = acc[md][nq][0] * inv[nq];
      o.y = acc[md][nq][1] * inv[nq];
      o.z = acc[md][nq][2] * inv[nq];
      o.w = acc[md][nq][3] * inv[nq];
      *(float4*)(ctx + (long long)(b * N_T + q0 + nq * 16 + l15) * N_D +
                 h * 64 + md * 16 + l4 * 4) = o;
    }
  }
}

// ---------------- LN1 + gate softmax + top2 (wave per token) ----------------
__global__ __launch_bounds__(256, 4)
void ln1_gate(const float* __restrict__ src, const float* __restrict__ attnout,
              const float* __restrict__ g, const float* __restrict__ bb,
              const float* __restrict__ gateW, const float* __restrict__ gateb,
              float* __restrict__ xout, u16* __restrict__ xbf,
              int* __restrict__ counts,
              int2* __restrict__ tok_top, float2* __restrict__ tok_w)
{
  const int wid = threadIdx.x >> 6, lane = threadIdx.x & 63;
  const int t = blockIdx.x * 4 + wid;
  const float4* s4 = (const float4*)(src + (long long)t * N_D);
  const float4* a4 = (const float4*)(attnout + (long long)t * N_D);
  float4 v[4];
  float sum = 0.f;
  #pragma unroll
  for (int c = 0; c < 4; c++) {
    const int idx = c * 64 + lane;
    float4 a = s4[idx], b2 = a4[idx];
    v[c] = make_float4(a.x + b2.x, a.y + b2.y, a.z + b2.z, a.w + b2.w);
    sum += v[c].x + v[c].y + v[c].z + v[c].w;
  }
  sum = wred(sum);
  const float mu = sum * (1.f / 1024.f);
  float s2 = 0.f;
  #pragma unroll
  for (int c = 0; c < 4; c++) {
    float dx = v[c].x - mu, dy = v[c].y - mu, dz = v[c].z - mu, dw = v[c].w - mu;
    s2 += dx * dx + dy * dy + dz * dz + dw * dw;
  }
  s2 = wred(s2);
  const float rs = rsqrtf(s2 * (1.f / 1024.f) + LNEPS);
  float acc[8];
  #pragma unroll
  for (int e2 = 0; e2 < 8; e2++) acc[e2] = 0.f;
  #pragma unroll
  for (int c = 0; c < 4; c++) {
    const int idx = c * 64 + lane;
    float4 gv = ((const float4*)g)[idx], bv = ((const float4*)bb)[idx];
    float xa[4];
    xa[0] = (v[c].x - mu) * rs * gv.x + bv.x;
    xa[1] = (v[c].y - mu) * rs * gv.y + bv.y;
    xa[2] = (v[c].z - mu) * rs * gv.z + bv.z;
    xa[3] = (v[c].w - mu) * rs * gv.w + bv.w;
    ((float4*)(xout + (long long)t * N_D))[idx] = make_float4(xa[0], xa[1], xa[2], xa[3]);
    *(uint2*)&xbf[(long long)t * N_D + idx * 4] =
        make_uint2(rne2(xa[0], xa[1]), rne2(xa[2], xa[3]));
    #pragma unroll
    for (int ii = 0; ii < 4; ii++) {
      const float xs = xa[ii];
      const float4* gw = (const float4*)(gateW + ((long long)(idx * 4 + ii)) * N_E);
      float4 w0 = gw[0], w1 = gw[1];
      acc[0] += xs * w0.x; acc[1] += xs * w0.y; acc[2] += xs * w0.z; acc[3] += xs * w0.w;
      acc[4] += xs * w1.x; acc[5] += xs * w1.y; acc[6] += xs * w1.z; acc[7] += xs * w1.w;
    }
  }
  #pragma unroll
  for (int e2 = 0; e2 < 8; e2++) acc[e2] = wred(acc[e2]);
  if (lane == 0) {
    float lg[8];
    #pragma unroll
    for (int e2 = 0; e2 < 8; e2++) lg[e2] = acc[e2] + gateb[e2];
    float mx = lg[0];
    #pragma unroll
    for (int e2 = 1; e2 < 8; e2++) mx = fmaxf(mx, lg[e2]);
    float Z = 0.f;
    #pragma unroll
    for (int e2 = 0; e2 < 8; e2++) Z += __expf(lg[e2] - mx);
    int e0 = 0; float v0 = lg[0];
    #pragma unroll
    for (int e2 = 1; e2 < 8; e2++) if (lg[e2] > v0) { v0 = lg[e2]; e0 = e2; }
    int e1 = -1; float v1 = -3.4e38f;
    #pragma unroll
    for (int e2 = 0; e2 < 8; e2++) if (e2 != e0 && lg[e2] > v1) { v1 = lg[e2]; e1 = e2; }
    atomicAdd(&counts[e0], 1);
    atomicAdd(&counts[e1], 1);
    tok_top[t] = make_int2(e0, e1);
    tok_w[t] = make_float2(__expf(v0 - mx) / Z, __expf(v1 - mx) / Z);
  }
}

// ---------------- routing: offsets, tile descriptors, padding fill ----------------
__global__ void route_build(const int* __restrict__ counts, int* __restrict__ offsets,
                            int* __restrict__ cursors, int* __restrict__ ntiles,
                            int2* __restrict__ tiles, int* __restrict__ token_idx,
                            float* __restrict__ slot_w)
{
  __shared__ int soff[N_E + 1];
  __shared__ int scnt[N_E];
  if (threadIdx.x == 0) {
    int off = 0, nt = 0;
    for (int ex = 0; ex < N_E; ex++) {
      soff[ex] = off; offsets[ex] = off; cursors[ex] = 0;
      const int cnt = counts[ex];
      scnt[ex] = cnt;
      const int pt = (cnt + 127) >> 7;
      for (int i = 0; i < pt; i++) { tiles[nt] = make_int2(ex, off + i * 128); nt++; }
      off += pt << 7;
    }
    soff[N_E] = off; offsets[N_E] = off;
    *ntiles = nt;
  }
  __syncthreads();
  for (int ex = 0; ex < N_E; ex++)
    for (int s = soff[ex] + scnt[ex] + (int)threadIdx.x; s < soff[ex + 1]; s += (int)blockDim.x) {
      token_idx[s] = 0; slot_w[s] = 0.f;
    }
}

__global__ __launch_bounds__(256)
void route_scatter(const int2* __restrict__ tok_top, const float2* __restrict__ tok_w,
                   const int* __restrict__ offsets, int* __restrict__ cursors,
                   int* __restrict__ token_idx, float* __restrict__ slot_w,
                   int* __restrict__ slotA, int* __restrict__ slotB)
{
  const int t = blockIdx.x * 256 + threadIdx.x;
  if (t >= N_BT) return;
  const int2 ee = tok_top[t];
  const float2 ww = tok_w[t];
  int p = atomicAdd(&cursors[ee.x], 1);
  int s = offsets[ee.x] + p;
  token_idx[s] = t; slot_w[s] = ww.x; slotA[t] = s;
  p = atomicAdd(&cursors[ee.y], 1);
  s = offsets[ee.y] + p;
  token_idx[s] = t; slot_w[s] = ww.y; slotB[t] = s;
}

// ---------------- final: y = LN2(x + out2[sA] + out2[sB]) ----------------
__global__ __launch_bounds__(256, 4)
void final_ln2(const float* __restrict__ x, const float* __restrict__ out2,
               const int* __restrict__ slotA, const int* __restrict__ slotB,
               const float* __restrict__ g, const float* __restrict__ bb,
               float* __restrict__ out)
{
  const int wid = threadIdx.x >> 6, lane = threadIdx.x & 63;
  const int t = blockIdx.x * 4 + wid;
  const int sA = slotA[t], sB = slotB[t];
  const float4* xr = (const float4*)(x + (long long)t * N_D);
  const float4* pa = (const float4*)(out2 + (long long)sA * N_D);
  const float4* pb = (const float4*)(out2 + (long long)sB * N_D);
  float4 v[4];
  float sum = 0.f;
  #pragma unroll
  for (int c = 0; c < 4; c++) {
    const int idx = c * 64 + lane;
    float4 a = xr[idx], b2 = pa[idx], c2 = pb[idx];
    v[c] = make_float4(a.x + b2.x + c2.x, a.y + b2.y + c2.y,
                       a.z + b2.z + c2.z, a.w + b2.w + c2.w);
    sum += v[c].x + v[c].y + v[c].z + v[c].w;
  }
  sum = wred(sum);
  const float mu = sum * (1.f / 1024.f);
  float s2 = 0.f;
  #pragma unroll
  for (int c = 0; c < 4; c++) {
    float dx = v[c].x - mu, dy = v[c].y - mu, dz = v[c].z - mu, dw = v[c].w - mu;
    s2 += dx * dx + dy * dy + dz * dz + dw * dw;
  }
  s2 = wred(s2);
  const float rs = rsqrtf(s2 * (1.f / 1024.f) + LNEPS);
  #pragma unroll
  for (int c = 0; c < 4; c++) {
    const int idx = c * 64 + lane;
    float4 gv = ((const float4*)g)[idx], bv = ((const float4*)bb)[idx];
    float4 o;
    o.x = (v[c].x - mu) * rs * gv.x + bv.x;
    o.y = (v[c].y - mu) * rs * gv.y + bv.y;
    o.z = (v[c].z - mu) * rs * gv.z + bv.z;
    o.w = (v[c].w - mu) * rs * gv.w + bv.w;
    ((float4*)(out + (long long)t * N_D))[idx] = o;
  }
}

// ---------------- launch ----------------
extern "C" void kernel_launch(void* const* d_in, const int* in_sizes, int n_in,
                              void* d_out, int out_size, void* d_ws, size_t ws_size,
                              hipStream_t stream)
{
  const float* src   = (const float*)d_in[0];
  const float* frac  = (const float*)d_in[1];
  const float* Wq    = (const float*)d_in[2];
  const float* bq    = (const float*)d_in[3];
  const float* Wk    = (const float*)d_in[4];
  const float* bk    = (const float*)d_in[5];
  const float* Wv    = (const float*)d_in[6];
  const float* bv    = (const float*)d_in[7];
  const float* Wo    = (const float*)d_in[8];
  const float* bo    = (const float*)d_in[9];
  const float* apos  = (const float*)d_in[10];
  const float* aneg  = (const float*)d_in[11];
  const float* gateW = (const float*)d_in[12];
  const float* gateb = (const float*)d_in[13];
  const float* W1    = (const float*)d_in[14];
  const float* b1    = (const float*)d_in[15];
  const float* W2    = (const float*)d_in[16];
  const float* b2    = (const float*)d_in[17];
  const float* ln1g  = (const float*)d_in[18];
  const float* ln1b  = (const float*)d_in[19];
  const float* ln2g  = (const float*)d_in[20];
  const float* ln2b  = (const float*)d_in[21];
  float* out = (float*)d_out;

  char* ws = (char*)d_ws;
  const size_t MB = 1ull << 20;
  u16* Bcath = (u16*)(ws + 0 * MB);
  u16* Bcatl = (u16*)(ws + 6 * MB);
  u16* WoTh  = (u16*)(ws + 12 * MB);
  u16* WoTl  = (u16*)(ws + 14 * MB);
  u16*   W1T  = (u16*)(ws + 16 * MB);    // 64 MB, dead after FFN GEMM1
  float* out2 = (float*)(ws + 16 * MB);  // <=38 MB, alias (written after W1T dead)
  u16*   W2T  = (u16*)(ws + 80 * MB);    // 64 MB
  u16*   QKVh = (u16*)(ws + 144 * MB);   // 24 MB: [4096][3072] hi (Q|K|V)
  u16*   QKVl = (u16*)(ws + 168 * MB);   // 24 MB lo
  u16*   Vth  = (u16*)(ws + 192 * MB);   // 8 MB per-head V^T hi
  u16*   Vtl  = (u16*)(ws + 200 * MB);   // 8 MB per-head V^T lo
  float* ctxb = (float*)(ws + 208 * MB); // 16 MB
  float* attnb= (float*)(ws + 144 * MB); // 16 MB alias (QKVh dead after attn)
  u16*   hb   = (u16*)(ws + 144 * MB);   // <=72 MB alias (all of 144-216 dead by FFN1)
  float* xb   = (float*)(ws + 224 * MB); // 16 MB fp32 -> total 240 MB
  u16*   xbf  = (u16*)(ws + 4 * MB);     // 8 MB bf16 alias (Bcat dead by ln1_gate)
  float* bcat = (float*)(ws + 240 * MB); // 12 KB
  char* misc = ws + 0;                   // aliases Bcat region (dead by routing phase)
  int*    counts    = (int*)(misc);
  int*    cursors   = (int*)(misc + 64);
  int*    offsets   = (int*)(misc + 128);
  int*    ntiles    = (int*)(misc + 256);
  int2*   tiles     = (int2*)(misc + 512);
  int2*   tok_top   = (int2*)(misc + 2048);
  float2* tok_w     = (float2*)(misc + 2048 + 32768);
  int*    token_idx = (int*)(misc + 2048 + 65536);
  float*  slot_w    = (float*)(misc + 2048 + 65536 + 36864);
  int*    slotA     = (int*)(misc + 2048 + 65536 + 73728);
  int*    slotB     = (int*)(misc + 2048 + 65536 + 73728 + 16384);

  dim3 b256(256);
  transpose_bf16<1><<<dim3(16, 16, 1), b256, 0, stream>>>(Wq, Bcath, Bcatl,
                                                          1024, 1024, 0.125f);
  transpose_bf16<1><<<dim3(16, 16, 1), b256, 0, stream>>>(Wk, Bcath + 1024 * 1024,
                                                          Bcatl + 1024 * 1024, 1024, 1024, 1.0f);
  transpose_bf16<1><<<dim3(16, 16, 1), b256, 0, stream>>>(Wv, Bcath + 2048 * 1024,
                                                          Bcatl + 2048 * 1024, 1024, 1024, 1.0f);
  transpose_bf16<1><<<dim3(16, 16, 1), b256, 0, stream>>>(Wo, WoTh, WoTl, 1024, 1024, 1.0f);
  transpose_bf16<0><<<dim3(64, 16, 8), b256, 0, stream>>>(W1, W1T, nullptr, 1024, 4096, 1.0f);
  transpose_bf16<0><<<dim3(16, 64, 8), b256, 0, stream>>>(W2, W2T, nullptr, 4096, 1024, 1.0f);
  bias_cat<<<dim3(12), b256, 0, stream>>>(bq, bk, bv, bcat);

  // fused QKV projection: [4096][3072] hi/lo bf16 (Q cols pre-scaled via Wq/bq); CG=3
  gemm128<1, 0, 0, 0, 2, 0, 3><<<dim3(32, 24), b256, 0, stream>>>(
      src, 1024, Bcath, Bcatl, 0, QKVh, 3072, bcat, 0, nullptr, nullptr, nullptr, nullptr,
      1024, QKVl, 1.0f);

  vtrans_bf16<<<dim3(16, 64), b256, 0, stream>>>(QKVh + 2048, QKVl + 2048, 3072, Vth, Vtl);

  attn_mfma<<<dim3(64, 8), b256, 0, stream>>>(QKVh, QKVl, QKVh + 1024, QKVl + 1024, 3072,
                                              Vth, Vtl, frac, apos, aneg, ctxb);

  gemm128<1, 0, 0, 0, 0, 0, 1><<<dim3(32, 8), b256, 0, stream>>>(
      ctxb, 1024, WoTh, WoTl, 0, attnb, 1024, bo, 0, nullptr, nullptr, nullptr, nullptr,
      1024, nullptr, 1.0f);

  hipMemsetAsync(counts, 0, 32, stream);   // misc aliases Bcat region (dead after QKV/Wo)
  ln1_gate<<<dim3(1024), b256, 0, stream>>>(src, attnb, ln1g, ln1b, gateW, gateb,
                                            xb, xbf, counts, tok_top, tok_w);
  route_build<<<dim3(1), dim3(64), 0, stream>>>(counts, offsets, cursors, ntiles,
                                                tiles, token_idx, slot_w);
  route_scatter<<<dim3(16), b256, 0, stream>>>(tok_top, tok_w, offsets, cursors,
                                               token_idx, slot_w, slotA, slotB);

  // grouped MoE FFN (bf16 A+B, double-buffered global_load_lds staging)
  gemm128<0, 1, 1, 0, 1, 1, 4><<<dim3(72, 32), b256, 0, stream>>>(
      xbf, 1024, W1T, nullptr, 4096ll * 1024, hb, 4096, b1, 4096,
      nullptr, token_idx, tiles, ntiles, 1024, nullptr, 1.0f);
  gemm128<0, 0, 0, 1, 0, 1, 8><<<dim3(72, 8), b256, 0, stream>>>(
      hb, 4096, W2T, nullptr, 1024ll * 4096, out2, 1024, b2, 1024,
      slot_w, nullptr, tiles, ntiles, 4096, nullptr, 1.0f);

  final_ln2<<<dim3(1024), b256, 0, stream>>>(xb, out2, slotA, slotB, ln2g, ln2b, out);
}

// Round 8
// 600.431 us; speedup vs baseline: 2.5845x; 1.1160x over previous
//
// CustomTransformerEncoderMoELayerStoich — MI355X (gfx950)
// Round 8: R7 (passing) + removal of the 8192 same-line device atomics in ln1_gate
// (measured: 111.7us at 2.9% VALU / 4.8% HBM = atomic-queue serialization).
// route_build now histograms tok_top itself (256 thr, LDS atomics). All else identical.

#include <hip/hip_runtime.h>
#include <stdint.h>

typedef unsigned short u16;
typedef unsigned int   u32;

using bf16x8 = __attribute__((ext_vector_type(8))) short;
using f32x4  = __attribute__((ext_vector_type(4))) float;

#define N_T   1024
#define N_D   1024
#define N_E   8
#define N_BT  4096
#define LNEPS 1e-5f

// ---------------- helpers ----------------
__device__ __forceinline__ u32 rne2(float a, float b) {
  u32 ua = __float_as_uint(a); ua = (ua + 0x7fffu + ((ua >> 16) & 1u)) >> 16;
  u32 ub = __float_as_uint(b); ub = (ub + 0x7fffu + ((ub >> 16) & 1u)) >> 16;
  return ua | (ub << 16);
}
__device__ __forceinline__ u16 rne1(float a) {
  u32 ua = __float_as_uint(a);
  return (u16)((ua + 0x7fffu + ((ua >> 16) & 1u)) >> 16);
}
__device__ __forceinline__ float bfhi_f(float a) {   // nearest-bf16 value as fp32
  u32 ua = __float_as_uint(a);
  ua = (ua + 0x7fffu + ((ua >> 16) & 1u)) & 0xffff0000u;
  return __uint_as_float(ua);
}
__device__ __forceinline__ int fch(int row) { return (row & 3) ^ ((row >> 2) & 3); }
__device__ __forceinline__ int swz(int row, int chunk) {
  return row * 32 + (((chunk ^ fch(row)) & 3) << 3);
}
__device__ __forceinline__ float wred(float v) {
  #pragma unroll
  for (int o2 = 32; o2 > 0; o2 >>= 1) v += __shfl_xor(v, o2, 64);
  return v;
}
__device__ __forceinline__ f32x4 mfma16(bf16x8 a, bf16x8 b, f32x4 c) {
  return __builtin_amdgcn_mfma_f32_16x16x32_bf16(a, b, c, 0, 0, 0);
}
// async global->LDS, 16B per lane; LDS dest = wave-uniform base + lane*16
typedef __attribute__((address_space(1))) const u32 gas_u32;
typedef __attribute__((address_space(3))) u32 las_u32;
__device__ __forceinline__ void gl16(const void* g, void* l) {
  __builtin_amdgcn_global_load_lds((gas_u32*)g, (las_u32*)l, 16, 0, 0);
}

// ---------------- transpose fp32 [R][C] -> bf16 [C][R] (scale, optional hi/lo split) ---------
template<int SPLIT>
__global__ __launch_bounds__(256)
void transpose_bf16(const float* __restrict__ in, u16* __restrict__ outh,
                    u16* __restrict__ outl, int R, int C, float scale)
{
  __shared__ u16 th[64][68];
  __shared__ u16 tl[SPLIT ? 64 : 1][SPLIT ? 68 : 1];
  const long long zb = (long long)blockIdx.z * R * C;
  const float* srcp = in + zb;
  const int r0 = blockIdx.y * 64, c0 = blockIdx.x * 64;
  const int t = threadIdx.x;
  {
    const int rr = t >> 4, cc = (t & 15) << 2;
    #pragma unroll
    for (int i = 0; i < 4; i++) {
      const int r = rr + i * 16;
      float4 v = *(const float4*)(srcp + (long long)(r0 + r) * C + c0 + cc);
      v.x *= scale; v.y *= scale; v.z *= scale; v.w *= scale;
      if constexpr (SPLIT) {
        float hx = bfhi_f(v.x), hy = bfhi_f(v.y), hz = bfhi_f(v.z), hw = bfhi_f(v.w);
        *(uint2*)&th[r][cc] = make_uint2(rne2(hx, hy), rne2(hz, hw));
        *(uint2*)&tl[r][cc] = make_uint2(rne2(v.x - hx, v.y - hy), rne2(v.z - hz, v.w - hw));
      } else {
        *(uint2*)&th[r][cc] = make_uint2(rne2(v.x, v.y), rne2(v.z, v.w));
      }
    }
  }
  __syncthreads();
  {
    const int c = t >> 2, rs = (t & 3) << 4;
    const long long ob = zb + (long long)(c0 + c) * R + r0 + rs;
    u32 w[8];
    #pragma unroll
    for (int i = 0; i < 8; i++)
      w[i] = (u32)th[rs + 2*i][c] | ((u32)th[rs + 2*i + 1][c] << 16);
    *(uint4*)(outh + ob)     = make_uint4(w[0], w[1], w[2], w[3]);
    *(uint4*)(outh + ob + 8) = make_uint4(w[4], w[5], w[6], w[7]);
    if constexpr (SPLIT) {
      #pragma unroll
      for (int i = 0; i < 8; i++)
        w[i] = (u32)tl[rs + 2*i][c] | ((u32)tl[rs + 2*i + 1][c] << 16);
      *(uint4*)(outl + ob)     = make_uint4(w[0], w[1], w[2], w[3]);
      *(uint4*)(outl + ob + 8) = make_uint4(w[4], w[5], w[6], w[7]);
    }
  }
}

// ---------------- concat scaled QKV bias: [bq*0.125; bk; bv] ----------------
__global__ __launch_bounds__(256)
void bias_cat(const float* __restrict__ bq, const float* __restrict__ bk,
              const float* __restrict__ bv, float* __restrict__ bcat)
{
  const int i = blockIdx.x * 256 + threadIdx.x;
  if (i < 1024)       bcat[i] = bq[i] * 0.125f;
  else if (i < 2048)  bcat[i] = bk[i - 1024];
  else if (i < 3072)  bcat[i] = bv[i - 2048];
}

// ---------------- V^T per-head transpose: hi/lo bf16 [kv][d] (strided) -> [d][kv] ------------
__global__ __launch_bounds__(256)
void vtrans_bf16(const u16* __restrict__ Vh, const u16* __restrict__ Vl, int ldv,
                 u16* __restrict__ Vth, u16* __restrict__ Vtl)
{
  __shared__ u16 th[64][72];
  __shared__ u16 tl[64][72];
  const int bh = blockIdx.y, b = bh >> 4, h = bh & 15;
  const int kt = blockIdx.x, tid = threadIdx.x;
  {
    const int sr = tid >> 2, scb = (tid & 3) << 4;   // kv row, d col base
    const long long off = (long long)(b * N_T + kt * 64 + sr) * ldv + h * 64 + scb;
    const uint4* vh = (const uint4*)(Vh + off);
    const uint4* vl = (const uint4*)(Vl + off);
    *(uint4*)&th[sr][scb]     = vh[0];
    *(uint4*)&th[sr][scb + 8] = vh[1];
    *(uint4*)&tl[sr][scb]     = vl[0];
    *(uint4*)&tl[sr][scb + 8] = vl[1];
  }
  __syncthreads();
  {
    const int od = tid >> 2, os0 = (tid & 3) << 4;   // d row, kv col base
    u16 wh[16], wl[16];
    #pragma unroll
    for (int i = 0; i < 16; i++) { wh[i] = th[os0 + i][od]; wl[i] = tl[os0 + i][od]; }
    u16* oph = Vth + (long long)(bh * 64 + od) * N_T + kt * 64 + os0;
    u16* opl = Vtl + (long long)(bh * 64 + od) * N_T + kt * 64 + os0;
    *(uint4*)oph = make_uint4((u32)wh[0] | ((u32)wh[1] << 16), (u32)wh[2] | ((u32)wh[3] << 16),
                              (u32)wh[4] | ((u32)wh[5] << 16), (u32)wh[6] | ((u32)wh[7] << 16));
    *(uint4*)(oph + 8) = make_uint4((u32)wh[8] | ((u32)wh[9] << 16), (u32)wh[10] | ((u32)wh[11] << 16),
                                    (u32)wh[12] | ((u32)wh[13] << 16), (u32)wh[14] | ((u32)wh[15] << 16));
    *(uint4*)opl = make_uint4((u32)wl[0] | ((u32)wl[1] << 16), (u32)wl[2] | ((u32)wl[3] << 16),
                              (u32)wl[4] | ((u32)wl[5] << 16), (u32)wl[6] | ((u32)wl[7] << 16));
    *(uint4*)(opl + 8) = make_uint4((u32)wl[8] | ((u32)wl[9] << 16), (u32)wl[10] | ((u32)wl[11] << 16),
                                    (u32)wl[12] | ((u32)wl[13] << 16), (u32)wl[14] | ((u32)wl[15] << 16));
  }
}

// ---------------- 128x128x32 MFMA GEMM (4 waves, 4x4 16x16 frags each) ----------------
// ASPLIT=1: A fp32 -> hi/lo regs -> LDS (3-term), B hi+lo via global_load_lds, single-buffer.
// ASPLIT=0: A,B bf16 via global_load_lds into DOUBLE-BUFFERED LDS (T3-min structure).
// CG-blocked XCD decode: per-XCD chunk = CG columns x all tiles, tile-major within chunk.
// OBF: 0 fp32 out, 1 bf16 out, 2 split hi/lo bf16 out (Cp, Cp2) with cscale folded.
template<int ASPLIT, int GATHER, int DORELU, int DOSCALE, int OBF, int GROUPED, int CG>
__global__ __launch_bounds__(256, 2)
void gemm128(const void* __restrict__ Ap, int lda,
             const u16* __restrict__ Bhp, const u16* __restrict__ Blp,
             long long bstride,
             void* __restrict__ Cp, int ldc,
             const float* __restrict__ biasp, int bias_stride,
             const float* __restrict__ slot_wp,
             const int* __restrict__ tokidx,
             const int2* __restrict__ tilesp, const int* __restrict__ ntilesp,
             int Ksz, void* __restrict__ Cp2, float cscale)
{
  // XCD remap (nwg % 8 == 0 for all grids used) + CG-blocked decode (CG | gridDim.y).
  const int gx = gridDim.x, nwg = gx * gridDim.y;
  const int orig = blockIdx.y * gx + blockIdx.x;
  const int flat = (orig & 7) * (nwg >> 3) + (orig >> 3);
  const int cgsz = gx * CG;
  const int colg = flat / cgsz, rem = flat % cgsz;
  const int bxx = rem / CG;
  const int byy = colg * CG + rem % CG;

  int e = 0, row0;
  if constexpr (GROUPED) {
    if (bxx >= *ntilesp) return;
    const int2 dsc = tilesp[bxx];
    e = dsc.x; row0 = dsc.y;
  } else {
    row0 = bxx * 128;
  }
  const int col0 = byy * 128;

  __shared__ __align__(16) u16 AhS[ASPLIT ? 1 : 2][128 * 32];
  __shared__ __align__(16) u16 BhS[ASPLIT ? 1 : 2][128 * 32];
  __shared__ __align__(16) u16 AlS[ASPLIT ? 128 * 32 : 8];
  __shared__ __align__(16) u16 BlS[ASPLIT ? 128 * 32 : 8];

  const int tid = threadIdx.x, wid = tid >> 6, lane = tid & 63;
  const int wm = (wid >> 1) << 6, wn = (wid & 1) << 6;
  const int l15 = lane & 15, l4 = lane >> 4;

  // async staging geometry: wave w fills rows [w*32, w*32+32); lane -> row, linear chunk
  // lane&3; global chunk = (lane&3)^fch(row) (inverse swizzle; read side uses swz()).
  const int srow0 = wid * 32 + (lane >> 2);
  const int srow1 = srow0 + 16;
  const int sg0 = ((lane & 3) ^ fch(srow0)) << 3;   // u16 elems
  const int sg1 = ((lane & 3) ^ fch(srow1)) << 3;
  const int lo0 = wid * 1024, lo1 = wid * 1024 + 512;

  const u16* Bg0 = Bhp + (long long)e * bstride + (long long)(col0 + srow0) * Ksz + sg0;
  const u16* Bg1 = Bhp + (long long)e * bstride + (long long)(col0 + srow1) * Ksz + sg1;
  const u16* Blg0 = nullptr; const u16* Blg1 = nullptr;
  if constexpr (ASPLIT) {
    Blg0 = Blp + (long long)e * bstride + (long long)(col0 + srow0) * Ksz + sg0;
    Blg1 = Blp + (long long)e * bstride + (long long)(col0 + srow1) * Ksz + sg1;
  }

  const u16* Ag0 = nullptr; const u16* Ag1 = nullptr;
  if constexpr (!ASPLIT) {
    long long ar0, ar1;
    if constexpr (GATHER) { ar0 = tokidx[row0 + srow0]; ar1 = tokidx[row0 + srow1]; }
    else                  { ar0 = row0 + srow0;          ar1 = row0 + srow1; }
    Ag0 = (const u16*)Ap + ar0 * (long long)lda + sg0;
    Ag1 = (const u16*)Ap + ar1 * (long long)lda + sg1;
  }

  f32x4 acc[4][4] = {};
  const int nk = Ksz >> 5;

  if constexpr (!ASPLIT) {
    // ===== double-buffered plain-bf16 path =====
    gl16(Ag0, &AhS[0][lo0]); gl16(Ag1, &AhS[0][lo1]);
    gl16(Bg0, &BhS[0][lo0]); gl16(Bg1, &BhS[0][lo1]);
    asm volatile("s_waitcnt vmcnt(0)" ::: "memory");
    __syncthreads();
    int cur = 0;
    for (int kt = 0; kt < nk; kt++) {
      if (kt + 1 < nk) {
        const int ko = (kt + 1) << 5;
        gl16(Ag0 + ko, &AhS[cur ^ 1][lo0]);
        gl16(Ag1 + ko, &AhS[cur ^ 1][lo1]);
        gl16(Bg0 + ko, &BhS[cur ^ 1][lo0]);
        gl16(Bg1 + ko, &BhS[cur ^ 1][lo1]);
      }
      bf16x8 ah[4], bh[4];
      #pragma unroll
      for (int i = 0; i < 4; i++) {
        ah[i] = *(const bf16x8*)&AhS[cur][swz(wm + i * 16 + l15, l4)];
        bh[i] = *(const bf16x8*)&BhS[cur][swz(wn + i * 16 + l15, l4)];
      }
      #pragma unroll
      for (int i = 0; i < 4; i++)
        #pragma unroll
        for (int j = 0; j < 4; j++)
          acc[i][j] = mfma16(ah[i], bh[j], acc[i][j]);
      asm volatile("s_waitcnt vmcnt(0)" ::: "memory");
      __syncthreads();
      cur ^= 1;
    }
  } else {
    // ===== fp32-A split path (verified R6 structure) =====
    const int prr = tid >> 1, pc2 = (tid & 1) << 1;
    const float* Arow = (const float*)Ap + (long long)(row0 + prr) * lda;
    uint4 sah0, sah1, sal0, sal1;
    auto gloadA = [&](int k0) {
      const float4* ap = (const float4*)(Arow + k0 + pc2 * 8);
      float4 f0 = ap[0], f1 = ap[1], f2 = ap[2], f3 = ap[3];
      float h0 = bfhi_f(f0.x), h1 = bfhi_f(f0.y), h2 = bfhi_f(f0.z), h3 = bfhi_f(f0.w);
      float h4 = bfhi_f(f1.x), h5 = bfhi_f(f1.y), h6 = bfhi_f(f1.z), h7 = bfhi_f(f1.w);
      sah0 = make_uint4(rne2(h0, h1), rne2(h2, h3), rne2(h4, h5), rne2(h6, h7));
      sal0 = make_uint4(rne2(f0.x - h0, f0.y - h1), rne2(f0.z - h2, f0.w - h3),
                        rne2(f1.x - h4, f1.y - h5), rne2(f1.z - h6, f1.w - h7));
      h0 = bfhi_f(f2.x); h1 = bfhi_f(f2.y); h2 = bfhi_f(f2.z); h3 = bfhi_f(f2.w);
      h4 = bfhi_f(f3.x); h5 = bfhi_f(f3.y); h6 = bfhi_f(f3.z); h7 = bfhi_f(f3.w);
      sah1 = make_uint4(rne2(h0, h1), rne2(h2, h3), rne2(h4, h5), rne2(h6, h7));
      sal1 = make_uint4(rne2(f2.x - h0, f2.y - h1), rne2(f2.z - h2, f2.w - h3),
                        rne2(f3.x - h4, f3.y - h5), rne2(f3.z - h6, f3.w - h7));
    };
    gloadA(0);
    for (int kt = 0; kt < nk; kt++) {
      __syncthreads();
      const int ko = kt << 5;
      *(uint4*)&AhS[0][swz(prr, pc2)]     = sah0;
      *(uint4*)&AhS[0][swz(prr, pc2 + 1)] = sah1;
      *(uint4*)&AlS[swz(prr, pc2)]        = sal0;
      *(uint4*)&AlS[swz(prr, pc2 + 1)]    = sal1;
      gl16(Bg0 + ko, &BhS[0][lo0]);
      gl16(Bg1 + ko, &BhS[0][lo1]);
      gl16(Blg0 + ko, &BlS[lo0]);
      gl16(Blg1 + ko, &BlS[lo1]);
      asm volatile("s_waitcnt vmcnt(0)" ::: "memory");
      __syncthreads();
      if (kt + 1 < nk) gloadA((kt + 1) << 5);

      bf16x8 ah[4], bh[4], al[4], bl[4];
      #pragma unroll
      for (int i = 0; i < 4; i++) {
        const int ar = wm + i * 16 + l15;
        const int br = wn + i * 16 + l15;
        ah[i] = *(const bf16x8*)&AhS[0][swz(ar, l4)];
        bh[i] = *(const bf16x8*)&BhS[0][swz(br, l4)];
        al[i] = *(const bf16x8*)&AlS[swz(ar, l4)];
        bl[i] = *(const bf16x8*)&BlS[swz(br, l4)];
      }
      #pragma unroll
      for (int i = 0; i < 4; i++) {
        #pragma unroll
        for (int j = 0; j < 4; j++) {
          acc[i][j] = mfma16(ah[i], bh[j], acc[i][j]);
          acc[i][j] = mfma16(ah[i], bl[j], acc[i][j]);
          acc[i][j] = mfma16(al[i], bh[j], acc[i][j]);
        }
      }
    }
  }

  #pragma unroll
  for (int i = 0; i < 4; i++) {
    #pragma unroll
    for (int j = 0; j < 4; j++) {
      const int orow0 = row0 + wm + i * 16 + (l4 << 2);
      const int ocol  = col0 + wn + j * 16 + l15;
      const float bv = biasp[(long long)e * bias_stride + col0 + wn + j * 16 + l15];
      #pragma unroll
      for (int q = 0; q < 4; q++) {
        float v = acc[i][j][q] + bv;
        if constexpr (DORELU) v = fmaxf(v, 0.f);
        const long long orow = orow0 + q;
        if constexpr (DOSCALE) v *= slot_wp[orow];
        if constexpr (OBF == 2) {
          const float vs = v * cscale;
          const float hi = bfhi_f(vs);
          ((u16*)Cp )[orow * ldc + ocol] = (u16)(__float_as_uint(hi) >> 16);
          ((u16*)Cp2)[orow * ldc + ocol] = rne1(vs - hi);
        } else if constexpr (OBF == 1) {
          ((u16*)Cp)[orow * ldc + ocol] = rne1(v);
        } else {
          ((float*)Cp)[orow * ldc + ocol] = v;
        }
      }
    }
  }
}

// ---------------- MFMA flash attention with stoichiometric bias ----------------
// grid (B*H=64, T/128=8), block 256 (4 waves); wave handles 32 q rows.
// Q/K pointers are column-offset views into the fused QKV hi/lo buffers (stride ldq).
__global__ __launch_bounds__(256, 2)
void attn_mfma(const u16* __restrict__ Qh, const u16* __restrict__ Ql,
               const u16* __restrict__ Kh, const u16* __restrict__ Kl, int ldq,
               const u16* __restrict__ Vth, const u16* __restrict__ Vtl,
               const float* __restrict__ frac,
               const float* __restrict__ apos, const float* __restrict__ aneg,
               float* __restrict__ ctx)
{
  __shared__ __align__(16) u16 KhS[64 * 64];   // [kv][d], chunk^(kv&7) swizzle
  __shared__ __align__(16) u16 KlS[64 * 64];
  __shared__ __align__(16) u16 VhS[64 * 64];   // [d][kv], same swizzle
  __shared__ __align__(16) u16 VlS[64 * 64];
  __shared__ __align__(16) u16 PS[4][32][72];  // per-wave P[q][kv], +8 pad
  __shared__ __align__(16) float fjS[64];

  const int bh = blockIdx.x, b = bh >> 4, h = bh & 15;
  const int tid = threadIdx.x, wid = tid >> 6, lane = tid & 63;
  const int l15 = lane & 15, l4 = lane >> 4;
  const int q0 = blockIdx.y * 128 + wid * 32;

  // Q fragments (B-operand: n = q = l15, k-chunk = l4), pre-scaled & pre-split
  bf16x8 qh[2][2], ql[2][2];
  #pragma unroll
  for (int ni = 0; ni < 2; ni++) {
    const long long qoff = (long long)(b * N_T + q0 + ni * 16 + l15) * ldq + h * 64 + l4 * 8;
    #pragma unroll
    for (int ks = 0; ks < 2; ks++) {
      qh[ni][ks] = *(const bf16x8*)(Qh + qoff + ks * 32);
      ql[ni][ks] = *(const bf16x8*)(Ql + qoff + ks * 32);
    }
  }
  float fq[2];
  #pragma unroll
  for (int ni = 0; ni < 2; ni++) fq[ni] = frac[b * N_T + q0 + ni * 16 + l15];
  const float ap = apos[h], an = aneg[h];

  f32x4 acc[4][2] = {};                 // O^T: d = md*16+l4*4+reg, q = nq*16+l15
  float mrun[2] = {-3.0e38f, -3.0e38f}, lrun[2] = {0.f, 0.f};

  const int sr = tid >> 2, scb = (tid & 3) << 4;
  const int ch0 = ((scb >> 3) ^ (sr & 7)) << 3;
  const int ch1 = (((scb >> 3) + 1) ^ (sr & 7)) << 3;

  for (int kt = 0; kt < 16; kt++) {
    __syncthreads();
    {
      const long long koff = (long long)(b * N_T + kt * 64 + sr) * ldq + h * 64 + scb;
      const uint4* khp = (const uint4*)(Kh + koff);
      const uint4* klp = (const uint4*)(Kl + koff);
      const long long voff = (long long)(bh * 64 + sr) * N_T + kt * 64 + scb;
      const uint4* vhp = (const uint4*)(Vth + voff);
      const uint4* vlp = (const uint4*)(Vtl + voff);
      *(uint4*)&KhS[sr * 64 + ch0] = khp[0];
      *(uint4*)&KhS[sr * 64 + ch1] = khp[1];
      *(uint4*)&KlS[sr * 64 + ch0] = klp[0];
      *(uint4*)&KlS[sr * 64 + ch1] = klp[1];
      *(uint4*)&VhS[sr * 64 + ch0] = vhp[0];
      *(uint4*)&VhS[sr * 64 + ch1] = vhp[1];
      *(uint4*)&VlS[sr * 64 + ch0] = vlp[0];
      *(uint4*)&VlS[sr * 64 + ch1] = vlp[1];
    }
    if (tid < 64) fjS[tid] = frac[b * N_T + kt * 64 + tid];
    __syncthreads();

    // ---- S^T = K * Q^T (3-term split)
    f32x4 s[4][2] = {};
    #pragma unroll
    for (int ks = 0; ks < 2; ks++) {
      bf16x8 kh[4], kl[4];
      #pragma unroll
      for (int mj = 0; mj < 4; mj++) {
        const int row = mj * 16 + l15;
        const int ch = (((ks << 2) + l4) ^ (row & 7)) << 3;
        kh[mj] = *(const bf16x8*)&KhS[row * 64 + ch];
        kl[mj] = *(const bf16x8*)&KlS[row * 64 + ch];
      }
      #pragma unroll
      for (int mj = 0; mj < 4; mj++) {
        #pragma unroll
        for (int ni = 0; ni < 2; ni++) {
          s[mj][ni] = mfma16(kh[mj], qh[ni][ks], s[mj][ni]);
          s[mj][ni] = mfma16(kh[mj], ql[ni][ks], s[mj][ni]);
          s[mj][ni] = mfma16(kl[mj], qh[ni][ks], s[mj][ni]);
        }
      }
    }

    // ---- bias (scalar fjS reads) ; kv = mj*16 + l4*4 + r, q = ni*16 + l15
    #pragma unroll
    for (int mj = 0; mj < 4; mj++) {
      const int kvb = mj * 16 + l4 * 4;
      const float f0 = fjS[kvb], f1 = fjS[kvb + 1], f2 = fjS[kvb + 2], f3 = fjS[kvb + 3];
      #pragma unroll
      for (int ni = 0; ni < 2; ni++) {
        float d0 = f0 - fq[ni], d1 = f1 - fq[ni], d2 = f2 - fq[ni], d3 = f3 - fq[ni];
        s[mj][ni][0] += (d0 > 0.f ? ap : an) * d0;
        s[mj][ni][1] += (d1 > 0.f ? ap : an) * d1;
        s[mj][ni][2] += (d2 > 0.f ? ap : an) * d2;
        s[mj][ni][3] += (d3 > 0.f ? ap : an) * d3;
      }
    }

    // ---- online softmax
    #pragma unroll
    for (int ni = 0; ni < 2; ni++) {
      float tm = s[0][ni][0];
      #pragma unroll
      for (int mj = 0; mj < 4; mj++) {
        tm = fmaxf(tm, fmaxf(fmaxf(s[mj][ni][0], s[mj][ni][1]),
                             fmaxf(s[mj][ni][2], s[mj][ni][3])));
      }
      tm = fmaxf(tm, __shfl_xor(tm, 16, 64));
      tm = fmaxf(tm, __shfl_xor(tm, 32, 64));
      const float nm = fmaxf(mrun[ni], tm);
      const float cor = __expf(mrun[ni] - nm);
      mrun[ni] = nm;
      lrun[ni] *= cor;
      #pragma unroll
      for (int md = 0; md < 4; md++) {
        acc[md][ni][0] *= cor; acc[md][ni][1] *= cor;
        acc[md][ni][2] *= cor; acc[md][ni][3] *= cor;
      }
      float rsum = 0.f;
      #pragma unroll
      for (int mj = 0; mj < 4; mj++) {
        #pragma unroll
        for (int r = 0; r < 4; r++) {
          const float p = __expf(s[mj][ni][r] - nm);
          s[mj][ni][r] = p;
          rsum += p;
        }
      }
      rsum += __shfl_xor(rsum, 16, 64);
      rsum += __shfl_xor(rsum, 32, 64);
      lrun[ni] += rsum;
    }

    // ---- P hi -> per-wave LDS (C-write-verified mapping), read B-frags
    #pragma unroll
    for (int ni = 0; ni < 2; ni++) {
      #pragma unroll
      for (int mj = 0; mj < 4; mj++) {
        float h0 = bfhi_f(s[mj][ni][0]), h1 = bfhi_f(s[mj][ni][1]);
        float h2 = bfhi_f(s[mj][ni][2]), h3 = bfhi_f(s[mj][ni][3]);
        u32* dst = (u32*)&PS[wid][ni * 16 + l15][mj * 16 + l4 * 4];
        dst[0] = rne2(h0, h1); dst[1] = rne2(h2, h3);
      }
    }
    bf16x8 pbh[2][2];
    #pragma unroll
    for (int ni = 0; ni < 2; ni++)
      #pragma unroll
      for (int ks = 0; ks < 2; ks++)
        pbh[ni][ks] = *(const bf16x8*)&PS[wid][ni * 16 + l15][ks * 32 + l4 * 8];

    // ---- P lo -> same LDS buffer, read B-frags
    #pragma unroll
    for (int ni = 0; ni < 2; ni++) {
      #pragma unroll
      for (int mj = 0; mj < 4; mj++) {
        float p0 = s[mj][ni][0], p1 = s[mj][ni][1], p2 = s[mj][ni][2], p3 = s[mj][ni][3];
        float h0 = bfhi_f(p0), h1 = bfhi_f(p1), h2 = bfhi_f(p2), h3 = bfhi_f(p3);
        u32* dst = (u32*)&PS[wid][ni * 16 + l15][mj * 16 + l4 * 4];
        dst[0] = rne2(p0 - h0, p1 - h1); dst[1] = rne2(p2 - h2, p3 - h3);
      }
    }
    bf16x8 pbl[2][2];
    #pragma unroll
    for (int ni = 0; ni < 2; ni++)
      #pragma unroll
      for (int ks = 0; ks < 2; ks++)
        pbl[ni][ks] = *(const bf16x8*)&PS[wid][ni * 16 + l15][ks * 32 + l4 * 8];

    // ---- O^T += V^T * P^T (3-term split; linear kv pairing)
    #pragma unroll
    for (int md = 0; md < 4; md++) {
      #pragma unroll
      for (int ks = 0; ks < 2; ks++) {
        const int row = md * 16 + l15;
        const int ch = (((ks << 2) + l4) ^ (row & 7)) << 3;
        const bf16x8 vh = *(const bf16x8*)&VhS[row * 64 + ch];
        const bf16x8 vl = *(const bf16x8*)&VlS[row * 64 + ch];
        #pragma unroll
        for (int nq = 0; nq < 2; nq++) {
          acc[md][nq] = mfma16(vh, pbh[nq][ks], acc[md][nq]);
          acc[md][nq] = mfma16(vh, pbl[nq][ks], acc[md][nq]);
          acc[md][nq] = mfma16(vl, pbh[nq][ks], acc[md][nq]);
        }
      }
    }
  }

  // ---- epilogue: ctx[q][d] = O^T[d][q] / l[q]
  const float inv[2] = {1.f / lrun[0], 1.f / lrun[1]};
  #pragma unroll
  for (int nq = 0; nq < 2; nq++) {
    #pragma unroll
    for (int md = 0; md < 4; md++) {
      float4 o;
      o.x = acc[md][nq][0] * inv[nq];
      o.y = acc[md][nq][1] * inv[nq];
      o.z = acc[md][nq][2] * inv[nq];
      o.w = acc[md][nq][3] * inv[nq];
      *(float4*)(ctx + (long long)(b * N_T + q0 + nq * 16 + l15) * N_D +
                 h * 64 + md * 16 + l4 * 4) = o;
    }
  }
}

// ---------------- LN1 + gate softmax + top2 (wave per token; NO device atomics) -------------
__global__ __launch_bounds__(256, 4)
void ln1_gate(const float* __restrict__ src, const float* __restrict__ attnout,
              const float* __restrict__ g, const float* __restrict__ bb,
              const float* __restrict__ gateW, const float* __restrict__ gateb,
              float* __restrict__ xout, u16* __restrict__ xbf,
              int2* __restrict__ tok_top, float2* __restrict__ tok_w)
{
  const int wid = threadIdx.x >> 6, lane = threadIdx.x & 63;
  const int t = blockIdx.x * 4 + wid;
  const float4* s4 = (const float4*)(src + (long long)t * N_D);
  const float4* a4 = (const float4*)(attnout + (long long)t * N_D);
  float4 v[4];
  float sum = 0.f;
  #pragma unroll
  for (int c = 0; c < 4; c++) {
    const int idx = c * 64 + lane;
    float4 a = s4[idx], b2 = a4[idx];
    v[c] = make_float4(a.x + b2.x, a.y + b2.y, a.z + b2.z, a.w + b2.w);
    sum += v[c].x + v[c].y + v[c].z + v[c].w;
  }
  sum = wred(sum);
  const float mu = sum * (1.f / 1024.f);
  float s2 = 0.f;
  #pragma unroll
  for (int c = 0; c < 4; c++) {
    float dx = v[c].x - mu, dy = v[c].y - mu, dz = v[c].z - mu, dw = v[c].w - mu;
    s2 += dx * dx + dy * dy + dz * dz + dw * dw;
  }
  s2 = wred(s2);
  const float rs = rsqrtf(s2 * (1.f / 1024.f) + LNEPS);
  float acc[8];
  #pragma unroll
  for (int e2 = 0; e2 < 8; e2++) acc[e2] = 0.f;
  #pragma unroll
  for (int c = 0; c < 4; c++) {
    const int idx = c * 64 + lane;
    float4 gv = ((const float4*)g)[idx], bv = ((const float4*)bb)[idx];
    float xa[4];
    xa[0] = (v[c].x - mu) * rs * gv.x + bv.x;
    xa[1] = (v[c].y - mu) * rs * gv.y + bv.y;
    xa[2] = (v[c].z - mu) * rs * gv.z + bv.z;
    xa[3] = (v[c].w - mu) * rs * gv.w + bv.w;
    ((float4*)(xout + (long long)t * N_D))[idx] = make_float4(xa[0], xa[1], xa[2], xa[3]);
    *(uint2*)&xbf[(long long)t * N_D + idx * 4] =
        make_uint2(rne2(xa[0], xa[1]), rne2(xa[2], xa[3]));
    #pragma unroll
    for (int ii = 0; ii < 4; ii++) {
      const float xs = xa[ii];
      const float4* gw = (const float4*)(gateW + ((long long)(idx * 4 + ii)) * N_E);
      float4 w0 = gw[0], w1 = gw[1];
      acc[0] += xs * w0.x; acc[1] += xs * w0.y; acc[2] += xs * w0.z; acc[3] += xs * w0.w;
      acc[4] += xs * w1.x; acc[5] += xs * w1.y; acc[6] += xs * w1.z; acc[7] += xs * w1.w;
    }
  }
  #pragma unroll
  for (int e2 = 0; e2 < 8; e2++) acc[e2] = wred(acc[e2]);
  if (lane == 0) {
    float lg[8];
    #pragma unroll
    for (int e2 = 0; e2 < 8; e2++) lg[e2] = acc[e2] + gateb[e2];
    float mx = lg[0];
    #pragma unroll
    for (int e2 = 1; e2 < 8; e2++) mx = fmaxf(mx, lg[e2]);
    float Z = 0.f;
    #pragma unroll
    for (int e2 = 0; e2 < 8; e2++) Z += __expf(lg[e2] - mx);
    int e0 = 0; float v0 = lg[0];
    #pragma unroll
    for (int e2 = 1; e2 < 8; e2++) if (lg[e2] > v0) { v0 = lg[e2]; e0 = e2; }
    int e1 = -1; float v1 = -3.4e38f;
    #pragma unroll
    for (int e2 = 0; e2 < 8; e2++) if (e2 != e0 && lg[e2] > v1) { v1 = lg[e2]; e1 = e2; }
    tok_top[t] = make_int2(e0, e1);
    tok_w[t] = make_float2(__expf(v0 - mx) / Z, __expf(v1 - mx) / Z);
  }
}

// ---------------- routing: histogram tok_top, offsets, tiles, padding fill ----------------
__global__ __launch_bounds__(256)
void route_build(const int2* __restrict__ tok_top, int* __restrict__ offsets,
                 int* __restrict__ cursors, int* __restrict__ ntiles,
                 int2* __restrict__ tiles, int* __restrict__ token_idx,
                 float* __restrict__ slot_w)
{
  __shared__ int cnt[N_E];
  __shared__ int soff[N_E + 1];
  __shared__ int scnt[N_E];
  const int tid = threadIdx.x;
  if (tid < N_E) cnt[tid] = 0;
  __syncthreads();
  // histogram: unrolled compare-accumulate (no runtime-indexed register arrays)
  int lc0 = 0, lc1 = 0, lc2 = 0, lc3 = 0, lc4 = 0, lc5 = 0, lc6 = 0, lc7 = 0;
  for (int t = tid; t < N_BT; t += 256) {
    const int2 ee = tok_top[t];
    lc0 += (ee.x == 0) + (ee.y == 0); lc1 += (ee.x == 1) + (ee.y == 1);
    lc2 += (ee.x == 2) + (ee.y == 2); lc3 += (ee.x == 3) + (ee.y == 3);
    lc4 += (ee.x == 4) + (ee.y == 4); lc5 += (ee.x == 5) + (ee.y == 5);
    lc6 += (ee.x == 6) + (ee.y == 6); lc7 += (ee.x == 7) + (ee.y == 7);
  }
  if (lc0) atomicAdd(&cnt[0], lc0); if (lc1) atomicAdd(&cnt[1], lc1);
  if (lc2) atomicAdd(&cnt[2], lc2); if (lc3) atomicAdd(&cnt[3], lc3);
  if (lc4) atomicAdd(&cnt[4], lc4); if (lc5) atomicAdd(&cnt[5], lc5);
  if (lc6) atomicAdd(&cnt[6], lc6); if (lc7) atomicAdd(&cnt[7], lc7);
  __syncthreads();
  if (tid == 0) {
    int off = 0, nt = 0;
    for (int ex = 0; ex < N_E; ex++) {
      soff[ex] = off; offsets[ex] = off; cursors[ex] = 0;
      const int c = cnt[ex];
      scnt[ex] = c;
      const int pt = (c + 127) >> 7;
      for (int i = 0; i < pt; i++) { tiles[nt] = make_int2(ex, off + i * 128); nt++; }
      off += pt << 7;
    }
    soff[N_E] = off; offsets[N_E] = off;
    *ntiles = nt;
  }
  __syncthreads();
  for (int ex = 0; ex < N_E; ex++)
    for (int s = soff[ex] + scnt[ex] + tid; s < soff[ex + 1]; s += 256) {
      token_idx[s] = 0; slot_w[s] = 0.f;
    }
}

__global__ __launch_bounds__(256)
void route_scatter(const int2* __restrict__ tok_top, const float2* __restrict__ tok_w,
                   const int* __restrict__ offsets, int* __restrict__ cursors,
                   int* __restrict__ token_idx, float* __restrict__ slot_w,
                   int* __restrict__ slotA, int* __restrict__ slotB)
{
  const int t = blockIdx.x * 256 + threadIdx.x;
  if (t >= N_BT) return;
  const int2 ee = tok_top[t];
  const float2 ww = tok_w[t];
  int p = atomicAdd(&cursors[ee.x], 1);
  int s = offsets[ee.x] + p;
  token_idx[s] = t; slot_w[s] = ww.x; slotA[t] = s;
  p = atomicAdd(&cursors[ee.y], 1);
  s = offsets[ee.y] + p;
  token_idx[s] = t; slot_w[s] = ww.y; slotB[t] = s;
}

// ---------------- final: y = LN2(x + out2[sA] + out2[sB]) ----------------
__global__ __launch_bounds__(256, 4)
void final_ln2(const float* __restrict__ x, const float* __restrict__ out2,
               const int* __restrict__ slotA, const int* __restrict__ slotB,
               const float* __restrict__ g, const float* __restrict__ bb,
               float* __restrict__ out)
{
  const int wid = threadIdx.x >> 6, lane = threadIdx.x & 63;
  const int t = blockIdx.x * 4 + wid;
  const int sA = slotA[t], sB = slotB[t];
  const float4* xr = (const float4*)(x + (long long)t * N_D);
  const float4* pa = (const float4*)(out2 + (long long)sA * N_D);
  const float4* pb = (const float4*)(out2 + (long long)sB * N_D);
  float4 v[4];
  float sum = 0.f;
  #pragma unroll
  for (int c = 0; c < 4; c++) {
    const int idx = c * 64 + lane;
    float4 a = xr[idx], b2 = pa[idx], c2 = pb[idx];
    v[c] = make_float4(a.x + b2.x + c2.x, a.y + b2.y + c2.y,
                       a.z + b2.z + c2.z, a.w + b2.w + c2.w);
    sum += v[c].x + v[c].y + v[c].z + v[c].w;
  }
  sum = wred(sum);
  const float mu = sum * (1.f / 1024.f);
  float s2 = 0.f;
  #pragma unroll
  for (int c = 0; c < 4; c++) {
    float dx = v[c].x - mu, dy = v[c].y - mu, dz = v[c].z - mu, dw = v[c].w - mu;
    s2 += dx * dx + dy * dy + dz * dz + dw * dw;
  }
  s2 = wred(s2);
  const float rs = rsqrtf(s2 * (1.f / 1024.f) + LNEPS);
  #pragma unroll
  for (int c = 0; c < 4; c++) {
    const int idx = c * 64 + lane;
    float4 gv = ((const float4*)g)[idx], bv = ((const float4*)bb)[idx];
    float4 o;
    o.x = (v[c].x - mu) * rs * gv.x + bv.x;
    o.y = (v[c].y - mu) * rs * gv.y + bv.y;
    o.z = (v[c].z - mu) * rs * gv.z + bv.z;
    o.w = (v[c].w - mu) * rs * gv.w + bv.w;
    ((float4*)(out + (long long)t * N_D))[idx] = o;
  }
}

// ---------------- launch ----------------
extern "C" void kernel_launch(void* const* d_in, const int* in_sizes, int n_in,
                              void* d_out, int out_size, void* d_ws, size_t ws_size,
                              hipStream_t stream)
{
  const float* src   = (const float*)d_in[0];
  const float* frac  = (const float*)d_in[1];
  const float* Wq    = (const float*)d_in[2];
  const float* bq    = (const float*)d_in[3];
  const float* Wk    = (const float*)d_in[4];
  const float* bk    = (const float*)d_in[5];
  const float* Wv    = (const float*)d_in[6];
  const float* bv    = (const float*)d_in[7];
  const float* Wo    = (const float*)d_in[8];
  const float* bo    = (const float*)d_in[9];
  const float* apos  = (const float*)d_in[10];
  const float* aneg  = (const float*)d_in[11];
  const float* gateW = (const float*)d_in[12];
  const float* gateb = (const float*)d_in[13];
  const float* W1    = (const float*)d_in[14];
  const float* b1    = (const float*)d_in[15];
  const float* W2    = (const float*)d_in[16];
  const float* b2    = (const float*)d_in[17];
  const float* ln1g  = (const float*)d_in[18];
  const float* ln1b  = (const float*)d_in[19];
  const float* ln2g  = (const float*)d_in[20];
  const float* ln2b  = (const float*)d_in[21];
  float* out = (float*)d_out;

  char* ws = (char*)d_ws;
  const size_t MB = 1ull << 20;
  u16* Bcath = (u16*)(ws + 0 * MB);
  u16* Bcatl = (u16*)(ws + 6 * MB);
  u16* WoTh  = (u16*)(ws + 12 * MB);
  u16* WoTl  = (u16*)(ws + 14 * MB);
  u16*   W1T  = (u16*)(ws + 16 * MB);    // 64 MB, dead after FFN GEMM1
  float* out2 = (float*)(ws + 16 * MB);  // <=38 MB, alias (written after W1T dead)
  u16*   W2T  = (u16*)(ws + 80 * MB);    // 64 MB
  u16*   QKVh = (u16*)(ws + 144 * MB);   // 24 MB: [4096][3072] hi (Q|K|V)
  u16*   QKVl = (u16*)(ws + 168 * MB);   // 24 MB lo
  u16*   Vth  = (u16*)(ws + 192 * MB);   // 8 MB per-head V^T hi
  u16*   Vtl  = (u16*)(ws + 200 * MB);   // 8 MB per-head V^T lo
  float* ctxb = (float*)(ws + 208 * MB); // 16 MB
  float* attnb= (float*)(ws + 144 * MB); // 16 MB alias (QKVh dead after attn)
  u16*   hb   = (u16*)(ws + 144 * MB);   // <=72 MB alias (all of 144-216 dead by FFN1)
  float* xb   = (float*)(ws + 224 * MB); // 16 MB fp32 -> total 240 MB
  u16*   xbf  = (u16*)(ws + 4 * MB);     // 8 MB bf16 alias (Bcat dead by ln1_gate)
  float* bcat = (float*)(ws + 240 * MB); // 12 KB
  char* misc = ws + 0;                   // aliases Bcat region (dead by routing phase)
  int*    cursors   = (int*)(misc + 64);
  int*    offsets   = (int*)(misc + 128);
  int*    ntiles    = (int*)(misc + 256);
  int2*   tiles     = (int2*)(misc + 512);
  int2*   tok_top   = (int2*)(misc + 2048);
  float2* tok_w     = (float2*)(misc + 2048 + 32768);
  int*    token_idx = (int*)(misc + 2048 + 65536);
  float*  slot_w    = (float*)(misc + 2048 + 65536 + 36864);
  int*    slotA     = (int*)(misc + 2048 + 65536 + 73728);
  int*    slotB     = (int*)(misc + 2048 + 65536 + 73728 + 16384);

  dim3 b256(256);
  transpose_bf16<1><<<dim3(16, 16, 1), b256, 0, stream>>>(Wq, Bcath, Bcatl,
                                                          1024, 1024, 0.125f);
  transpose_bf16<1><<<dim3(16, 16, 1), b256, 0, stream>>>(Wk, Bcath + 1024 * 1024,
                                                          Bcatl + 1024 * 1024, 1024, 1024, 1.0f);
  transpose_bf16<1><<<dim3(16, 16, 1), b256, 0, stream>>>(Wv, Bcath + 2048 * 1024,
                                                          Bcatl + 2048 * 1024, 1024, 1024, 1.0f);
  transpose_bf16<1><<<dim3(16, 16, 1), b256, 0, stream>>>(Wo, WoTh, WoTl, 1024, 1024, 1.0f);
  transpose_bf16<0><<<dim3(64, 16, 8), b256, 0, stream>>>(W1, W1T, nullptr, 1024, 4096, 1.0f);
  transpose_bf16<0><<<dim3(16, 64, 8), b256, 0, stream>>>(W2, W2T, nullptr, 4096, 1024, 1.0f);
  bias_cat<<<dim3(12), b256, 0, stream>>>(bq, bk, bv, bcat);

  // fused QKV projection: [4096][3072] hi/lo bf16 (Q cols pre-scaled via Wq/bq); CG=3
  gemm128<1, 0, 0, 0, 2, 0, 3><<<dim3(32, 24), b256, 0, stream>>>(
      src, 1024, Bcath, Bcatl, 0, QKVh, 3072, bcat, 0, nullptr, nullptr, nullptr, nullptr,
      1024, QKVl, 1.0f);

  vtrans_bf16<<<dim3(16, 64), b256, 0, stream>>>(QKVh + 2048, QKVl + 2048, 3072, Vth, Vtl);

  attn_mfma<<<dim3(64, 8), b256, 0, stream>>>(QKVh, QKVl, QKVh + 1024, QKVl + 1024, 3072,
                                              Vth, Vtl, frac, apos, aneg, ctxb);

  gemm128<1, 0, 0, 0, 0, 0, 1><<<dim3(32, 8), b256, 0, stream>>>(
      ctxb, 1024, WoTh, WoTl, 0, attnb, 1024, bo, 0, nullptr, nullptr, nullptr, nullptr,
      1024, nullptr, 1.0f);

  ln1_gate<<<dim3(1024), b256, 0, stream>>>(src, attnb, ln1g, ln1b, gateW, gateb,
                                            xb, xbf, tok_top, tok_w);
  route_build<<<dim3(1), b256, 0, stream>>>(tok_top, offsets, cursors, ntiles,
                                            tiles, token_idx, slot_w);
  route_scatter<<<dim3(16), b256, 0, stream>>>(tok_top, tok_w, offsets, cursors,
                                               token_idx, slot_w, slotA, slotB);

  // grouped MoE FFN (bf16 A+B, double-buffered global_load_lds staging)
  gemm128<0, 1, 1, 0, 1, 1, 4><<<dim3(72, 32), b256, 0, stream>>>(
      xbf, 1024, W1T, nullptr, 4096ll * 1024, hb, 4096, b1, 4096,
      nullptr, token_idx, tiles, ntiles, 1024, nullptr, 1.0f);
  gemm128<0, 0, 0, 1, 0, 1, 8><<<dim3(72, 8), b256, 0, stream>>>(
      hb, 4096, W2T, nullptr, 1024ll * 4096, out2, 1024, b2, 1024,
      slot_w, nullptr, tiles, ntiles, 4096, nullptr, 1.0f);

  final_ln2<<<dim3(1024), b256, 0, stream>>>(xb, out2, slotA, slotB, ln2g, ln2b, out);
}